// Round 24
// baseline (917.511 us; speedup 1.0000x reference)
//
#include <hip/hip_runtime.h>

static constexpr int FU_L  = 676;   // 26*26
static constexpr int FU_H  = 26;
static constexpr int FU_C  = 512;
static constexpr int FU_CQ = 128;   // C/4

// ================= fast-path ws layout (floats) =================
static constexpr unsigned FU_OFF_MBUF = 0u;          // 22151168  m (conv1 out)
static constexpr unsigned FU_OFF_BM   = 22151168u;   //  5537792  Bm f32 [o][l]; later V f32 [o][s]
static constexpr unsigned FU_OFF_BIG  = 27688960u;   // 22151168  phase0: sim partials; phase1: BmHL/BmTHL/GHL; phase2: yvt-HL
static constexpr unsigned FU_OFF_V    = 49840128u;   //  4194304  WT (early); later VT hi/lo u16 (fragment-major)
static constexpr unsigned FU_OFF_SIM  = 54034432u;   //   389376  sim (b,9,676)
static constexpr unsigned FU_OFF_M2HL = 54423808u;   //   262144  m2_w hi/lo u16
static constexpr unsigned FU_OFF_W2HL = 54685952u;   //   262144  conv2_w hi/lo u16 (fragment-major)
static constexpr unsigned FU_OFF_S2   = 54948096u;   //      512
static constexpr unsigned FU_OFF_BI2  = 54948608u;   //      512
static constexpr unsigned FU_FAST_FLOATS = 54949120u;   // 219.8 MB

// fallback (round-5) layout
static constexpr unsigned FU_FB_MBUF = 0u;
static constexpr unsigned FU_FB_BM   = 22151168u;
static constexpr unsigned FU_FB_V    = 27688960u;
static constexpr unsigned FU_FB_SIM  = 31883264u;
static constexpr unsigned FU_FB_FLOATS = 32272640u;  // 129.1 MB

// u16 sub-offsets inside BIG (phase 1)
static constexpr unsigned FU_U16_BMHI  = 0u;
static constexpr unsigned FU_U16_BMLO  = 5537792u;
static constexpr unsigned FU_U16_BMTHI = 11075584u;  // fragment-major [(o>>5)][l][o&31]
static constexpr unsigned FU_U16_BMTLO = 16613376u;
static constexpr unsigned FU_U16_GHI   = 22151168u;
static constexpr unsigned FU_U16_GLO   = 26345472u;
// u16 sub-offsets inside BIG (phase 2): yvt fragment-major [kc][l2][ksub]
static constexpr unsigned FU_U16_YVHI  = 0u;
static constexpr unsigned FU_U16_YVLO  = 22151168u;
// u16 layout of d_out when used as scratch
static constexpr unsigned FU_U16_XHI   = 0u;
static constexpr unsigned FU_U16_XLO   = 22151168u;
// u16 sub-offsets inside VT region
static constexpr unsigned FU_U16_VTLO  = 4194304u;

typedef __bf16 fu_bf16x8 __attribute__((ext_vector_type(8)));
typedef float  fu_f32x4  __attribute__((ext_vector_type(4)));

union FuFrag {
  uint4 u4;
  uint2 u2[2];
  fu_bf16x8 bf;
};

__device__ __forceinline__ unsigned short fu_rnebf(float f){
  unsigned int u = __float_as_uint(f);
  u += 0x7fffu + ((u >> 16) & 1u);
  return (unsigned short)(u >> 16);
}
__device__ __forceinline__ void fu_hilo(float f, unsigned short& h, unsigned short& l){
  h = fu_rnebf(f);
  float fh = __uint_as_float(((unsigned int)h) << 16);
  l = fu_rnebf(f - fh);
}
__device__ __forceinline__ fu_f32x4 fu_mm(const FuFrag& a, const FuFrag& b, fu_f32x4 c){
  return __builtin_amdgcn_mfma_f32_16x16x32_bf16(a.bf, b.bf, c, 0, 0, 0);
}

// Identifier-named kernel; kept for symbol presence + diagnostics.
__global__ __launch_bounds__(256) void FoldUnfoldModule_82592221102582_kernel(
    float* __restrict__ out, int n, float val){
  int i = blockIdx.x*256 + threadIdx.x;
  int stride = gridDim.x*256;
  for (; i < n; i += stride) out[i] = val;
}

// ---------------- self-similarity v3: grid (11,64,4); 128 ch per block -> partials ----------------
__global__ __launch_bounds__(256) void fu_sim3(const float* __restrict__ x, float* __restrict__ psim){
  __shared__ float red[3][64][8];
  int lq = threadIdx.x & 63, cg = threadIdx.x >> 6;
  int l = blockIdx.x*64 + lq;
  int b = blockIdx.y;
  int z = blockIdx.z;
  bool lval = l < FU_L;
  int yy = l / FU_H, xx = l - yy*FU_H;
  int noff[8]; bool nval[8];
  #pragma unroll
  for (int t=1;t<9;t++){
    int di = t/3 - 1, dj = t%3 - 1;
    int y2 = yy + di, x2 = xx + dj;
    nval[t-1] = lval && (y2>=0 && y2<FU_H && x2>=0 && x2<FU_H);
    noff[t-1] = nval[t-1] ? (y2*FU_H + x2) : 0;
  }
  float acc[8] = {0,0,0,0,0,0,0,0};
  const float* xb = x + (size_t)b*FU_C*FU_L;
  int c0 = z*128 + cg*32;
  for (int c=c0; c<c0+32; c++){
    const float* row = xb + c*FU_L;
    float ctr = lval ? row[l] : 0.f;
    #pragma unroll
    for (int t=0;t<8;t++)
      if (nval[t]) acc[t] += row[noff[t]] * ctr;
  }
  if (cg > 0){
    #pragma unroll
    for (int t=0;t<8;t++) red[cg-1][lq][t] = acc[t];
  }
  __syncthreads();
  if (cg == 0 && lval){
    #pragma unroll
    for (int g=0;g<3;g++)
      #pragma unroll
      for (int t=0;t<8;t++) acc[t] += red[g][lq][t];
    float* pb = psim + ((size_t)z*64 + b)*8*FU_L;
    #pragma unroll
    for (int t=0;t<8;t++) pb[t*FU_L + l] = acc[t];
  }
}

// reduce 4 partials -> sim[b][9][676] (tap 0 zeroed)
__global__ __launch_bounds__(256) void fu_sim_red(const float* __restrict__ psim, float* __restrict__ simb){
  int i = blockIdx.x*256 + threadIdx.x;          // over 64*8*676
  const int tot = 64*8*FU_L;
  if (i >= tot) return;
  int b = i / (8*FU_L);
  int r = i - b*8*FU_L;                          // tap*676 + l, taps 1..8
  const size_t zs = (size_t)64*8*FU_L;
  float s = psim[(size_t)b*8*FU_L + r] + psim[zs + (size_t)b*8*FU_L + r]
          + psim[2*zs + (size_t)b*8*FU_L + r] + psim[3*zs + (size_t)b*8*FU_L + r];
  simb[(size_t)b*9*FU_L + FU_L + r] = s;
  if (i < 64*FU_L) simb[(size_t)(i/FU_L)*9*FU_L + (i%FU_L)] = 0.f;
}

// ---------------- self-similarity v2 (fallback path only) ----------------
__global__ __launch_bounds__(256) void fu_sim2(const float* __restrict__ x, float* __restrict__ simb){
  __shared__ float red[3][64][8];
  int lq = threadIdx.x & 63, cg = threadIdx.x >> 6;
  int l = blockIdx.x*64 + lq;
  int b = blockIdx.y;
  bool lval = l < FU_L;
  int yy = l / FU_H, xx = l - yy*FU_H;
  int noff[8]; bool nval[8];
  #pragma unroll
  for (int t=1;t<9;t++){
    int di = t/3 - 1, dj = t%3 - 1;
    int y2 = yy + di, x2 = xx + dj;
    nval[t-1] = lval && (y2>=0 && y2<FU_H && x2>=0 && x2<FU_H);
    noff[t-1] = nval[t-1] ? (y2*FU_H + x2) : 0;
  }
  float acc[8] = {0,0,0,0,0,0,0,0};
  const float* xb = x + (size_t)b*FU_C*FU_L;
  int c0 = cg*128;
  for (int c=c0; c<c0+128; c++){
    const float* row = xb + c*FU_L;
    float ctr = lval ? row[l] : 0.f;
    #pragma unroll
    for (int t=0;t<8;t++)
      if (nval[t]) acc[t] += row[noff[t]] * ctr;
  }
  if (cg > 0){
    #pragma unroll
    for (int t=0;t<8;t++) red[cg-1][lq][t] = acc[t];
  }
  __syncthreads();
  if (cg == 0 && lval){
    #pragma unroll
    for (int g=0;g<3;g++)
      #pragma unroll
      for (int t=0;t<8;t++) acc[t] += red[g][lq][t];
    float* sb = simb + (size_t)b*9*FU_L;
    sb[l] = 0.f;
    #pragma unroll
    for (int t=0;t<8;t++) sb[(t+1)*FU_L + l] = acc[t];
  }
}

// ---------------- conv1: padded-halo LDS, 3 l x 32 o per thread, scalar weights ----------------
__global__ __launch_bounds__(256) void fu_conv1b(const float* __restrict__ cw,
                                                 const float* __restrict__ g1, const float* __restrict__ b1,
                                                 const float* __restrict__ m1, const float* __restrict__ v1,
                                                 const float* __restrict__ simb, float* __restrict__ mbuf){
  __shared__ float sp[8][784];
  const int b  = blockIdx.x;
  const int o0 = blockIdx.y * 32;
  const int tid = threadIdx.x;
  const float* sb = simb + (size_t)b*9*FU_L;
  for (int i = tid; i < 8*784; i += 256){
    int ch = i / 784, p = i - ch*784;
    int py = p / 28, px = p - py*28;
    float v = 0.f;
    if (py >= 1 && py <= 26 && px >= 1 && px <= 26)
      v = sb[(ch+1)*FU_L + (py-1)*FU_H + (px-1)];
    sp[ch][p] = v;
  }
  __syncthreads();

  const int l0 = tid, l1 = tid + 256, l2 = tid + 512;
  const bool l2ok = l2 < FU_L;
  const int lc2 = l2ok ? l2 : 0;
  int yy, xx;
  yy = l0/FU_H; xx = l0 - yy*FU_H; const int pb0 = yy*28 + xx;
  yy = l1/FU_H; xx = l1 - yy*FU_H; const int pb1 = yy*28 + xx;
  yy = lc2/FU_H; xx = lc2 - yy*FU_H; const int pb2 = yy*28 + xx;

  for (int ot = 0; ot < 4; ot++){
    float acc[8][3];
    #pragma unroll
    for (int oo=0;oo<8;oo++){ acc[oo][0]=0.f; acc[oo][1]=0.f; acc[oo][2]=0.f; }
    for (int ch = 0; ch < 8; ch++){
      const float* spc = sp[ch];
      float sa[9], sbv[9], sc[9];
      #pragma unroll
      for (int dy=0; dy<3; dy++)
        #pragma unroll
        for (int dx=0; dx<3; dx++){
          int t = dy*3 + dx, off = dy*28 + dx;
          sa[t]  = spc[pb0 + off];
          sbv[t] = spc[pb1 + off];
          sc[t]  = spc[pb2 + off];
        }
      #pragma unroll
      for (int oo=0; oo<8; oo++){
        const float* wp = cw + (size_t)(o0 + ot*8 + oo)*81 + (ch+1)*9;
        #pragma unroll
        for (int t=0; t<9; t++){
          float w = wp[t];
          acc[oo][0] += w*sa[t];
          acc[oo][1] += w*sbv[t];
          acc[oo][2] += w*sc[t];
        }
      }
    }
    #pragma unroll
    for (int oo=0; oo<8; oo++){
      int o = o0 + ot*8 + oo;
      float s1 = g1[o] / sqrtf(v1[o] + 1e-5f);
      float bb = b1[o] - m1[o]*s1;
      size_t base = ((size_t)b*FU_C + o)*FU_L;
      float r0 = acc[oo][0]*s1 + bb; r0 = r0 >= 0.f ? r0 : 0.01f*r0;
      float r1 = acc[oo][1]*s1 + bb; r1 = r1 >= 0.f ? r1 : 0.01f*r1;
      float r2 = acc[oo][2]*s1 + bb; r2 = r2 >= 0.f ? r2 : 0.01f*r2;
      mbuf[base + l0] = r0;
      mbuf[base + l1] = r1;
      if (l2ok) mbuf[base + l2] = r2;
    }
  }
}

// ---------------- m1_w [o][c] -> WT [c][o] (128x512 -> 512x128) ----------------
__global__ __launch_bounds__(256) void fu_tr_w1(const float* __restrict__ w, float* __restrict__ wt){
  __shared__ float t[32][33];
  const int o0 = blockIdx.x*32;   // 4
  const int c0 = blockIdx.y*32;   // 16
  const int tx = threadIdx.x & 31, ty = threadIdx.x >> 5;
  #pragma unroll
  for (int q=0;q<4;q++)
    t[ty+8*q][tx] = w[(size_t)(o0+ty+8*q)*FU_C + c0+tx];
  __syncthreads();
  #pragma unroll
  for (int q=0;q<4;q++)
    wt[(size_t)(c0+ty+8*q)*FU_CQ + o0+tx] = t[tx][ty+8*q];
}

// ---------------- Bm = m1_w @ x via WT[c][o]; 4 o x 4 l per thread; flat 1536 + XCD swizzle ----------------
__global__ __launch_bounds__(256) void fu_gemm_bm(const float* __restrict__ WT, const float* __restrict__ x,
                                                  float* __restrict__ bmout){
  const int flat = blockIdx.x;                      // 1536 = 64 b x (6 l-tiles x 4 o-tiles)
  const int swz  = (flat & 7)*192 + (flat >> 3);    // bijective; each XCD owns 8 whole batches
  const int b    = swz / 24;
  const int rem  = swz - b*24;
  const int ot   = rem / 6;                         // o-tile 0..3
  const int lt   = rem - ot*6;                      // l-tile 0..5
  int tid = threadIdx.x, p = tid & 31, og = tid >> 5;
  int l = lt*128 + p*4;
  int o = ot*32 + og*4;
  if (l >= FU_L) return;                            // 676 = 169*4: active lanes always full float4
  const float* inb = x + (size_t)b*FU_C*FU_L + l;
  float a[4][4] = {};
  for (int c=0;c<FU_C;c++){
    float4 xa = *(const float4*)(inb + (size_t)c*FU_L);
    float4 wv = *(const float4*)(WT + (size_t)c*FU_CQ + o);
    float xs[4] = {xa.x,xa.y,xa.z,xa.w};
    #pragma unroll
    for (int j=0;j<4;j++){
      a[0][j] += wv.x*xs[j]; a[1][j] += wv.y*xs[j];
      a[2][j] += wv.z*xs[j]; a[3][j] += wv.w*xs[j];
    }
  }
  float* o0 = bmout + (size_t)b*FU_CQ*FU_L + o*FU_L + l;
  #pragma unroll
  for (int oo=0;oo<4;oo++){
    float4 v;
    v.x = a[oo][0]; v.y = a[oo][1]; v.z = a[oo][2]; v.w = a[oo][3];
    *(float4*)(o0 + oo*FU_L) = v;
  }
}

// ---------------- fallback-only kernels (round-5 path) ----------------
__global__ __launch_bounds__(256) void fu_gemm_bm_fb(const float* __restrict__ W, const float* __restrict__ x,
                                                     float* __restrict__ bmout){
  int tid = threadIdx.x, p = tid & 31, og = tid >> 5;
  int l = blockIdx.x*256 + p*8;
  int o = blockIdx.y*32 + og*4;
  int b = blockIdx.z;
  if (l >= FU_L) return;
  int nv = FU_L - l; if (nv > 8) nv = 8;
  bool hi_ok = (l + 8 <= FU_L);
  const float* inb = x + (size_t)b*FU_C*FU_L + l;
  float a[4][8] = {};
  for (int c=0;c<FU_C;c++){
    const float* r = inb + c*FU_L;
    float4 xa = *(const float4*)(r);
    float4 xb2;
    if (hi_ok) xb2 = *(const float4*)(r + 4); else { xb2.x=0;xb2.y=0;xb2.z=0;xb2.w=0; }
    float xs[8] = {xa.x,xa.y,xa.z,xa.w,xb2.x,xb2.y,xb2.z,xb2.w};
    float w0 = W[(o+0)*FU_C + c], w1 = W[(o+1)*FU_C + c];
    float w2 = W[(o+2)*FU_C + c], w3 = W[(o+3)*FU_C + c];
    #pragma unroll
    for (int j=0;j<8;j++){
      a[0][j] += w0*xs[j]; a[1][j] += w1*xs[j];
      a[2][j] += w2*xs[j]; a[3][j] += w3*xs[j];
    }
  }
  float* o0 = bmout + (size_t)b*FU_CQ*FU_L + o*FU_L + l;
  #pragma unroll
  for (int oo=0;oo<4;oo++)
    for (int j=0;j<nv;j++) o0[oo*FU_L + j] = a[oo][j];
}

__global__ __launch_bounds__(256) void fu_gemm_b2(const float* __restrict__ W, const float* __restrict__ x,
                                                  float* __restrict__ b2out){
  int tid = threadIdx.x, p = tid & 31, og = tid >> 5;
  int l = blockIdx.x*256 + p*8;
  int o = blockIdx.y*16 + og*2;
  int b = blockIdx.z;
  if (l >= FU_L) return;
  int nv = FU_L - l; if (nv > 8) nv = 8;
  bool hi_ok = (l + 8 <= FU_L);
  const float* inb = x + (size_t)b*FU_C*FU_L + l;
  const float* w0p = W + o*FU_C;
  const float* w1p = w0p + FU_C;
  float a0[8] = {0,0,0,0,0,0,0,0};
  float a1[8] = {0,0,0,0,0,0,0,0};
  for (int c=0;c<FU_C;c++){
    const float* r = inb + c*FU_L;
    float4 xa = *(const float4*)(r);
    float4 xb2;
    if (hi_ok) xb2 = *(const float4*)(r + 4); else { xb2.x=0;xb2.y=0;xb2.z=0;xb2.w=0; }
    float xs[8] = {xa.x,xa.y,xa.z,xa.w,xb2.x,xb2.y,xb2.z,xb2.w};
    float w0 = w0p[c], w1 = w1p[c];
    #pragma unroll
    for (int j=0;j<8;j++){ a0[j] += w0*xs[j]; a1[j] += w1*xs[j]; }
  }
  float* o0 = b2out + (size_t)b*FU_C*FU_L + o*FU_L + l;
  for (int j=0;j<nv;j++){ o0[j] = a0[j]; o0[FU_L+j] = a1[j]; }
}

__global__ __launch_bounds__(256) void fu_V(const float* __restrict__ bm, const float* __restrict__ b2in,
                                            float* __restrict__ vout){
  int tid = threadIdx.x; int tx = tid & 15, ty = tid >> 4;
  int o = blockIdx.y*64 + ty*4;
  int s = blockIdx.x*64 + tx*4;
  int b = blockIdx.z;
  const float* A  = bm + (size_t)b*FU_CQ*FU_L;
  const float* Bt = b2in + (size_t)b*FU_C*FU_L;
  float acc[4][4] = {};
  for (int k=0;k<FU_L;k+=4){
    float4 av[4], bv[4];
    #pragma unroll
    for (int i=0;i<4;i++) av[i] = *(const float4*)(A + (o+i)*FU_L + k);
    #pragma unroll
    for (int j=0;j<4;j++) bv[j] = *(const float4*)(Bt + (s+j)*FU_L + k);
    #pragma unroll
    for (int i=0;i<4;i++){
      #pragma unroll
      for (int j=0;j<4;j++)
        acc[i][j] += av[i].x*bv[j].x + av[i].y*bv[j].y + av[i].z*bv[j].z + av[i].w*bv[j].w;
    }
  }
  #pragma unroll
  for (int i=0;i<4;i++)
    #pragma unroll
    for (int j=0;j<4;j++)
      vout[(size_t)b*FU_CQ*FU_C + (o+i)*FU_C + s + j] = acc[i][j]*(1.0f/676.0f);
}

__global__ __launch_bounds__(256) void fu_y(const float* __restrict__ bm, const float* __restrict__ v,
                                            float* __restrict__ yout){
  int tid = threadIdx.x; int tx = tid & 15, ty = tid >> 4;
  int l = blockIdx.y*64 + ty*4;
  int s = blockIdx.x*64 + tx*4;
  int b = blockIdx.z;
  if (l >= FU_L) return;
  const float* A  = bm + (size_t)b*FU_CQ*FU_L;
  const float* Vb = v  + (size_t)b*FU_CQ*FU_C;
  float acc[4][4] = {};
  for (int c=0;c<FU_CQ;c++){
    float4 av = *(const float4*)(A + c*FU_L + l);
    float4 bv = *(const float4*)(Vb + c*FU_C + s);
    float ai[4] = {av.x, av.y, av.z, av.w};
    float bj[4] = {bv.x, bv.y, bv.z, bv.w};
    #pragma unroll
    for (int i=0;i<4;i++)
      #pragma unroll
      for (int j=0;j<4;j++)
        acc[i][j] += ai[i]*bj[j];
  }
  #pragma unroll
  for (int i=0;i<4;i++)
    #pragma unroll
    for (int j=0;j<4;j++)
      yout[(size_t)b*FU_L*FU_C + (size_t)(l+i)*FU_C + s + j] = acc[i][j];
}

__global__ __launch_bounds__(256) void fu_c2(const float* __restrict__ yv, const float* __restrict__ W,
                                             const float* __restrict__ g2, const float* __restrict__ b2,
                                             const float* __restrict__ m2, const float* __restrict__ v2,
                                             const float* __restrict__ x, float* __restrict__ mio){
  int tid = threadIdx.x, p = tid & 31, og = tid >> 5;
  int l = blockIdx.x*256 + p*8;
  int o = blockIdx.y*16 + og*2;
  int b = blockIdx.z;
  if (l >= FU_L) return;
  int nv = FU_L - l; if (nv > 8) nv = 8;
  bool hi_ok = (l + 8 <= FU_L);
  const float* inb = yv + (size_t)b*FU_C*FU_L + l;
  const float* w0p = W + o*FU_C;
  const float* w1p = w0p + FU_C;
  float a0[8] = {0,0,0,0,0,0,0,0};
  float a1[8] = {0,0,0,0,0,0,0,0};
  for (int c=0;c<FU_C;c++){
    const float* r = inb + c*FU_L;
    float4 xa = *(const float4*)(r);
    float4 xb2;
    if (hi_ok) xb2 = *(const float4*)(r + 4); else { xb2.x=0;xb2.y=0;xb2.z=0;xb2.w=0; }
    float xs[8] = {xa.x,xa.y,xa.z,xa.w,xb2.x,xb2.y,xb2.z,xb2.w};
    float w0 = w0p[c], w1 = w1p[c];
    #pragma unroll
    for (int j=0;j<8;j++){ a0[j] += w0*xs[j]; a1[j] += w1*xs[j]; }
  }
  float s20 = g2[o]   / sqrtf(v2[o]   + 1e-5f);
  float s21 = g2[o+1] / sqrtf(v2[o+1] + 1e-5f);
  float bi0 = b2[o]   - m2[o]*s20;
  float bi1 = b2[o+1] - m2[o+1]*s21;
  size_t base = (size_t)b*FU_C*FU_L + (size_t)o*FU_L + l;
  for (int j=0;j<nv;j++){
    float v0 = a0[j]*s20 + bi0; v0 = v0 >= 0.f ? v0 : 0.01f*v0;
    float v1 = a1[j]*s21 + bi1; v1 = v1 >= 0.f ? v1 : 0.01f*v1;
    mio[base + j]        = v0 + mio[base + j]        * x[base + j];
    mio[base + FU_L + j] = v1 + mio[base + FU_L + j] * x[base + FU_L + j];
  }
}

// ---------------- GNN fast path v6: 4 instances/block; 2-lane-split phase 1; hoisted phases 3/4 ----------------
__global__ __launch_bounds__(256) void fu_gnn6(const float* __restrict__ mmat, const float* __restrict__ ivmat,
                                               const float* __restrict__ xg,
                                               const float* __restrict__ wgm, const float* __restrict__ lna,
                                               const float* __restrict__ lnb, float* __restrict__ out){
  __shared__ float sX[4][676], sA[4][676], sXn[4][676], sWg[676], sLa[26], sLb[26];
  const int g = threadIdx.x >> 6;   // instance 0..3
  const int t = threadIdx.x & 63;
  const size_t n = (size_t)blockIdx.x*4 + g;
  const float* Mrow = mmat + n*676;
  const float* Irow = ivmat + n*676;
  const float* Xres = xg + n*676;
  for (int i=t;i<676;i+=64)
    sX[g][i] = Irow[i] + Mrow[i]*Xres[i];
  if (g == 0){
    for (int i=t;i<676;i+=64) sWg[i] = wgm[i];
    if (t < 26){ sLa[t] = lna[t]; sLb[t] = lnb[t]; }
  }
  __syncthreads();
  // phase 1: 52 lanes; 2 lanes per softmax column, then 2 lanes per LN row (shuffle-combined halves)
  if (t < 52){
    const int cr = t >> 1;          // column (softmax) / row (LN) 0..25
    const int h0 = (t & 1)*13;
    // --- softmax over h for column cr ---
    float mx = -1e30f;
    #pragma unroll
    for (int k=0;k<13;k++) mx = fmaxf(mx, sX[g][(h0+k)*26 + cr]);
    mx = fmaxf(mx, __shfl_xor(mx, 1));
    float sum = 0.f;
    #pragma unroll
    for (int k=0;k<13;k++){
      float e = __expf(sX[g][(h0+k)*26 + cr] - mx);
      sA[g][cr*26 + h0 + k] = e;
      sum += e;
    }
    sum += __shfl_xor(sum, 1);
    float inv = 1.f/sum;
    #pragma unroll
    for (int k=0;k<13;k++) sA[g][cr*26 + h0 + k] *= inv;
    // --- LayerNorm over v for row cr ---
    float s = 0.f;
    #pragma unroll
    for (int k=0;k<13;k++) s += sX[g][cr*26 + h0 + k];
    s += __shfl_xor(s, 1);
    float mean = s * (1.f/26.f);
    float var = 0.f;
    #pragma unroll
    for (int k=0;k<13;k++){ float d = sX[g][cr*26 + h0 + k] - mean; var += d*d; }
    var += __shfl_xor(var, 1);
    var *= (1.f/25.f);
    float invd = 1.f/(sqrtf(var) + 1e-6f);
    #pragma unroll
    for (int k=0;k<13;k++){
      int v = h0 + k;
      sXn[g][cr*26 + v] = sLa[v]*(sX[g][cr*26 + v] - mean)*invd + sLb[v];
    }
  }
  __syncthreads();
  // phase 3: node = A @ Xn -> sX. 2 threads/row: row r = t>>1 (t<52), 13 cols each.
  {
    const int r = t >> 1;
    if (r < 26){
      const int v0 = (t & 1)*13;
      float ar[26];
      #pragma unroll
      for (int h=0;h<26;h++) ar[h] = sA[g][r*26 + h];
      #pragma unroll
      for (int k=0;k<13;k++){
        int v = v0 + k;
        float s = 0.f;
        #pragma unroll
        for (int h=0;h<26;h++) s += ar[h]*sXn[g][h*26 + v];
        sX[g][r*26 + v] = s;
      }
    }
  }
  __syncthreads();
  // phase 4: out = relu(node @ Wg) + x. 2 threads/row.
  {
    const int r = t >> 1;
    if (r < 26){
      const int u0 = (t & 1)*13;
      float nr[26];
      #pragma unroll
      for (int v=0;v<26;v++) nr[v] = sX[g][r*26 + v];
      #pragma unroll
      for (int k=0;k<13;k++){
        int u = u0 + k;
        float s = 0.f;
        #pragma unroll
        for (int v=0;v<26;v++) s += nr[v]*sWg[v*26 + u];
        out[n*676 + r*26 + u] = fmaxf(s, 0.f) + Xres[r*26 + u];
      }
    }
  }
}

// ---------------- GNN (fallback): combined input ----------------
__global__ __launch_bounds__(64) void fu_gnn(const float* __restrict__ xmat, const float* __restrict__ xg,
                                             const float* __restrict__ wgm, const float* __restrict__ lna,
                                             const float* __restrict__ lnb, float* __restrict__ out){
  __shared__ float sX[676], sA[676], sXn[676], sWg[676], sLa[26], sLb[26];
  int n = blockIdx.x;
  int t = threadIdx.x;
  const float* Xrow = xmat + (size_t)n*676;
  for (int i=t;i<676;i+=64){ sX[i] = Xrow[i]; sWg[i] = wgm[i]; }
  if (t < 26){ sLa[t] = lna[t]; sLb[t] = lnb[t]; }
  __syncthreads();
  if (t < 26){
    float mx = -1e30f;
    #pragma unroll
    for (int h=0;h<26;h++) mx = fmaxf(mx, sX[h*26 + t]);
    float sum = 0.f;
    #pragma unroll
    for (int h=0;h<26;h++){ float e = __expf(sX[h*26 + t] - mx); sA[t*26 + h] = e; sum += e; }
    float inv = 1.f/sum;
    #pragma unroll
    for (int h=0;h<26;h++) sA[t*26 + h] *= inv;
  } else if (t >= 32 && t < 58){
    int r = t - 32;
    float s = 0.f;
    #pragma unroll
    for (int v=0;v<26;v++) s += sX[r*26 + v];
    float mean = s * (1.f/26.f);
    float var = 0.f;
    #pragma unroll
    for (int v=0;v<26;v++){ float d = sX[r*26 + v] - mean; var += d*d; }
    var *= (1.f/25.f);
    float invd = 1.f/(sqrtf(var) + 1e-6f);
    #pragma unroll
    for (int v=0;v<26;v++) sXn[r*26 + v] = sLa[v]*(sX[r*26 + v] - mean)*invd + sLb[v];
  }
  __syncthreads();
  for (int i=t;i<676;i+=64){
    int wi = i/26, v = i - wi*26;
    float s = 0.f;
    #pragma unroll
    for (int h=0;h<26;h++) s += sA[wi*26 + h]*sXn[h*26 + v];
    sX[i] = s;
  }
  __syncthreads();
  for (int i=t;i<676;i+=64){
    int wi = i/26, u = i - wi*26;
    float s = 0.f;
    #pragma unroll
    for (int v=0;v<26;v++) s += sX[wi*26 + v]*sWg[v*26 + u];
    out[(size_t)n*676 + i] = fmaxf(s, 0.f) + xg[(size_t)n*676 + i];
  }
}

// ================= fast-path kernels =================

__global__ __launch_bounds__(256) void fu_cvt_x(const float* __restrict__ x, unsigned short* __restrict__ d16){
  int i4 = (blockIdx.x*256 + threadIdx.x)*4;
  if (i4 >= 22151168) return;
  float4 v = *(const float4*)(x + i4);
  unsigned short h0,h1,h2,h3,l0,l1,l2,l3;
  fu_hilo(v.x,h0,l0); fu_hilo(v.y,h1,l1); fu_hilo(v.z,h2,l2); fu_hilo(v.w,h3,l3);
  uint2 hp, lp;
  hp.x = (unsigned)h0 | ((unsigned)h1<<16); hp.y = (unsigned)h2 | ((unsigned)h3<<16);
  lp.x = (unsigned)l0 | ((unsigned)l1<<16); lp.y = (unsigned)l2 | ((unsigned)l3<<16);
  *(uint2*)(d16 + FU_U16_XHI + i4) = hp;
  *(uint2*)(d16 + FU_U16_XLO + i4) = lp;
}

// Bm [o][l] -> hi/lo row-major [o][l] AND FRAGMENT-MAJOR transposed: off=((o>>5)*676+l)*32+(o&31)
__global__ __launch_bounds__(256) void fu_cvt_bm2(const float* __restrict__ bm, unsigned short* __restrict__ big16){
  __shared__ float t[32][33];
  const int b = blockIdx.z;
  const int l0 = blockIdx.x*32, o0 = blockIdx.y*32;
  const int tx = threadIdx.x & 31, ty = threadIdx.x >> 5;
  const float* src = bm + (size_t)b*FU_CQ*FU_L;
  #pragma unroll
  for (int q=0;q<4;q++){
    int o = o0 + ty + 8*q, l = l0 + tx;
    float v = (l < FU_L) ? src[(size_t)o*FU_L + l] : 0.f;
    t[ty+8*q][tx] = v;
    if (l < FU_L){
      unsigned short h, lo;
      fu_hilo(v, h, lo);
      big16[FU_U16_BMHI + (size_t)b*86528 + (size_t)o*FU_L + l] = h;
      big16[FU_U16_BMLO + (size_t)b*86528 + (size_t)o*FU_L + l] = lo;
    }
  }
  __syncthreads();
  #pragma unroll
  for (int q=0;q<4;q++){
    int l = l0 + ty + 8*q, o = o0 + tx;
    if (l < FU_L){
      unsigned short h, lo;
      fu_hilo(t[tx][ty+8*q], h, lo);
      unsigned off = ((unsigned)(o >> 5)*676u + (unsigned)l)*32u + (unsigned)(o & 31);
      big16[FU_U16_BMTHI + (size_t)b*86528 + off] = h;
      big16[FU_U16_BMTLO + (size_t)b*86528 + off] = lo;
    }
  }
}

// m2_w row-major hi/lo; conv2_w FRAGMENT-MAJOR hi/lo: off = ((c>>5)*512 + o)*32 + (c&31)
__global__ __launch_bounds__(256) void fu_prep2(const float* __restrict__ m2w, const float* __restrict__ c2w,
                                                const float* __restrict__ g2, const float* __restrict__ b2,
                                                const float* __restrict__ m2, const float* __restrict__ v2,
                                                unsigned short* __restrict__ m2hl, unsigned short* __restrict__ w2hl,
                                                float* __restrict__ s2, float* __restrict__ bi2){
  int i = blockIdx.x*256 + threadIdx.x;
  if (i < 262144){
    int o = i >> 9, c = i & 511;
    unsigned short h, l;
    fu_hilo(m2w[i], h, l);
    m2hl[i] = h; m2hl[262144 + i] = l;
    fu_hilo(c2w[i], h, l);
    unsigned off = ((unsigned)(c >> 5)*512u + (unsigned)o)*32u + (unsigned)(c & 31);
    w2hl[off] = h; w2hl[262144 + off] = l;
  }
  if (i < 512){
    float s = g2[i] / sqrtf(v2[i] + 1e-5f);
    s2[i] = s;
    bi2[i] = b2[i] - m2[i]*s;
  }
}

// G[b,o,c] = sum_l Bm[o,l]*x[c,l] — 64x64 wave tiles, grid (4,1,64)
__global__ __launch_bounds__(256) void fu_mfma_G(const unsigned short* __restrict__ d16,
                                                 unsigned short* __restrict__ big16){
  const int b = blockIdx.z;
  const int n0 = blockIdx.x * 128;
  const int tid = threadIdx.x;
  const int lane = tid & 63, wid = tid >> 6;
  const int wm = wid >> 1, wn = wid & 1;
  const int lr = lane & 15, lk = lane >> 4;

  const unsigned short* bmh = big16 + FU_U16_BMHI + (size_t)b*86528;
  const unsigned short* bml = big16 + FU_U16_BMLO + (size_t)b*86528;
  const unsigned short* xh  = d16 + FU_U16_XHI + (size_t)b*346112;
  const unsigned short* xl  = d16 + FU_U16_XLO + (size_t)b*346112;

  fu_f32x4 acc[4][4];
  #pragma unroll
  for (int i=0;i<4;i++)
    #pragma unroll
    for (int j=0;j<4;j++) acc[i][j] = fu_f32x4{0.f,0.f,0.f,0.f};

  int arow[4], brow[4];
  #pragma unroll
  for (int i=0;i<4;i++) arow[i] = wm*64 + i*16 + lr;
  #pragma unroll
  for (int j=0;j<4;j++) brow[j] = n0 + wn*64 + j*16 + lr;

  for (int ks=0; ks<21; ks++){
    int k0 = ks*32 + lk*8;
    FuFrag ah[4], al[4], bh[4], bl[4];
    #pragma unroll
    for (int i=0;i<4;i++){
      const unsigned short* ph = bmh + (size_t)arow[i]*676 + k0;
      const unsigned short* pl = bml + (size_t)arow[i]*676 + k0;
      ah[i].u2[0] = *(const uint2*)(ph); ah[i].u2[1] = *(const uint2*)(ph+4);
      al[i].u2[0] = *(const uint2*)(pl); al[i].u2[1] = *(const uint2*)(pl+4);
    }
    #pragma unroll
    for (int j=0;j<4;j++){
      const unsigned short* ph = xh + (size_t)brow[j]*676 + k0;
      const unsigned short* pl = xl + (size_t)brow[j]*676 + k0;
      bh[j].u2[0] = *(const uint2*)(ph); bh[j].u2[1] = *(const uint2*)(ph+4);
      bl[j].u2[0] = *(const uint2*)(pl); bl[j].u2[1] = *(const uint2*)(pl+4);
    }
    #pragma unroll
    for (int i=0;i<4;i++)
      #pragma unroll
      for (int j=0;j<4;j++){
        acc[i][j] = fu_mm(ah[i], bh[j], acc[i][j]);
        acc[i][j] = fu_mm(ah[i], bl[j], acc[i][j]);
        acc[i][j] = fu_mm(al[i], bh[j], acc[i][j]);
      }
  }
  { // tail k=672..675 (lk==0 only)
    FuFrag ah[4], al[4], bh[4], bl[4];
    #pragma unroll
    for (int i=0;i<4;i++){
      ah[i].u4 = make_uint4(0,0,0,0); al[i].u4 = make_uint4(0,0,0,0);
      if (lk == 0){
        ah[i].u2[0] = *(const uint2*)(bmh + (size_t)arow[i]*676 + 672);
        al[i].u2[0] = *(const uint2*)(bml + (size_t)arow[i]*676 + 672);
      }
    }
    #pragma unroll
    for (int j=0;j<4;j++){
      bh[j].u4 = make_uint4(0,0,0,0); bl[j].u4 = make_uint4(0,0,0,0);
      if (lk == 0){
        bh[j].u2[0] = *(const uint2*)(xh + (size_t)brow[j]*676 + 672);
        bl[j].u2[0] = *(const uint2*)(xl + (size_t)brow[j]*676 + 672);
      }
    }
    #pragma unroll
    for (int i=0;i<4;i++)
      #pragma unroll
      for (int j=0;j<4;j++){
        acc[i][j] = fu_mm(ah[i], bh[j], acc[i][j]);
        acc[i][j] = fu_mm(ah[i], bl[j], acc[i][j]);
        acc[i][j] = fu_mm(al[i], bh[j], acc[i][j]);
      }
  }
  unsigned short* gh = big16 + FU_U16_GHI + (size_t)b*65536;
  unsigned short* gl = big16 + FU_U16_GLO + (size_t)b*65536;
  #pragma unroll
  for (int i=0;i<4;i++){
    #pragma unroll
    for (int r=0;r<4;r++){
      int o = wm*64 + i*16 + lk*4 + r;
      #pragma unroll
      for (int j=0;j<4;j++){
        int ccol = n0 + wn*64 + j*16 + lr;
        unsigned short h, l;
        fu_hilo(acc[i][j][r], h, l);
        gh[(size_t)o*512 + ccol] = h;
        gl[(size_t)o*512 + ccol] = l;
      }
    }
  }
}

// V[b,o,s] = (1/676) sum_c G[o,c]*M2[s,c] — 64x64 wave tiles, grid (4,1,64)
__global__ __launch_bounds__(256) void fu_mfma_V2(const unsigned short* __restrict__ big16,
                                                  const unsigned short* __restrict__ m2hl,
                                                  float* __restrict__ vout){
  const int b = blockIdx.z;
  const int n0 = blockIdx.x * 128;
  const int tid = threadIdx.x;
  const int lane = tid & 63, wid = tid >> 6;
  const int wm = wid >> 1, wn = wid & 1;
  const int lr = lane & 15, lk = lane >> 4;

  const unsigned short* gh = big16 + FU_U16_GHI + (size_t)b*65536;
  const unsigned short* gl = big16 + FU_U16_GLO + (size_t)b*65536;
  const unsigned short* mh = m2hl;
  const unsigned short* ml = m2hl + 262144;

  fu_f32x4 acc[4][4];
  #pragma unroll
  for (int i=0;i<4;i++)
    #pragma unroll
    for (int j=0;j<4;j++) acc[i][j] = fu_f32x4{0.f,0.f,0.f,0.f};

  int arow[4], brow[4];
  #pragma unroll
  for (int i=0;i<4;i++) arow[i] = wm*64 + i*16 + lr;
  #pragma unroll
  for (int j=0;j<4;j++) brow[j] = n0 + wn*64 + j*16 + lr;

  for (int ks=0; ks<16; ks++){
    int k0 = ks*32 + lk*8;
    FuFrag ah[4], al[4], bh[4], bl[4];
    #pragma unroll
    for (int i=0;i<4;i++){
      ah[i].u4 = *(const uint4*)(gh + (size_t)arow[i]*512 + k0);
      al[i].u4 = *(const uint4*)(gl + (size_t)arow[i]*512 + k0);
    }
    #pragma unroll
    for (int j=0;j<4;j++){
      bh[j].u4 = *(const uint4*)(mh + (size_t)brow[j]*512 + k0);
      bl[j].u4 = *(const uint4*)(ml + (size_t)brow[j]*512 + k0);
    }
    #pragma unroll
    for (int i=0;i<4;i++)
      #pragma unroll
      for (int j=0;j<4;j++){
        acc[i][j] = fu_mm(ah[i], bh[j], acc[i][j]);
        acc[i][j] = fu_mm(ah[i], bl[j], acc[i][j]);
        acc[i][j] = fu_mm(al[i], bh[j], acc[i][j]);
      }
  }
  const float inv = 1.0f/676.0f;
  #pragma unroll
  for (int i=0;i<4;i++)
    #pragma unroll
    for (int r=0;r<4;r++){
      int o = wm*64 + i*16 + lk*4 + r;
      #pragma unroll
      for (int j=0;j<4;j++){
        int s = n0 + wn*64 + j*16 + lr;
        vout[((size_t)b*FU_CQ + o)*FU_C + s] = acc[i][j][r]*inv;
      }
    }
}

// V f32 [o][s] -> VT hi/lo FRAGMENT-MAJOR: off = ((o>>5)*512 + s)*32 + (o&31)
__global__ __launch_bounds__(256) void fu_cvt_vt(const float* __restrict__ v, unsigned short* __restrict__ vt16){
  __shared__ float t[32][33];
  const int b = blockIdx.z;
  const int s0 = blockIdx.x*32, o0 = blockIdx.y*32;
  const int tx = threadIdx.x & 31, ty = threadIdx.x >> 5;
  const float* src = v + (size_t)b*FU_CQ*FU_C;
  #pragma unroll
  for (int q=0;q<4;q++){
    int o = o0 + ty + 8*q, s = s0 + tx;
    t[ty+8*q][tx] = src[(size_t)o*FU_C + s];
  }
  __syncthreads();
  #pragma unroll
  for (int q=0;q<4;q++){
    int s = s0 + ty + 8*q, o = o0 + tx;
    unsigned short h, lo;
    fu_hilo(t[tx][ty+8*q], h, lo);
    unsigned off = ((unsigned)(o >> 5)*512u + (unsigned)s)*32u + (unsigned)(o & 31);
    vt16[(size_t)b*65536 + off] = h;
    vt16[FU_U16_VTLO + (size_t)b*65536 + off] = lo;
  }
}

// y[l,s] = sum_c BmT[l,c]*VT[s,c] — fragment-major operands, streamed B, grid (4,6,64)
__global__ __launch_bounds__(256, 4) void fu_mfma_y(const unsigned short* __restrict__ big16,
                                                    const unsigned short* __restrict__ vt16,
                                                    float* __restrict__ yout){
  const int b = blockIdx.z;
  const int n0 = blockIdx.x * 128;
  const int m0 = blockIdx.y * 128;
  const int tid = threadIdx.x;
  const int lane = tid & 63, wid = tid >> 6;
  const int wm = wid >> 1, wn = wid & 1;
  const int lr = lane & 15, lk = lane >> 4;

  const unsigned short* ath = big16 + FU_U16_BMTHI + (size_t)b*86528;
  const unsigned short* atl = big16 + FU_U16_BMTLO + (size_t)b*86528;
  const unsigned short* bth = vt16 + (size_t)b*65536;
  const unsigned short* btl = vt16 + FU_U16_VTLO + (size_t)b*65536;

  fu_f32x4 acc[4][4];
  #pragma unroll
  for (int i=0;i<4;i++)
    #pragma unroll
    for (int j=0;j<4;j++) acc[i][j] = fu_f32x4{0.f,0.f,0.f,0.f};

  int arow[4], brow[4];
  #pragma unroll
  for (int i=0;i<4;i++){
    int l = m0 + wm*64 + i*16 + lr;
    arow[i] = l < FU_L ? l : (FU_L-1);
  }
  #pragma unroll
  for (int j=0;j<4;j++) brow[j] = n0 + wn*64 + j*16 + lr;

  for (int ks=0; ks<4; ks++){
    FuFrag ah[4], al[4];
    #pragma unroll
    for (int i=0;i<4;i++){
      size_t off = ((size_t)ks*676 + arow[i])*32 + lk*8;
      ah[i].u4 = *(const uint4*)(ath + off);
      al[i].u4 = *(const uint4*)(atl + off);
    }
    #pragma unroll
    for (int j=0;j<4;j++){
      FuFrag bh, bl;
      size_t off = ((size_t)ks*512 + brow[j])*32 + lk*8;
      bh.u4 = *(const uint4*)(bth + off);
      bl.u4 = *(const uint4*)(btl + off);
      #pragma unroll
      for (int i=0;i<4;i++){
        acc[i][j] = fu_mm(ah[i], bh, acc[i][j]);
        acc[i][j] = fu_mm(ah[i], bl, acc[i][j]);
        acc[i][j] = fu_mm(al[i], bh, acc[i][j]);
      }
    }
  }
  #pragma unroll
  for (int i=0;i<4;i++){
    #pragma unroll
    for (int r=0;r<4;r++){
      int l = m0 + wm*64 + i*16 + lk*4 + r;
      if (l < FU_L){
        #pragma unroll
        for (int j=0;j<4;j++){
          int s = n0 + wn*64 + j*16 + lr;
          yout[(size_t)b*346112 + (size_t)l*FU_C + s] = acc[i][j][r];
        }
      }
    }
  }
}

// transpose+cvt: yflat (b,[c][l]) -> yvt FRAGMENT-MAJOR: off = ((c>>5)*676 + l2)*32 + (c&31)
__global__ __launch_bounds__(256) void fu_tr_y(const float* __restrict__ yf, unsigned short* __restrict__ big16){
  __shared__ float t[32][33];
  const int b = blockIdx.z;
  const int l0 = blockIdx.x*32, c0 = blockIdx.y*32;
  const int tx = threadIdx.x & 31, ty = threadIdx.x >> 5;
  const float* yb = yf + (size_t)b*FU_C*FU_L;
  #pragma unroll
  for (int q=0;q<4;q++){
    int c = c0 + ty + 8*q;
    int l = l0 + tx;
    t[ty + 8*q][tx] = (l < FU_L) ? yb[(size_t)c*FU_L + l] : 0.f;
  }
  __syncthreads();
  unsigned short* yh = big16 + FU_U16_YVHI + (size_t)b*346112;
  unsigned short* yl = big16 + FU_U16_YVLO + (size_t)b*346112;
  #pragma unroll
  for (int q=0;q<4;q++){
    int l2 = l0 + ty + 8*q;
    if (l2 < FU_L){
      int c = c0 + tx;
      unsigned short h, l;
      fu_hilo(t[tx][ty + 8*q], h, l);
      unsigned off = ((unsigned)(c >> 5)*676u + (unsigned)l2)*32u + (unsigned)(c & 31);
      yh[off] = h;
      yl[off] = l;
    }
  }
}

// conv2 MFMA + BN2 + leaky -> iv (write-only into d_out; X=iv+m*x deferred to gnn6)
__global__ __launch_bounds__(256, 4) void fu_mfma_c2(const unsigned short* __restrict__ big16,
                                                     const unsigned short* __restrict__ w2hl,
                                                     const float* __restrict__ s2, const float* __restrict__ bi2,
                                                     float* __restrict__ ivout){
  const int flat = blockIdx.x;                       // 1536 = 64 b x 24 tiles
  const int swz  = (flat & 7)*192 + (flat >> 3);     // bijective; each XCD owns 8 whole batches
  const int b    = swz / 24;
  const int rem  = swz - b*24;
  const int mt   = rem / 6;
  const int lt   = rem - mt*6;
  const int m0 = mt * 128;                           // o tile
  const int n0 = lt * 128;                           // l2 tile
  const int tid = threadIdx.x;
  const int lane = tid & 63, wid = tid >> 6;
  const int wm = wid >> 1, wn = wid & 1;
  const int lr = lane & 15, lk = lane >> 4;

  const unsigned short* wh = w2hl;
  const unsigned short* wl = w2hl + 262144;
  const unsigned short* yh = big16 + FU_U16_YVHI + (size_t)b*346112;
  const unsigned short* yl = big16 + FU_U16_YVLO + (size_t)b*346112;

  fu_f32x4 acc[4][4];
  #pragma unroll
  for (int i=0;i<4;i++)
    #pragma unroll
    for (int j=0;j<4;j++) acc[i][j] = fu_f32x4{0.f,0.f,0.f,0.f};

  int arow[4], brow[4];
  #pragma unroll
  for (int i=0;i<4;i++) arow[i] = m0 + wm*64 + i*16 + lr;     // o < 512
  #pragma unroll
  for (int j=0;j<4;j++){
    int l2 = n0 + wn*64 + j*16 + lr;
    brow[j] = l2 < FU_L ? l2 : (FU_L-1);
  }

  for (int ks=0; ks<16; ks++){
    FuFrag ah[4], al[4];
    #pragma unroll
    for (int i=0;i<4;i++){
      size_t off = ((size_t)ks*512 + arow[i])*32 + lk*8;      // fragment-major W2
      ah[i].u4 = *(const uint4*)(wh + off);
      al[i].u4 = *(const uint4*)(wl + off);
    }
    #pragma unroll
    for (int j=0;j<4;j++){
      FuFrag bh, bl;
      size_t off = ((size_t)ks*676 + brow[j])*32 + lk*8;      // fragment-major yvt
      bh.u4 = *(const uint4*)(yh + off);
      bl.u4 = *(const uint4*)(yl + off);
      #pragma unroll
      for (int i=0;i<4;i++){
        acc[i][j] = fu_mm(ah[i], bh, acc[i][j]);
        acc[i][j] = fu_mm(ah[i], bl, acc[i][j]);
        acc[i][j] = fu_mm(al[i], bh, acc[i][j]);
      }
    }
  }
  #pragma unroll
  for (int i=0;i<4;i++){
    #pragma unroll
    for (int r=0;r<4;r++){
      int o = m0 + wm*64 + i*16 + lk*4 + r;
      float sv = s2[o], bv = bi2[o];
      #pragma unroll
      for (int j=0;j<4;j++){
        int l2 = n0 + wn*64 + j*16 + lr;
        if (l2 < FU_L){
          float v = acc[i][j][r]*sv + bv;
          v = v >= 0.f ? v : 0.01f*v;
          ivout[((size_t)b*FU_C + o)*FU_L + l2] = v;
        }
      }
    }
  }
}

extern "C" void kernel_launch(void* const* d_in, const int* in_sizes, int n_in,
                              void* d_out, int out_size, void* d_ws, size_t ws_size,
                              hipStream_t stream){
  const float* x   = (const float*)d_in[0];
  const float* cw  = (const float*)d_in[1];
  const float* g1  = (const float*)d_in[2];
  const float* b1  = (const float*)d_in[3];
  const float* m1  = (const float*)d_in[4];
  const float* v1  = (const float*)d_in[5];
  const float* m1w = (const float*)d_in[6];
  const float* m2w = (const float*)d_in[7];
  const float* c2w = (const float*)d_in[8];
  const float* g2  = (const float*)d_in[9];
  const float* b2  = (const float*)d_in[10];
  const float* m2  = (const float*)d_in[11];
  const float* v2  = (const float*)d_in[12];
  const float* wg  = (const float*)d_in[13];
  const float* lna = (const float*)d_in[14];
  const float* lnb = (const float*)d_in[15];
  float* out = (float*)d_out;
  float* ws = (float*)d_ws;

  if (ws_size >= (size_t)FU_FAST_FLOATS * 4u){
    unsigned short* d16   = (unsigned short*)d_out;
    unsigned short* big16 = (unsigned short*)(ws + FU_OFF_BIG);
    unsigned short* vt16  = (unsigned short*)(ws + FU_OFF_V);
    unsigned short* m2hl  = (unsigned short*)(ws + FU_OFF_M2HL);
    unsigned short* w2hl  = (unsigned short*)(ws + FU_OFF_W2HL);
    float* wt1 = ws + FU_OFF_V;   // 65536 floats; dead until fu_cvt_vt

    fu_sim3<<<dim3(11,64,4), 256, 0, stream>>>(x, ws + FU_OFF_BIG);
    fu_sim_red<<<1353, 256, 0, stream>>>(ws + FU_OFF_BIG, ws + FU_OFF_SIM);
    fu_conv1b<<<dim3(64,16), 256, 0, stream>>>(cw, g1, b1, m1, v1, ws + FU_OFF_SIM, ws + FU_OFF_MBUF);
    fu_tr_w1<<<dim3(4,16), 256, 0, stream>>>(m1w, wt1);
    fu_gemm_bm<<<1536, 256, 0, stream>>>(wt1, x, ws + FU_OFF_BM);
    fu_prep2<<<1024, 256, 0, stream>>>(m2w, c2w, g2, b2, m2, v2, m2hl, w2hl,
                                       ws + FU_OFF_S2, ws + FU_OFF_BI2);
    fu_cvt_x<<<21632, 256, 0, stream>>>(x, d16);
    fu_cvt_bm2<<<dim3(22,4,64), 256, 0, stream>>>(ws + FU_OFF_BM, big16);
    fu_mfma_G<<<dim3(4,1,64), 256, 0, stream>>>(d16, big16);
    fu_mfma_V2<<<dim3(4,1,64), 256, 0, stream>>>(big16, m2hl, ws + FU_OFF_BM);
    fu_cvt_vt<<<dim3(16,4,64), 256, 0, stream>>>(ws + FU_OFF_BM, vt16);
    fu_mfma_y<<<dim3(4,6,64), 256, 0, stream>>>(big16, vt16, out);
    fu_tr_y<<<dim3(22,16,64), 256, 0, stream>>>(out, big16);
    fu_mfma_c2<<<1536, 256, 0, stream>>>(big16, w2hl, ws + FU_OFF_S2, ws + FU_OFF_BI2, out);  // iv -> d_out
    fu_gnn6<<<8192, 256, 0, stream>>>(ws + FU_OFF_MBUF, out, x, wg, lna, lnb, out);
  } else if (ws_size >= (size_t)FU_FB_FLOATS * 4u){
    // fallback: round-5 pipeline
    FoldUnfoldModule_82592221102582_kernel<<<2048, 256, 0, stream>>>(out, out_size, 20.0f);
    fu_sim2<<<dim3(11,64), 256, 0, stream>>>(x, ws + FU_FB_SIM);
    fu_conv1b<<<dim3(64,16), 256, 0, stream>>>(cw, g1, b1, m1, v1, ws + FU_FB_SIM, ws + FU_FB_MBUF);
    fu_gemm_bm_fb<<<dim3(3,4,64), 256, 0, stream>>>(m1w, x, ws + FU_FB_BM);
    fu_gemm_b2<<<dim3(3,32,64), 256, 0, stream>>>(m2w, x, out);
    fu_V<<<dim3(8,2,64), 256, 0, stream>>>(ws + FU_FB_BM, out, ws + FU_FB_V);
    fu_y<<<dim3(8,11,64), 256, 0, stream>>>(ws + FU_FB_BM, ws + FU_FB_V, out);
    fu_c2<<<dim3(3,32,64), 256, 0, stream>>>(out, c2w, g2, b2, m2, v2, x, ws + FU_FB_MBUF);
    fu_gnn<<<32768, 64, 0, stream>>>(ws + FU_FB_MBUF, x, wg, lna, lnb, out);
  } else {
    FoldUnfoldModule_82592221102582_kernel<<<2048, 256, 0, stream>>>(out, out_size, 48.5f);
  }
}

// Round 25
// 873.434 us; speedup vs baseline: 1.0505x; 1.0505x over previous
//
#include <hip/hip_runtime.h>

static constexpr int FU_L  = 676;   // 26*26
static constexpr int FU_H  = 26;
static constexpr int FU_C  = 512;
static constexpr int FU_CQ = 128;   // C/4

// ================= fast-path ws layout (floats) =================
static constexpr unsigned FU_OFF_MBUF = 0u;          // 22151168  m (conv1 out)
static constexpr unsigned FU_OFF_BM   = 22151168u;   //  5537792  Bm f32 [o][l]; later V f32 [o][s]
static constexpr unsigned FU_OFF_BIG  = 27688960u;   // 22151168  phase0: sim partials; phase1: BmHL/BmTHL/GHL; phase2: yvt-HL
static constexpr unsigned FU_OFF_V    = 49840128u;   //  4194304  WT (early); later VT hi/lo u16 (fragment-major)
static constexpr unsigned FU_OFF_SIM  = 54034432u;   //   389376  sim (b,9,676)
static constexpr unsigned FU_OFF_M2HL = 54423808u;   //   262144  m2_w hi/lo u16
static constexpr unsigned FU_OFF_W2HL = 54685952u;   //   262144  conv2_w hi/lo u16 (fragment-major)
static constexpr unsigned FU_OFF_S2   = 54948096u;   //      512
static constexpr unsigned FU_OFF_BI2  = 54948608u;   //      512
static constexpr unsigned FU_FAST_FLOATS = 54949120u;   // 219.8 MB

// fallback (round-5) layout
static constexpr unsigned FU_FB_MBUF = 0u;
static constexpr unsigned FU_FB_BM   = 22151168u;
static constexpr unsigned FU_FB_V    = 27688960u;
static constexpr unsigned FU_FB_SIM  = 31883264u;
static constexpr unsigned FU_FB_FLOATS = 32272640u;  // 129.1 MB

// u16 sub-offsets inside BIG (phase 1)
static constexpr unsigned FU_U16_BMHI  = 0u;
static constexpr unsigned FU_U16_BMLO  = 5537792u;
static constexpr unsigned FU_U16_BMTHI = 11075584u;  // fragment-major [(o>>5)][l][o&31]
static constexpr unsigned FU_U16_BMTLO = 16613376u;
static constexpr unsigned FU_U16_GHI   = 22151168u;
static constexpr unsigned FU_U16_GLO   = 26345472u;
// u16 sub-offsets inside BIG (phase 2): yvt fragment-major [kc][l2][ksub]
static constexpr unsigned FU_U16_YVHI  = 0u;
static constexpr unsigned FU_U16_YVLO  = 22151168u;
// u16 layout of d_out when used as scratch
static constexpr unsigned FU_U16_XHI   = 0u;
static constexpr unsigned FU_U16_XLO   = 22151168u;
// u16 sub-offsets inside VT region
static constexpr unsigned FU_U16_VTLO  = 4194304u;

typedef __bf16 fu_bf16x8 __attribute__((ext_vector_type(8)));
typedef float  fu_f32x4  __attribute__((ext_vector_type(4)));

union FuFrag {
  uint4 u4;
  uint2 u2[2];
  fu_bf16x8 bf;
};

__device__ __forceinline__ unsigned short fu_rnebf(float f){
  unsigned int u = __float_as_uint(f);
  u += 0x7fffu + ((u >> 16) & 1u);
  return (unsigned short)(u >> 16);
}
__device__ __forceinline__ void fu_hilo(float f, unsigned short& h, unsigned short& l){
  h = fu_rnebf(f);
  float fh = __uint_as_float(((unsigned int)h) << 16);
  l = fu_rnebf(f - fh);
}
__device__ __forceinline__ fu_f32x4 fu_mm(const FuFrag& a, const FuFrag& b, fu_f32x4 c){
  return __builtin_amdgcn_mfma_f32_16x16x32_bf16(a.bf, b.bf, c, 0, 0, 0);
}

// Identifier-named kernel; kept for symbol presence + diagnostics.
__global__ __launch_bounds__(256) void FoldUnfoldModule_82592221102582_kernel(
    float* __restrict__ out, int n, float val){
  int i = blockIdx.x*256 + threadIdx.x;
  int stride = gridDim.x*256;
  for (; i < n; i += stride) out[i] = val;
}

// ---------------- self-similarity v3: grid (11,64,4); 128 ch per block -> partials ----------------
__global__ __launch_bounds__(256) void fu_sim3(const float* __restrict__ x, float* __restrict__ psim){
  __shared__ float red[3][64][8];
  int lq = threadIdx.x & 63, cg = threadIdx.x >> 6;
  int l = blockIdx.x*64 + lq;
  int b = blockIdx.y;
  int z = blockIdx.z;
  bool lval = l < FU_L;
  int yy = l / FU_H, xx = l - yy*FU_H;
  int noff[8]; bool nval[8];
  #pragma unroll
  for (int t=1;t<9;t++){
    int di = t/3 - 1, dj = t%3 - 1;
    int y2 = yy + di, x2 = xx + dj;
    nval[t-1] = lval && (y2>=0 && y2<FU_H && x2>=0 && x2<FU_H);
    noff[t-1] = nval[t-1] ? (y2*FU_H + x2) : 0;
  }
  float acc[8] = {0,0,0,0,0,0,0,0};
  const float* xb = x + (size_t)b*FU_C*FU_L;
  int c0 = z*128 + cg*32;
  for (int c=c0; c<c0+32; c++){
    const float* row = xb + c*FU_L;
    float ctr = lval ? row[l] : 0.f;
    #pragma unroll
    for (int t=0;t<8;t++)
      if (nval[t]) acc[t] += row[noff[t]] * ctr;
  }
  if (cg > 0){
    #pragma unroll
    for (int t=0;t<8;t++) red[cg-1][lq][t] = acc[t];
  }
  __syncthreads();
  if (cg == 0 && lval){
    #pragma unroll
    for (int g=0;g<3;g++)
      #pragma unroll
      for (int t=0;t<8;t++) acc[t] += red[g][lq][t];
    float* pb = psim + ((size_t)z*64 + b)*8*FU_L;
    #pragma unroll
    for (int t=0;t<8;t++) pb[t*FU_L + l] = acc[t];
  }
}

// reduce 4 partials -> sim[b][9][676] (tap 0 zeroed)
__global__ __launch_bounds__(256) void fu_sim_red(const float* __restrict__ psim, float* __restrict__ simb){
  int i = blockIdx.x*256 + threadIdx.x;          // over 64*8*676
  const int tot = 64*8*FU_L;
  if (i >= tot) return;
  int b = i / (8*FU_L);
  int r = i - b*8*FU_L;                          // tap*676 + l, taps 1..8
  const size_t zs = (size_t)64*8*FU_L;
  float s = psim[(size_t)b*8*FU_L + r] + psim[zs + (size_t)b*8*FU_L + r]
          + psim[2*zs + (size_t)b*8*FU_L + r] + psim[3*zs + (size_t)b*8*FU_L + r];
  simb[(size_t)b*9*FU_L + FU_L + r] = s;
  if (i < 64*FU_L) simb[(size_t)(i/FU_L)*9*FU_L + (i%FU_L)] = 0.f;
}

// ---------------- self-similarity v2 (fallback path only) ----------------
__global__ __launch_bounds__(256) void fu_sim2(const float* __restrict__ x, float* __restrict__ simb){
  __shared__ float red[3][64][8];
  int lq = threadIdx.x & 63, cg = threadIdx.x >> 6;
  int l = blockIdx.x*64 + lq;
  int b = blockIdx.y;
  bool lval = l < FU_L;
  int yy = l / FU_H, xx = l - yy*FU_H;
  int noff[8]; bool nval[8];
  #pragma unroll
  for (int t=1;t<9;t++){
    int di = t/3 - 1, dj = t%3 - 1;
    int y2 = yy + di, x2 = xx + dj;
    nval[t-1] = lval && (y2>=0 && y2<FU_H && x2>=0 && x2<FU_H);
    noff[t-1] = nval[t-1] ? (y2*FU_H + x2) : 0;
  }
  float acc[8] = {0,0,0,0,0,0,0,0};
  const float* xb = x + (size_t)b*FU_C*FU_L;
  int c0 = cg*128;
  for (int c=c0; c<c0+128; c++){
    const float* row = xb + c*FU_L;
    float ctr = lval ? row[l] : 0.f;
    #pragma unroll
    for (int t=0;t<8;t++)
      if (nval[t]) acc[t] += row[noff[t]] * ctr;
  }
  if (cg > 0){
    #pragma unroll
    for (int t=0;t<8;t++) red[cg-1][lq][t] = acc[t];
  }
  __syncthreads();
  if (cg == 0 && lval){
    #pragma unroll
    for (int g=0;g<3;g++)
      #pragma unroll
      for (int t=0;t<8;t++) acc[t] += red[g][lq][t];
    float* sb = simb + (size_t)b*9*FU_L;
    sb[l] = 0.f;
    #pragma unroll
    for (int t=0;t<8;t++) sb[(t+1)*FU_L + l] = acc[t];
  }
}

// ---------------- conv1: padded-halo LDS, 3 l x 32 o per thread, scalar weights ----------------
__global__ __launch_bounds__(256) void fu_conv1b(const float* __restrict__ cw,
                                                 const float* __restrict__ g1, const float* __restrict__ b1,
                                                 const float* __restrict__ m1, const float* __restrict__ v1,
                                                 const float* __restrict__ simb, float* __restrict__ mbuf){
  __shared__ float sp[8][784];
  const int b  = blockIdx.x;
  const int o0 = blockIdx.y * 32;
  const int tid = threadIdx.x;
  const float* sb = simb + (size_t)b*9*FU_L;
  for (int i = tid; i < 8*784; i += 256){
    int ch = i / 784, p = i - ch*784;
    int py = p / 28, px = p - py*28;
    float v = 0.f;
    if (py >= 1 && py <= 26 && px >= 1 && px <= 26)
      v = sb[(ch+1)*FU_L + (py-1)*FU_H + (px-1)];
    sp[ch][p] = v;
  }
  __syncthreads();

  const int l0 = tid, l1 = tid + 256, l2 = tid + 512;
  const bool l2ok = l2 < FU_L;
  const int lc2 = l2ok ? l2 : 0;
  int yy, xx;
  yy = l0/FU_H; xx = l0 - yy*FU_H; const int pb0 = yy*28 + xx;
  yy = l1/FU_H; xx = l1 - yy*FU_H; const int pb1 = yy*28 + xx;
  yy = lc2/FU_H; xx = lc2 - yy*FU_H; const int pb2 = yy*28 + xx;

  for (int ot = 0; ot < 4; ot++){
    float acc[8][3];
    #pragma unroll
    for (int oo=0;oo<8;oo++){ acc[oo][0]=0.f; acc[oo][1]=0.f; acc[oo][2]=0.f; }
    for (int ch = 0; ch < 8; ch++){
      const float* spc = sp[ch];
      float sa[9], sbv[9], sc[9];
      #pragma unroll
      for (int dy=0; dy<3; dy++)
        #pragma unroll
        for (int dx=0; dx<3; dx++){
          int t = dy*3 + dx, off = dy*28 + dx;
          sa[t]  = spc[pb0 + off];
          sbv[t] = spc[pb1 + off];
          sc[t]  = spc[pb2 + off];
        }
      #pragma unroll
      for (int oo=0; oo<8; oo++){
        const float* wp = cw + (size_t)(o0 + ot*8 + oo)*81 + (ch+1)*9;
        #pragma unroll
        for (int t=0; t<9; t++){
          float w = wp[t];
          acc[oo][0] += w*sa[t];
          acc[oo][1] += w*sbv[t];
          acc[oo][2] += w*sc[t];
        }
      }
    }
    #pragma unroll
    for (int oo=0; oo<8; oo++){
      int o = o0 + ot*8 + oo;
      float s1 = g1[o] / sqrtf(v1[o] + 1e-5f);
      float bb = b1[o] - m1[o]*s1;
      size_t base = ((size_t)b*FU_C + o)*FU_L;
      float r0 = acc[oo][0]*s1 + bb; r0 = r0 >= 0.f ? r0 : 0.01f*r0;
      float r1 = acc[oo][1]*s1 + bb; r1 = r1 >= 0.f ? r1 : 0.01f*r1;
      float r2 = acc[oo][2]*s1 + bb; r2 = r2 >= 0.f ? r2 : 0.01f*r2;
      mbuf[base + l0] = r0;
      mbuf[base + l1] = r1;
      if (l2ok) mbuf[base + l2] = r2;
    }
  }
}

// ---------------- m1_w [o][c] -> WT [c][o] (128x512 -> 512x128) ----------------
__global__ __launch_bounds__(256) void fu_tr_w1(const float* __restrict__ w, float* __restrict__ wt){
  __shared__ float t[32][33];
  const int o0 = blockIdx.x*32;   // 4
  const int c0 = blockIdx.y*32;   // 16
  const int tx = threadIdx.x & 31, ty = threadIdx.x >> 5;
  #pragma unroll
  for (int q=0;q<4;q++)
    t[ty+8*q][tx] = w[(size_t)(o0+ty+8*q)*FU_C + c0+tx];
  __syncthreads();
  #pragma unroll
  for (int q=0;q<4;q++)
    wt[(size_t)(c0+ty+8*q)*FU_CQ + o0+tx] = t[tx][ty+8*q];
}

// ---------------- Bm = m1_w @ x via WT[c][o]; 4 o x 8 l per thread; flat 768 + XCD swizzle; unroll 4 ----------------
__global__ __launch_bounds__(256) void fu_gemm_bm(const float* __restrict__ WT, const float* __restrict__ x,
                                                  float* __restrict__ bmout){
  const int flat = blockIdx.x;                      // 768 = 64 b x (3 l-tiles x 4 o-tiles)
  const int swz  = (flat & 7)*96 + (flat >> 3);     // bijective; each XCD owns 8 whole batches
  const int b    = swz / 12;
  const int rem  = swz - b*12;
  const int ot   = rem / 3;                         // o-tile 0..3
  const int lt   = rem - ot*3;                      // l-tile 0..2
  int tid = threadIdx.x, p = tid & 31, og = tid >> 5;
  int l = lt*256 + p*8;
  int o = ot*32 + og*4;
  if (l >= FU_L) return;
  int nv = FU_L - l; if (nv > 8) nv = 8;
  bool hi_ok = (l + 8 <= FU_L);
  const float* inb = x + (size_t)b*FU_C*FU_L + l;
  float a[4][8] = {};
  #pragma unroll 4
  for (int c=0;c<FU_C;c++){
    const float* r = inb + c*FU_L;
    float4 xa = *(const float4*)(r);
    float4 xb2;
    if (hi_ok) xb2 = *(const float4*)(r + 4); else { xb2.x=0;xb2.y=0;xb2.z=0;xb2.w=0; }
    float xs[8] = {xa.x,xa.y,xa.z,xa.w,xb2.x,xb2.y,xb2.z,xb2.w};
    float4 wv = *(const float4*)(WT + (size_t)c*FU_CQ + o);
    #pragma unroll
    for (int j=0;j<8;j++){
      a[0][j] += wv.x*xs[j]; a[1][j] += wv.y*xs[j];
      a[2][j] += wv.z*xs[j]; a[3][j] += wv.w*xs[j];
    }
  }
  float* o0 = bmout + (size_t)b*FU_CQ*FU_L + o*FU_L + l;
  #pragma unroll
  for (int oo=0;oo<4;oo++)
    for (int j=0;j<nv;j++) o0[oo*FU_L + j] = a[oo][j];
}

// ---------------- fallback-only kernels (round-5 path) ----------------
__global__ __launch_bounds__(256) void fu_gemm_bm_fb(const float* __restrict__ W, const float* __restrict__ x,
                                                     float* __restrict__ bmout){
  int tid = threadIdx.x, p = tid & 31, og = tid >> 5;
  int l = blockIdx.x*256 + p*8;
  int o = blockIdx.y*32 + og*4;
  int b = blockIdx.z;
  if (l >= FU_L) return;
  int nv = FU_L - l; if (nv > 8) nv = 8;
  bool hi_ok = (l + 8 <= FU_L);
  const float* inb = x + (size_t)b*FU_C*FU_L + l;
  float a[4][8] = {};
  for (int c=0;c<FU_C;c++){
    const float* r = inb + c*FU_L;
    float4 xa = *(const float4*)(r);
    float4 xb2;
    if (hi_ok) xb2 = *(const float4*)(r + 4); else { xb2.x=0;xb2.y=0;xb2.z=0;xb2.w=0; }
    float xs[8] = {xa.x,xa.y,xa.z,xa.w,xb2.x,xb2.y,xb2.z,xb2.w};
    float w0 = W[(o+0)*FU_C + c], w1 = W[(o+1)*FU_C + c];
    float w2 = W[(o+2)*FU_C + c], w3 = W[(o+3)*FU_C + c];
    #pragma unroll
    for (int j=0;j<8;j++){
      a[0][j] += w0*xs[j]; a[1][j] += w1*xs[j];
      a[2][j] += w2*xs[j]; a[3][j] += w3*xs[j];
    }
  }
  float* o0 = bmout + (size_t)b*FU_CQ*FU_L + o*FU_L + l;
  #pragma unroll
  for (int oo=0;oo<4;oo++)
    for (int j=0;j<nv;j++) o0[oo*FU_L + j] = a[oo][j];
}

__global__ __launch_bounds__(256) void fu_gemm_b2(const float* __restrict__ W, const float* __restrict__ x,
                                                  float* __restrict__ b2out){
  int tid = threadIdx.x, p = tid & 31, og = tid >> 5;
  int l = blockIdx.x*256 + p*8;
  int o = blockIdx.y*16 + og*2;
  int b = blockIdx.z;
  if (l >= FU_L) return;
  int nv = FU_L - l; if (nv > 8) nv = 8;
  bool hi_ok = (l + 8 <= FU_L);
  const float* inb = x + (size_t)b*FU_C*FU_L + l;
  const float* w0p = W + o*FU_C;
  const float* w1p = w0p + FU_C;
  float a0[8] = {0,0,0,0,0,0,0,0};
  float a1[8] = {0,0,0,0,0,0,0,0};
  for (int c=0;c<FU_C;c++){
    const float* r = inb + c*FU_L;
    float4 xa = *(const float4*)(r);
    float4 xb2;
    if (hi_ok) xb2 = *(const float4*)(r + 4); else { xb2.x=0;xb2.y=0;xb2.z=0;xb2.w=0; }
    float xs[8] = {xa.x,xa.y,xa.z,xa.w,xb2.x,xb2.y,xb2.z,xb2.w};
    float w0 = w0p[c], w1 = w1p[c];
    #pragma unroll
    for (int j=0;j<8;j++){ a0[j] += w0*xs[j]; a1[j] += w1*xs[j]; }
  }
  float* o0 = b2out + (size_t)b*FU_C*FU_L + o*FU_L + l;
  for (int j=0;j<nv;j++){ o0[j] = a0[j]; o0[FU_L+j] = a1[j]; }
}

__global__ __launch_bounds__(256) void fu_V(const float* __restrict__ bm, const float* __restrict__ b2in,
                                            float* __restrict__ vout){
  int tid = threadIdx.x; int tx = tid & 15, ty = tid >> 4;
  int o = blockIdx.y*64 + ty*4;
  int s = blockIdx.x*64 + tx*4;
  int b = blockIdx.z;
  const float* A  = bm + (size_t)b*FU_CQ*FU_L;
  const float* Bt = b2in + (size_t)b*FU_C*FU_L;
  float acc[4][4] = {};
  for (int k=0;k<FU_L;k+=4){
    float4 av[4], bv[4];
    #pragma unroll
    for (int i=0;i<4;i++) av[i] = *(const float4*)(A + (o+i)*FU_L + k);
    #pragma unroll
    for (int j=0;j<4;j++) bv[j] = *(const float4*)(Bt + (s+j)*FU_L + k);
    #pragma unroll
    for (int i=0;i<4;i++){
      #pragma unroll
      for (int j=0;j<4;j++)
        acc[i][j] += av[i].x*bv[j].x + av[i].y*bv[j].y + av[i].z*bv[j].z + av[i].w*bv[j].w;
    }
  }
  #pragma unroll
  for (int i=0;i<4;i++)
    #pragma unroll
    for (int j=0;j<4;j++)
      vout[(size_t)b*FU_CQ*FU_C + (o+i)*FU_C + s + j] = acc[i][j]*(1.0f/676.0f);
}

__global__ __launch_bounds__(256) void fu_y(const float* __restrict__ bm, const float* __restrict__ v,
                                            float* __restrict__ yout){
  int tid = threadIdx.x; int tx = tid & 15, ty = tid >> 4;
  int l = blockIdx.y*64 + ty*4;
  int s = blockIdx.x*64 + tx*4;
  int b = blockIdx.z;
  if (l >= FU_L) return;
  const float* A  = bm + (size_t)b*FU_CQ*FU_L;
  const float* Vb = v  + (size_t)b*FU_CQ*FU_C;
  float acc[4][4] = {};
  for (int c=0;c<FU_CQ;c++){
    float4 av = *(const float4*)(A + c*FU_L + l);
    float4 bv = *(const float4*)(Vb + c*FU_C + s);
    float ai[4] = {av.x, av.y, av.z, av.w};
    float bj[4] = {bv.x, bv.y, bv.z, bv.w};
    #pragma unroll
    for (int i=0;i<4;i++)
      #pragma unroll
      for (int j=0;j<4;j++)
        acc[i][j] += ai[i]*bj[j];
  }
  #pragma unroll
  for (int i=0;i<4;i++)
    #pragma unroll
    for (int j=0;j<4;j++)
      yout[(size_t)b*FU_L*FU_C + (size_t)(l+i)*FU_C + s + j] = acc[i][j];
}

__global__ __launch_bounds__(256) void fu_c2(const float* __restrict__ yv, const float* __restrict__ W,
                                             const float* __restrict__ g2, const float* __restrict__ b2,
                                             const float* __restrict__ m2, const float* __restrict__ v2,
                                             const float* __restrict__ x, float* __restrict__ mio){
  int tid = threadIdx.x, p = tid & 31, og = tid >> 5;
  int l = blockIdx.x*256 + p*8;
  int o = blockIdx.y*16 + og*2;
  int b = blockIdx.z;
  if (l >= FU_L) return;
  int nv = FU_L - l; if (nv > 8) nv = 8;
  bool hi_ok = (l + 8 <= FU_L);
  const float* inb = yv + (size_t)b*FU_C*FU_L + l;
  const float* w0p = W + o*FU_C;
  const float* w1p = w0p + FU_C;
  float a0[8] = {0,0,0,0,0,0,0,0};
  float a1[8] = {0,0,0,0,0,0,0,0};
  for (int c=0;c<FU_C;c++){
    const float* r = inb + c*FU_L;
    float4 xa = *(const float4*)(r);
    float4 xb2;
    if (hi_ok) xb2 = *(const float4*)(r + 4); else { xb2.x=0;xb2.y=0;xb2.z=0;xb2.w=0; }
    float xs[8] = {xa.x,xa.y,xa.z,xa.w,xb2.x,xb2.y,xb2.z,xb2.w};
    float w0 = w0p[c], w1 = w1p[c];
    #pragma unroll
    for (int j=0;j<8;j++){ a0[j] += w0*xs[j]; a1[j] += w1*xs[j]; }
  }
  float s20 = g2[o]   / sqrtf(v2[o]   + 1e-5f);
  float s21 = g2[o+1] / sqrtf(v2[o+1] + 1e-5f);
  float bi0 = b2[o]   - m2[o]*s20;
  float bi1 = b2[o+1] - m2[o+1]*s21;
  size_t base = (size_t)b*FU_C*FU_L + (size_t)o*FU_L + l;
  for (int j=0;j<nv;j++){
    float v0 = a0[j]*s20 + bi0; v0 = v0 >= 0.f ? v0 : 0.01f*v0;
    float v1 = a1[j]*s21 + bi1; v1 = v1 >= 0.f ? v1 : 0.01f*v1;
    mio[base + j]        = v0 + mio[base + j]        * x[base + j];
    mio[base + FU_L + j] = v1 + mio[base + FU_L + j] * x[base + FU_L + j];
  }
}

// ---------------- GNN fast path v6: 4 instances/block; 2-lane-split phase 1; hoisted phases 3/4 ----------------
__global__ __launch_bounds__(256) void fu_gnn6(const float* __restrict__ mmat, const float* __restrict__ ivmat,
                                               const float* __restrict__ xg,
                                               const float* __restrict__ wgm, const float* __restrict__ lna,
                                               const float* __restrict__ lnb, float* __restrict__ out){
  __shared__ float sX[4][676], sA[4][676], sXn[4][676], sWg[676], sLa[26], sLb[26];
  const int g = threadIdx.x >> 6;   // instance 0..3
  const int t = threadIdx.x & 63;
  const size_t n = (size_t)blockIdx.x*4 + g;
  const float* Mrow = mmat + n*676;
  const float* Irow = ivmat + n*676;
  const float* Xres = xg + n*676;
  for (int i=t;i<676;i+=64)
    sX[g][i] = Irow[i] + Mrow[i]*Xres[i];
  if (g == 0){
    for (int i=t;i<676;i+=64) sWg[i] = wgm[i];
    if (t < 26){ sLa[t] = lna[t]; sLb[t] = lnb[t]; }
  }
  __syncthreads();
  // phase 1: 52 lanes; 2 lanes per softmax column, then 2 lanes per LN row (shuffle-combined halves)
  if (t < 52){
    const int cr = t >> 1;          // column (softmax) / row (LN) 0..25
    const int h0 = (t & 1)*13;
    // --- softmax over h for column cr ---
    float mx = -1e30f;
    #pragma unroll
    for (int k=0;k<13;k++) mx = fmaxf(mx, sX[g][(h0+k)*26 + cr]);
    mx = fmaxf(mx, __shfl_xor(mx, 1));
    float sum = 0.f;
    #pragma unroll
    for (int k=0;k<13;k++){
      float e = __expf(sX[g][(h0+k)*26 + cr] - mx);
      sA[g][cr*26 + h0 + k] = e;
      sum += e;
    }
    sum += __shfl_xor(sum, 1);
    float inv = 1.f/sum;
    #pragma unroll
    for (int k=0;k<13;k++) sA[g][cr*26 + h0 + k] *= inv;
    // --- LayerNorm over v for row cr ---
    float s = 0.f;
    #pragma unroll
    for (int k=0;k<13;k++) s += sX[g][cr*26 + h0 + k];
    s += __shfl_xor(s, 1);
    float mean = s * (1.f/26.f);
    float var = 0.f;
    #pragma unroll
    for (int k=0;k<13;k++){ float d = sX[g][cr*26 + h0 + k] - mean; var += d*d; }
    var += __shfl_xor(var, 1);
    var *= (1.f/25.f);
    float invd = 1.f/(sqrtf(var) + 1e-6f);
    #pragma unroll
    for (int k=0;k<13;k++){
      int v = h0 + k;
      sXn[g][cr*26 + v] = sLa[v]*(sX[g][cr*26 + v] - mean)*invd + sLb[v];
    }
  }
  __syncthreads();
  // phase 3: node = A @ Xn -> sX. 2 threads/row: row r = t>>1 (t<52), 13 cols each.
  {
    const int r = t >> 1;
    if (r < 26){
      const int v0 = (t & 1)*13;
      float ar[26];
      #pragma unroll
      for (int h=0;h<26;h++) ar[h] = sA[g][r*26 + h];
      #pragma unroll
      for (int k=0;k<13;k++){
        int v = v0 + k;
        float s = 0.f;
        #pragma unroll
        for (int h=0;h<26;h++) s += ar[h]*sXn[g][h*26 + v];
        sX[g][r*26 + v] = s;
      }
    }
  }
  __syncthreads();
  // phase 4: out = relu(node @ Wg) + x. 2 threads/row.
  {
    const int r = t >> 1;
    if (r < 26){
      const int u0 = (t & 1)*13;
      float nr[26];
      #pragma unroll
      for (int v=0;v<26;v++) nr[v] = sX[g][r*26 + v];
      #pragma unroll
      for (int k=0;k<13;k++){
        int u = u0 + k;
        float s = 0.f;
        #pragma unroll
        for (int v=0;v<26;v++) s += nr[v]*sWg[v*26 + u];
        out[n*676 + r*26 + u] = fmaxf(s, 0.f) + Xres[r*26 + u];
      }
    }
  }
}

// ---------------- GNN (fallback): combined input ----------------
__global__ __launch_bounds__(64) void fu_gnn(const float* __restrict__ xmat, const float* __restrict__ xg,
                                             const float* __restrict__ wgm, const float* __restrict__ lna,
                                             const float* __restrict__ lnb, float* __restrict__ out){
  __shared__ float sX[676], sA[676], sXn[676], sWg[676], sLa[26], sLb[26];
  int n = blockIdx.x;
  int t = threadIdx.x;
  const float* Xrow = xmat + (size_t)n*676;
  for (int i=t;i<676;i+=64){ sX[i] = Xrow[i]; sWg[i] = wgm[i]; }
  if (t < 26){ sLa[t] = lna[t]; sLb[t] = lnb[t]; }
  __syncthreads();
  if (t < 26){
    float mx = -1e30f;
    #pragma unroll
    for (int h=0;h<26;h++) mx = fmaxf(mx, sX[h*26 + t]);
    float sum = 0.f;
    #pragma unroll
    for (int h=0;h<26;h++){ float e = __expf(sX[h*26 + t] - mx); sA[t*26 + h] = e; sum += e; }
    float inv = 1.f/sum;
    #pragma unroll
    for (int h=0;h<26;h++) sA[t*26 + h] *= inv;
  } else if (t >= 32 && t < 58){
    int r = t - 32;
    float s = 0.f;
    #pragma unroll
    for (int v=0;v<26;v++) s += sX[r*26 + v];
    float mean = s * (1.f/26.f);
    float var = 0.f;
    #pragma unroll
    for (int v=0;v<26;v++){ float d = sX[r*26 + v] - mean; var += d*d; }
    var *= (1.f/25.f);
    float invd = 1.f/(sqrtf(var) + 1e-6f);
    #pragma unroll
    for (int v=0;v<26;v++) sXn[r*26 + v] = sLa[v]*(sX[r*26 + v] - mean)*invd + sLb[v];
  }
  __syncthreads();
  for (int i=t;i<676;i+=64){
    int wi = i/26, v = i - wi*26;
    float s = 0.f;
    #pragma unroll
    for (int h=0;h<26;h++) s += sA[wi*26 + h]*sXn[h*26 + v];
    sX[i] = s;
  }
  __syncthreads();
  for (int i=t;i<676;i+=64){
    int wi = i/26, u = i - wi*26;
    float s = 0.f;
    #pragma unroll
    for (int v=0;v<26;v++) s += sX[wi*26 + v]*sWg[v*26 + u];
    out[(size_t)n*676 + i] = fmaxf(s, 0.f) + xg[(size_t)n*676 + i];
  }
}

// ================= fast-path kernels =================

__global__ __launch_bounds__(256) void fu_cvt_x(const float* __restrict__ x, unsigned short* __restrict__ d16){
  int i4 = (blockIdx.x*256 + threadIdx.x)*4;
  if (i4 >= 22151168) return;
  float4 v = *(const float4*)(x + i4);
  unsigned short h0,h1,h2,h3,l0,l1,l2,l3;
  fu_hilo(v.x,h0,l0); fu_hilo(v.y,h1,l1); fu_hilo(v.z,h2,l2); fu_hilo(v.w,h3,l3);
  uint2 hp, lp;
  hp.x = (unsigned)h0 | ((unsigned)h1<<16); hp.y = (unsigned)h2 | ((unsigned)h3<<16);
  lp.x = (unsigned)l0 | ((unsigned)l1<<16); lp.y = (unsigned)l2 | ((unsigned)l3<<16);
  *(uint2*)(d16 + FU_U16_XHI + i4) = hp;
  *(uint2*)(d16 + FU_U16_XLO + i4) = lp;
}

// Bm [o][l] -> hi/lo row-major [o][l] AND FRAGMENT-MAJOR transposed: off=((o>>5)*676+l)*32+(o&31)
__global__ __launch_bounds__(256) void fu_cvt_bm2(const float* __restrict__ bm, unsigned short* __restrict__ big16){
  __shared__ float t[32][33];
  const int b = blockIdx.z;
  const int l0 = blockIdx.x*32, o0 = blockIdx.y*32;
  const int tx = threadIdx.x & 31, ty = threadIdx.x >> 5;
  const float* src = bm + (size_t)b*FU_CQ*FU_L;
  #pragma unroll
  for (int q=0;q<4;q++){
    int o = o0 + ty + 8*q, l = l0 + tx;
    float v = (l < FU_L) ? src[(size_t)o*FU_L + l] : 0.f;
    t[ty+8*q][tx] = v;
    if (l < FU_L){
      unsigned short h, lo;
      fu_hilo(v, h, lo);
      big16[FU_U16_BMHI + (size_t)b*86528 + (size_t)o*FU_L + l] = h;
      big16[FU_U16_BMLO + (size_t)b*86528 + (size_t)o*FU_L + l] = lo;
    }
  }
  __syncthreads();
  #pragma unroll
  for (int q=0;q<4;q++){
    int l = l0 + ty + 8*q, o = o0 + tx;
    if (l < FU_L){
      unsigned short h, lo;
      fu_hilo(t[tx][ty+8*q], h, lo);
      unsigned off = ((unsigned)(o >> 5)*676u + (unsigned)l)*32u + (unsigned)(o & 31);
      big16[FU_U16_BMTHI + (size_t)b*86528 + off] = h;
      big16[FU_U16_BMTLO + (size_t)b*86528 + off] = lo;
    }
  }
}

// m2_w row-major hi/lo; conv2_w FRAGMENT-MAJOR hi/lo: off = ((c>>5)*512 + o)*32 + (c&31)
__global__ __launch_bounds__(256) void fu_prep2(const float* __restrict__ m2w, const float* __restrict__ c2w,
                                                const float* __restrict__ g2, const float* __restrict__ b2,
                                                const float* __restrict__ m2, const float* __restrict__ v2,
                                                unsigned short* __restrict__ m2hl, unsigned short* __restrict__ w2hl,
                                                float* __restrict__ s2, float* __restrict__ bi2){
  int i = blockIdx.x*256 + threadIdx.x;
  if (i < 262144){
    int o = i >> 9, c = i & 511;
    unsigned short h, l;
    fu_hilo(m2w[i], h, l);
    m2hl[i] = h; m2hl[262144 + i] = l;
    fu_hilo(c2w[i], h, l);
    unsigned off = ((unsigned)(c >> 5)*512u + (unsigned)o)*32u + (unsigned)(c & 31);
    w2hl[off] = h; w2hl[262144 + off] = l;
  }
  if (i < 512){
    float s = g2[i] / sqrtf(v2[i] + 1e-5f);
    s2[i] = s;
    bi2[i] = b2[i] - m2[i]*s;
  }
}

// G[b,o,c] = sum_l Bm[o,l]*x[c,l] — 64x64 wave tiles, grid (4,1,64)
__global__ __launch_bounds__(256) void fu_mfma_G(const unsigned short* __restrict__ d16,
                                                 unsigned short* __restrict__ big16){
  const int b = blockIdx.z;
  const int n0 = blockIdx.x * 128;
  const int tid = threadIdx.x;
  const int lane = tid & 63, wid = tid >> 6;
  const int wm = wid >> 1, wn = wid & 1;
  const int lr = lane & 15, lk = lane >> 4;

  const unsigned short* bmh = big16 + FU_U16_BMHI + (size_t)b*86528;
  const unsigned short* bml = big16 + FU_U16_BMLO + (size_t)b*86528;
  const unsigned short* xh  = d16 + FU_U16_XHI + (size_t)b*346112;
  const unsigned short* xl  = d16 + FU_U16_XLO + (size_t)b*346112;

  fu_f32x4 acc[4][4];
  #pragma unroll
  for (int i=0;i<4;i++)
    #pragma unroll
    for (int j=0;j<4;j++) acc[i][j] = fu_f32x4{0.f,0.f,0.f,0.f};

  int arow[4], brow[4];
  #pragma unroll
  for (int i=0;i<4;i++) arow[i] = wm*64 + i*16 + lr;
  #pragma unroll
  for (int j=0;j<4;j++) brow[j] = n0 + wn*64 + j*16 + lr;

  for (int ks=0; ks<21; ks++){
    int k0 = ks*32 + lk*8;
    FuFrag ah[4], al[4], bh[4], bl[4];
    #pragma unroll
    for (int i=0;i<4;i++){
      const unsigned short* ph = bmh + (size_t)arow[i]*676 + k0;
      const unsigned short* pl = bml + (size_t)arow[i]*676 + k0;
      ah[i].u2[0] = *(const uint2*)(ph); ah[i].u2[1] = *(const uint2*)(ph+4);
      al[i].u2[0] = *(const uint2*)(pl); al[i].u2[1] = *(const uint2*)(pl+4);
    }
    #pragma unroll
    for (int j=0;j<4;j++){
      const unsigned short* ph = xh + (size_t)brow[j]*676 + k0;
      const unsigned short* pl = xl + (size_t)brow[j]*676 + k0;
      bh[j].u2[0] = *(const uint2*)(ph); bh[j].u2[1] = *(const uint2*)(ph+4);
      bl[j].u2[0] = *(const uint2*)(pl); bl[j].u2[1] = *(const uint2*)(pl+4);
    }
    #pragma unroll
    for (int i=0;i<4;i++)
      #pragma unroll
      for (int j=0;j<4;j++){
        acc[i][j] = fu_mm(ah[i], bh[j], acc[i][j]);
        acc[i][j] = fu_mm(ah[i], bl[j], acc[i][j]);
        acc[i][j] = fu_mm(al[i], bh[j], acc[i][j]);
      }
  }
  { // tail k=672..675 (lk==0 only)
    FuFrag ah[4], al[4], bh[4], bl[4];
    #pragma unroll
    for (int i=0;i<4;i++){
      ah[i].u4 = make_uint4(0,0,0,0); al[i].u4 = make_uint4(0,0,0,0);
      if (lk == 0){
        ah[i].u2[0] = *(const uint2*)(bmh + (size_t)arow[i]*676 + 672);
        al[i].u2[0] = *(const uint2*)(bml + (size_t)arow[i]*676 + 672);
      }
    }
    #pragma unroll
    for (int j=0;j<4;j++){
      bh[j].u4 = make_uint4(0,0,0,0); bl[j].u4 = make_uint4(0,0,0,0);
      if (lk == 0){
        bh[j].u2[0] = *(const uint2*)(xh + (size_t)brow[j]*676 + 672);
        bl[j].u2[0] = *(const uint2*)(xl + (size_t)brow[j]*676 + 672);
      }
    }
    #pragma unroll
    for (int i=0;i<4;i++)
      #pragma unroll
      for (int j=0;j<4;j++){
        acc[i][j] = fu_mm(ah[i], bh[j], acc[i][j]);
        acc[i][j] = fu_mm(ah[i], bl[j], acc[i][j]);
        acc[i][j] = fu_mm(al[i], bh[j], acc[i][j]);
      }
  }
  unsigned short* gh = big16 + FU_U16_GHI + (size_t)b*65536;
  unsigned short* gl = big16 + FU_U16_GLO + (size_t)b*65536;
  #pragma unroll
  for (int i=0;i<4;i++){
    #pragma unroll
    for (int r=0;r<4;r++){
      int o = wm*64 + i*16 + lk*4 + r;
      #pragma unroll
      for (int j=0;j<4;j++){
        int ccol = n0 + wn*64 + j*16 + lr;
        unsigned short h, l;
        fu_hilo(acc[i][j][r], h, l);
        gh[(size_t)o*512 + ccol] = h;
        gl[(size_t)o*512 + ccol] = l;
      }
    }
  }
}

// V[b,o,s] = (1/676) sum_c G[o,c]*M2[s,c] — 64x64 wave tiles, grid (4,1,64)
__global__ __launch_bounds__(256) void fu_mfma_V2(const unsigned short* __restrict__ big16,
                                                  const unsigned short* __restrict__ m2hl,
                                                  float* __restrict__ vout){
  const int b = blockIdx.z;
  const int n0 = blockIdx.x * 128;
  const int tid = threadIdx.x;
  const int lane = tid & 63, wid = tid >> 6;
  const int wm = wid >> 1, wn = wid & 1;
  const int lr = lane & 15, lk = lane >> 4;

  const unsigned short* gh = big16 + FU_U16_GHI + (size_t)b*65536;
  const unsigned short* gl = big16 + FU_U16_GLO + (size_t)b*65536;
  const unsigned short* mh = m2hl;
  const unsigned short* ml = m2hl + 262144;

  fu_f32x4 acc[4][4];
  #pragma unroll
  for (int i=0;i<4;i++)
    #pragma unroll
    for (int j=0;j<4;j++) acc[i][j] = fu_f32x4{0.f,0.f,0.f,0.f};

  int arow[4], brow[4];
  #pragma unroll
  for (int i=0;i<4;i++) arow[i] = wm*64 + i*16 + lr;
  #pragma unroll
  for (int j=0;j<4;j++) brow[j] = n0 + wn*64 + j*16 + lr;

  for (int ks=0; ks<16; ks++){
    int k0 = ks*32 + lk*8;
    FuFrag ah[4], al[4], bh[4], bl[4];
    #pragma unroll
    for (int i=0;i<4;i++){
      ah[i].u4 = *(const uint4*)(gh + (size_t)arow[i]*512 + k0);
      al[i].u4 = *(const uint4*)(gl + (size_t)arow[i]*512 + k0);
    }
    #pragma unroll
    for (int j=0;j<4;j++){
      bh[j].u4 = *(const uint4*)(mh + (size_t)brow[j]*512 + k0);
      bl[j].u4 = *(const uint4*)(ml + (size_t)brow[j]*512 + k0);
    }
    #pragma unroll
    for (int i=0;i<4;i++)
      #pragma unroll
      for (int j=0;j<4;j++){
        acc[i][j] = fu_mm(ah[i], bh[j], acc[i][j]);
        acc[i][j] = fu_mm(ah[i], bl[j], acc[i][j]);
        acc[i][j] = fu_mm(al[i], bh[j], acc[i][j]);
      }
  }
  const float inv = 1.0f/676.0f;
  #pragma unroll
  for (int i=0;i<4;i++)
    #pragma unroll
    for (int r=0;r<4;r++){
      int o = wm*64 + i*16 + lk*4 + r;
      #pragma unroll
      for (int j=0;j<4;j++){
        int s = n0 + wn*64 + j*16 + lr;
        vout[((size_t)b*FU_CQ + o)*FU_C + s] = acc[i][j][r]*inv;
      }
    }
}

// V f32 [o][s] -> VT hi/lo FRAGMENT-MAJOR: off = ((o>>5)*512 + s)*32 + (o&31)
__global__ __launch_bounds__(256) void fu_cvt_vt(const float* __restrict__ v, unsigned short* __restrict__ vt16){
  __shared__ float t[32][33];
  const int b = blockIdx.z;
  const int s0 = blockIdx.x*32, o0 = blockIdx.y*32;
  const int tx = threadIdx.x & 31, ty = threadIdx.x >> 5;
  const float* src = v + (size_t)b*FU_CQ*FU_C;
  #pragma unroll
  for (int q=0;q<4;q++){
    int o = o0 + ty + 8*q, s = s0 + tx;
    t[ty+8*q][tx] = src[(size_t)o*FU_C + s];
  }
  __syncthreads();
  #pragma unroll
  for (int q=0;q<4;q++){
    int s = s0 + ty + 8*q, o = o0 + tx;
    unsigned short h, lo;
    fu_hilo(t[tx][ty+8*q], h, lo);
    unsigned off = ((unsigned)(o >> 5)*512u + (unsigned)s)*32u + (unsigned)(o & 31);
    vt16[(size_t)b*65536 + off] = h;
    vt16[FU_U16_VTLO + (size_t)b*65536 + off] = lo;
  }
}

// y[l,s] = sum_c BmT[l,c]*VT[s,c] — fragment-major operands, streamed B, grid (4,6,64)
__global__ __launch_bounds__(256, 4) void fu_mfma_y(const unsigned short* __restrict__ big16,
                                                    const unsigned short* __restrict__ vt16,
                                                    float* __restrict__ yout){
  const int b = blockIdx.z;
  const int n0 = blockIdx.x * 128;
  const int m0 = blockIdx.y * 128;
  const int tid = threadIdx.x;
  const int lane = tid & 63, wid = tid >> 6;
  const int wm = wid >> 1, wn = wid & 1;
  const int lr = lane & 15, lk = lane >> 4;

  const unsigned short* ath = big16 + FU_U16_BMTHI + (size_t)b*86528;
  const unsigned short* atl = big16 + FU_U16_BMTLO + (size_t)b*86528;
  const unsigned short* bth = vt16 + (size_t)b*65536;
  const unsigned short* btl = vt16 + FU_U16_VTLO + (size_t)b*65536;

  fu_f32x4 acc[4][4];
  #pragma unroll
  for (int i=0;i<4;i++)
    #pragma unroll
    for (int j=0;j<4;j++) acc[i][j] = fu_f32x4{0.f,0.f,0.f,0.f};

  int arow[4], brow[4];
  #pragma unroll
  for (int i=0;i<4;i++){
    int l = m0 + wm*64 + i*16 + lr;
    arow[i] = l < FU_L ? l : (FU_L-1);
  }
  #pragma unroll
  for (int j=0;j<4;j++) brow[j] = n0 + wn*64 + j*16 + lr;

  for (int ks=0; ks<4; ks++){
    FuFrag ah[4], al[4];
    #pragma unroll
    for (int i=0;i<4;i++){
      size_t off = ((size_t)ks*676 + arow[i])*32 + lk*8;
      ah[i].u4 = *(const uint4*)(ath + off);
      al[i].u4 = *(const uint4*)(atl + off);
    }
    #pragma unroll
    for (int j=0;j<4;j++){
      FuFrag bh, bl;
      size_t off = ((size_t)ks*512 + brow[j])*32 + lk*8;
      bh.u4 = *(const uint4*)(bth + off);
      bl.u4 = *(const uint4*)(btl + off);
      #pragma unroll
      for (int i=0;i<4;i++){
        acc[i][j] = fu_mm(ah[i], bh, acc[i][j]);
        acc[i][j] = fu_mm(ah[i], bl, acc[i][j]);
        acc[i][j] = fu_mm(al[i], bh, acc[i][j]);
      }
    }
  }
  #pragma unroll
  for (int i=0;i<4;i++){
    #pragma unroll
    for (int r=0;r<4;r++){
      int l = m0 + wm*64 + i*16 + lk*4 + r;
      if (l < FU_L){
        #pragma unroll
        for (int j=0;j<4;j++){
          int s = n0 + wn*64 + j*16 + lr;
          yout[(size_t)b*346112 + (size_t)l*FU_C + s] = acc[i][j][r];
        }
      }
    }
  }
}

// transpose+cvt: yflat (b,[c][l]) -> yvt FRAGMENT-MAJOR: off = ((c>>5)*676 + l2)*32 + (c&31)
__global__ __launch_bounds__(256) void fu_tr_y(const float* __restrict__ yf, unsigned short* __restrict__ big16){
  __shared__ float t[32][33];
  const int b = blockIdx.z;
  const int l0 = blockIdx.x*32, c0 = blockIdx.y*32;
  const int tx = threadIdx.x & 31, ty = threadIdx.x >> 5;
  const float* yb = yf + (size_t)b*FU_C*FU_L;
  #pragma unroll
  for (int q=0;q<4;q++){
    int c = c0 + ty + 8*q;
    int l = l0 + tx;
    t[ty + 8*q][tx] = (l < FU_L) ? yb[(size_t)c*FU_L + l] : 0.f;
  }
  __syncthreads();
  unsigned short* yh = big16 + FU_U16_YVHI + (size_t)b*346112;
  unsigned short* yl = big16 + FU_U16_YVLO + (size_t)b*346112;
  #pragma unroll
  for (int q=0;q<4;q++){
    int l2 = l0 + ty + 8*q;
    if (l2 < FU_L){
      int c = c0 + tx;
      unsigned short h, l;
      fu_hilo(t[tx][ty + 8*q], h, l);
      unsigned off = ((unsigned)(c >> 5)*676u + (unsigned)l2)*32u + (unsigned)(c & 31);
      yh[off] = h;
      yl[off] = l;
    }
  }
}

// conv2 MFMA + BN2 + leaky -> iv (write-only into d_out; X=iv+m*x deferred to gnn6)
__global__ __launch_bounds__(256, 4) void fu_mfma_c2(const unsigned short* __restrict__ big16,
                                                     const unsigned short* __restrict__ w2hl,
                                                     const float* __restrict__ s2, const float* __restrict__ bi2,
                                                     float* __restrict__ ivout){
  const int flat = blockIdx.x;                       // 1536 = 64 b x 24 tiles
  const int swz  = (flat & 7)*192 + (flat >> 3);     // bijective; each XCD owns 8 whole batches
  const int b    = swz / 24;
  const int rem  = swz - b*24;
  const int mt   = rem / 6;
  const int lt   = rem - mt*6;
  const int m0 = mt * 128;                           // o tile
  const int n0 = lt * 128;                           // l2 tile
  const int tid = threadIdx.x;
  const int lane = tid & 63, wid = tid >> 6;
  const int wm = wid >> 1, wn = wid & 1;
  const int lr = lane & 15, lk = lane >> 4;

  const unsigned short* wh = w2hl;
  const unsigned short* wl = w2hl + 262144;
  const unsigned short* yh = big16 + FU_U16_YVHI + (size_t)b*346112;
  const unsigned short* yl = big16 + FU_U16_YVLO + (size_t)b*346112;

  fu_f32x4 acc[4][4];
  #pragma unroll
  for (int i=0;i<4;i++)
    #pragma unroll
    for (int j=0;j<4;j++) acc[i][j] = fu_f32x4{0.f,0.f,0.f,0.f};

  int arow[4], brow[4];
  #pragma unroll
  for (int i=0;i<4;i++) arow[i] = m0 + wm*64 + i*16 + lr;     // o < 512
  #pragma unroll
  for (int j=0;j<4;j++){
    int l2 = n0 + wn*64 + j*16 + lr;
    brow[j] = l2 < FU_L ? l2 : (FU_L-1);
  }

  for (int ks=0; ks<16; ks++){
    FuFrag ah[4], al[4];
    #pragma unroll
    for (int i=0;i<4;i++){
      size_t off = ((size_t)ks*512 + arow[i])*32 + lk*8;      // fragment-major W2
      ah[i].u4 = *(const uint4*)(wh + off);
      al[i].u4 = *(const uint4*)(wl + off);
    }
    #pragma unroll
    for (int j=0;j<4;j++){
      FuFrag bh, bl;
      size_t off = ((size_t)ks*676 + brow[j])*32 + lk*8;      // fragment-major yvt
      bh.u4 = *(const uint4*)(yh + off);
      bl.u4 = *(const uint4*)(yl + off);
      #pragma unroll
      for (int i=0;i<4;i++){
        acc[i][j] = fu_mm(ah[i], bh, acc[i][j]);
        acc[i][j] = fu_mm(ah[i], bl, acc[i][j]);
        acc[i][j] = fu_mm(al[i], bh, acc[i][j]);
      }
    }
  }
  #pragma unroll
  for (int i=0;i<4;i++){
    #pragma unroll
    for (int r=0;r<4;r++){
      int o = m0 + wm*64 + i*16 + lk*4 + r;
      float sv = s2[o], bv = bi2[o];
      #pragma unroll
      for (int j=0;j<4;j++){
        int l2 = n0 + wn*64 + j*16 + lr;
        if (l2 < FU_L){
          float v = acc[i][j][r]*sv + bv;
          v = v >= 0.f ? v : 0.01f*v;
          ivout[((size_t)b*FU_C + o)*FU_L + l2] = v;
        }
      }
    }
  }
}

extern "C" void kernel_launch(void* const* d_in, const int* in_sizes, int n_in,
                              void* d_out, int out_size, void* d_ws, size_t ws_size,
                              hipStream_t stream){
  const float* x   = (const float*)d_in[0];
  const float* cw  = (const float*)d_in[1];
  const float* g1  = (const float*)d_in[2];
  const float* b1  = (const float*)d_in[3];
  const float* m1  = (const float*)d_in[4];
  const float* v1  = (const float*)d_in[5];
  const float* m1w = (const float*)d_in[6];
  const float* m2w = (const float*)d_in[7];
  const float* c2w = (const float*)d_in[8];
  const float* g2  = (const float*)d_in[9];
  const float* b2  = (const float*)d_in[10];
  const float* m2  = (const float*)d_in[11];
  const float* v2  = (const float*)d_in[12];
  const float* wg  = (const float*)d_in[13];
  const float* lna = (const float*)d_in[14];
  const float* lnb = (const float*)d_in[15];
  float* out = (float*)d_out;
  float* ws = (float*)d_ws;

  if (ws_size >= (size_t)FU_FAST_FLOATS * 4u){
    unsigned short* d16   = (unsigned short*)d_out;
    unsigned short* big16 = (unsigned short*)(ws + FU_OFF_BIG);
    unsigned short* vt16  = (unsigned short*)(ws + FU_OFF_V);
    unsigned short* m2hl  = (unsigned short*)(ws + FU_OFF_M2HL);
    unsigned short* w2hl  = (unsigned short*)(ws + FU_OFF_W2HL);
    float* wt1 = ws + FU_OFF_V;   // 65536 floats; dead until fu_cvt_vt

    fu_sim3<<<dim3(11,64,4), 256, 0, stream>>>(x, ws + FU_OFF_BIG);
    fu_sim_red<<<1353, 256, 0, stream>>>(ws + FU_OFF_BIG, ws + FU_OFF_SIM);
    fu_conv1b<<<dim3(64,16), 256, 0, stream>>>(cw, g1, b1, m1, v1, ws + FU_OFF_SIM, ws + FU_OFF_MBUF);
    fu_tr_w1<<<dim3(4,16), 256, 0, stream>>>(m1w, wt1);
    fu_gemm_bm<<<768, 256, 0, stream>>>(wt1, x, ws + FU_OFF_BM);
    fu_prep2<<<1024, 256, 0, stream>>>(m2w, c2w, g2, b2, m2, v2, m2hl, w2hl,
                                       ws + FU_OFF_S2, ws + FU_OFF_BI2);
    fu_cvt_x<<<21632, 256, 0, stream>>>(x, d16);
    fu_cvt_bm2<<<dim3(22,4,64), 256, 0, stream>>>(ws + FU_OFF_BM, big16);
    fu_mfma_G<<<dim3(4,1,64), 256, 0, stream>>>(d16, big16);
    fu_mfma_V2<<<dim3(4,1,64), 256, 0, stream>>>(big16, m2hl, ws + FU_OFF_BM);
    fu_cvt_vt<<<dim3(16,4,64), 256, 0, stream>>>(ws + FU_OFF_BM, vt16);
    fu_mfma_y<<<dim3(4,6,64), 256, 0, stream>>>(big16, vt16, out);
    fu_tr_y<<<dim3(22,16,64), 256, 0, stream>>>(out, big16);
    fu_mfma_c2<<<1536, 256, 0, stream>>>(big16, w2hl, ws + FU_OFF_S2, ws + FU_OFF_BI2, out);  // iv -> d_out
    fu_gnn6<<<8192, 256, 0, stream>>>(ws + FU_OFF_MBUF, out, x, wg, lna, lnb, out);
  } else if (ws_size >= (size_t)FU_FB_FLOATS * 4u){
    // fallback: round-5 pipeline
    FoldUnfoldModule_82592221102582_kernel<<<2048, 256, 0, stream>>>(out, out_size, 20.0f);
    fu_sim2<<<dim3(11,64), 256, 0, stream>>>(x, ws + FU_FB_SIM);
    fu_conv1b<<<dim3(64,16), 256, 0, stream>>>(cw, g1, b1, m1, v1, ws + FU_FB_SIM, ws + FU_FB_MBUF);
    fu_gemm_bm_fb<<<dim3(3,4,64), 256, 0, stream>>>(m1w, x, ws + FU_FB_BM);
    fu_gemm_b2<<<dim3(3,32,64), 256, 0, stream>>>(m2w, x, out);
    fu_V<<<dim3(8,2,64), 256, 0, stream>>>(ws + FU_FB_BM, out, ws + FU_FB_V);
    fu_y<<<dim3(8,11,64), 256, 0, stream>>>(ws + FU_FB_BM, ws + FU_FB_V, out);
    fu_c2<<<dim3(3,32,64), 256, 0, stream>>>(out, c2w, g2, b2, m2, v2, x, ws + FU_FB_MBUF);
    fu_gnn<<<32768, 64, 0, stream>>>(ws + FU_FB_MBUF, x, wg, lna, lnb, out);
  } else {
    FoldUnfoldModule_82592221102582_kernel<<<2048, 256, 0, stream>>>(out, out_size, 48.5f);
  }
}

// Round 26
// 862.029 us; speedup vs baseline: 1.0644x; 1.0132x over previous
//
#include <hip/hip_runtime.h>

static constexpr int FU_L  = 676;   // 26*26
static constexpr int FU_H  = 26;
static constexpr int FU_C  = 512;
static constexpr int FU_CQ = 128;   // C/4

// ================= fast-path ws layout (floats) =================
static constexpr unsigned FU_OFF_MBUF = 0u;          // 22151168  m (conv1 out)
static constexpr unsigned FU_OFF_BM   = 22151168u;   //  5537792  Bm f32 [o][l]; later V f32 [o][s]
static constexpr unsigned FU_OFF_BIG  = 27688960u;   // 22151168  phase0: sim partials; phase1: BmHL/BmTHL/GHL; phase2: yvt-HL
static constexpr unsigned FU_OFF_V    = 49840128u;   //  4194304  WT (early); later VT hi/lo u16 (fragment-major)
static constexpr unsigned FU_OFF_SIM  = 54034432u;   //   389376  sim (b,9,676)
static constexpr unsigned FU_OFF_M2HL = 54423808u;   //   262144  m2_w hi/lo u16
static constexpr unsigned FU_OFF_W2HL = 54685952u;   //   262144  conv2_w hi/lo u16 (fragment-major)
static constexpr unsigned FU_OFF_S2   = 54948096u;   //      512
static constexpr unsigned FU_OFF_BI2  = 54948608u;   //      512
static constexpr unsigned FU_FAST_FLOATS = 54949120u;   // 219.8 MB

// fallback (round-5) layout
static constexpr unsigned FU_FB_MBUF = 0u;
static constexpr unsigned FU_FB_BM   = 22151168u;
static constexpr unsigned FU_FB_V    = 27688960u;
static constexpr unsigned FU_FB_SIM  = 31883264u;
static constexpr unsigned FU_FB_FLOATS = 32272640u;  // 129.1 MB

// u16 sub-offsets inside BIG (phase 1)
static constexpr unsigned FU_U16_BMHI  = 0u;
static constexpr unsigned FU_U16_BMLO  = 5537792u;
static constexpr unsigned FU_U16_BMTHI = 11075584u;  // fragment-major [(o>>5)][l][o&31]
static constexpr unsigned FU_U16_BMTLO = 16613376u;
static constexpr unsigned FU_U16_GHI   = 22151168u;
static constexpr unsigned FU_U16_GLO   = 26345472u;
// u16 sub-offsets inside BIG (phase 2): yvt fragment-major [kc][l2][ksub]
static constexpr unsigned FU_U16_YVHI  = 0u;
static constexpr unsigned FU_U16_YVLO  = 22151168u;
// u16 layout of d_out when used as scratch
static constexpr unsigned FU_U16_XHI   = 0u;
static constexpr unsigned FU_U16_XLO   = 22151168u;
// u16 sub-offsets inside VT region
static constexpr unsigned FU_U16_VTLO  = 4194304u;

typedef __bf16 fu_bf16x8 __attribute__((ext_vector_type(8)));
typedef float  fu_f32x4  __attribute__((ext_vector_type(4)));

union FuFrag {
  uint4 u4;
  uint2 u2[2];
  fu_bf16x8 bf;
};

__device__ __forceinline__ unsigned short fu_rnebf(float f){
  unsigned int u = __float_as_uint(f);
  u += 0x7fffu + ((u >> 16) & 1u);
  return (unsigned short)(u >> 16);
}
__device__ __forceinline__ void fu_hilo(float f, unsigned short& h, unsigned short& l){
  h = fu_rnebf(f);
  float fh = __uint_as_float(((unsigned int)h) << 16);
  l = fu_rnebf(f - fh);
}
__device__ __forceinline__ fu_f32x4 fu_mm(const FuFrag& a, const FuFrag& b, fu_f32x4 c){
  return __builtin_amdgcn_mfma_f32_16x16x32_bf16(a.bf, b.bf, c, 0, 0, 0);
}

// Identifier-named kernel; kept for symbol presence + diagnostics.
__global__ __launch_bounds__(256) void FoldUnfoldModule_82592221102582_kernel(
    float* __restrict__ out, int n, float val){
  int i = blockIdx.x*256 + threadIdx.x;
  int stride = gridDim.x*256;
  for (; i < n; i += stride) out[i] = val;
}

// ---------------- self-similarity v3: grid (11,64,4); 128 ch per block -> partials ----------------
__global__ __launch_bounds__(256) void fu_sim3(const float* __restrict__ x, float* __restrict__ psim){
  __shared__ float red[3][64][8];
  int lq = threadIdx.x & 63, cg = threadIdx.x >> 6;
  int l = blockIdx.x*64 + lq;
  int b = blockIdx.y;
  int z = blockIdx.z;
  bool lval = l < FU_L;
  int yy = l / FU_H, xx = l - yy*FU_H;
  int noff[8]; bool nval[8];
  #pragma unroll
  for (int t=1;t<9;t++){
    int di = t/3 - 1, dj = t%3 - 1;
    int y2 = yy + di, x2 = xx + dj;
    nval[t-1] = lval && (y2>=0 && y2<FU_H && x2>=0 && x2<FU_H);
    noff[t-1] = nval[t-1] ? (y2*FU_H + x2) : 0;
  }
  float acc[8] = {0,0,0,0,0,0,0,0};
  const float* xb = x + (size_t)b*FU_C*FU_L;
  int c0 = z*128 + cg*32;
  for (int c=c0; c<c0+32; c++){
    const float* row = xb + c*FU_L;
    float ctr = lval ? row[l] : 0.f;
    #pragma unroll
    for (int t=0;t<8;t++)
      if (nval[t]) acc[t] += row[noff[t]] * ctr;
  }
  if (cg > 0){
    #pragma unroll
    for (int t=0;t<8;t++) red[cg-1][lq][t] = acc[t];
  }
  __syncthreads();
  if (cg == 0 && lval){
    #pragma unroll
    for (int g=0;g<3;g++)
      #pragma unroll
      for (int t=0;t<8;t++) acc[t] += red[g][lq][t];
    float* pb = psim + ((size_t)z*64 + b)*8*FU_L;
    #pragma unroll
    for (int t=0;t<8;t++) pb[t*FU_L + l] = acc[t];
  }
}

// reduce 4 partials -> sim[b][9][676] (tap 0 zeroed)
__global__ __launch_bounds__(256) void fu_sim_red(const float* __restrict__ psim, float* __restrict__ simb){
  int i = blockIdx.x*256 + threadIdx.x;          // over 64*8*676
  const int tot = 64*8*FU_L;
  if (i >= tot) return;
  int b = i / (8*FU_L);
  int r = i - b*8*FU_L;                          // tap*676 + l, taps 1..8
  const size_t zs = (size_t)64*8*FU_L;
  float s = psim[(size_t)b*8*FU_L + r] + psim[zs + (size_t)b*8*FU_L + r]
          + psim[2*zs + (size_t)b*8*FU_L + r] + psim[3*zs + (size_t)b*8*FU_L + r];
  simb[(size_t)b*9*FU_L + FU_L + r] = s;
  if (i < 64*FU_L) simb[(size_t)(i/FU_L)*9*FU_L + (i%FU_L)] = 0.f;
}

// ---------------- self-similarity v2 (fallback path only) ----------------
__global__ __launch_bounds__(256) void fu_sim2(const float* __restrict__ x, float* __restrict__ simb){
  __shared__ float red[3][64][8];
  int lq = threadIdx.x & 63, cg = threadIdx.x >> 6;
  int l = blockIdx.x*64 + lq;
  int b = blockIdx.y;
  bool lval = l < FU_L;
  int yy = l / FU_H, xx = l - yy*FU_H;
  int noff[8]; bool nval[8];
  #pragma unroll
  for (int t=1;t<9;t++){
    int di = t/3 - 1, dj = t%3 - 1;
    int y2 = yy + di, x2 = xx + dj;
    nval[t-1] = lval && (y2>=0 && y2<FU_H && x2>=0 && x2<FU_H);
    noff[t-1] = nval[t-1] ? (y2*FU_H + x2) : 0;
  }
  float acc[8] = {0,0,0,0,0,0,0,0};
  const float* xb = x + (size_t)b*FU_C*FU_L;
  int c0 = cg*128;
  for (int c=c0; c<c0+128; c++){
    const float* row = xb + c*FU_L;
    float ctr = lval ? row[l] : 0.f;
    #pragma unroll
    for (int t=0;t<8;t++)
      if (nval[t]) acc[t] += row[noff[t]] * ctr;
  }
  if (cg > 0){
    #pragma unroll
    for (int t=0;t<8;t++) red[cg-1][lq][t] = acc[t];
  }
  __syncthreads();
  if (cg == 0 && lval){
    #pragma unroll
    for (int g=0;g<3;g++)
      #pragma unroll
      for (int t=0;t<8;t++) acc[t] += red[g][lq][t];
    float* sb = simb + (size_t)b*9*FU_L;
    sb[l] = 0.f;
    #pragma unroll
    for (int t=0;t<8;t++) sb[(t+1)*FU_L + l] = acc[t];
  }
}

// ---------------- conv1: padded-halo LDS, 3 l x 32 o per thread, scalar weights ----------------
__global__ __launch_bounds__(256) void fu_conv1b(const float* __restrict__ cw,
                                                 const float* __restrict__ g1, const float* __restrict__ b1,
                                                 const float* __restrict__ m1, const float* __restrict__ v1,
                                                 const float* __restrict__ simb, float* __restrict__ mbuf){
  __shared__ float sp[8][784];
  const int b  = blockIdx.x;
  const int o0 = blockIdx.y * 32;
  const int tid = threadIdx.x;
  const float* sb = simb + (size_t)b*9*FU_L;
  for (int i = tid; i < 8*784; i += 256){
    int ch = i / 784, p = i - ch*784;
    int py = p / 28, px = p - py*28;
    float v = 0.f;
    if (py >= 1 && py <= 26 && px >= 1 && px <= 26)
      v = sb[(ch+1)*FU_L + (py-1)*FU_H + (px-1)];
    sp[ch][p] = v;
  }
  __syncthreads();

  const int l0 = tid, l1 = tid + 256, l2 = tid + 512;
  const bool l2ok = l2 < FU_L;
  const int lc2 = l2ok ? l2 : 0;
  int yy, xx;
  yy = l0/FU_H; xx = l0 - yy*FU_H; const int pb0 = yy*28 + xx;
  yy = l1/FU_H; xx = l1 - yy*FU_H; const int pb1 = yy*28 + xx;
  yy = lc2/FU_H; xx = lc2 - yy*FU_H; const int pb2 = yy*28 + xx;

  for (int ot = 0; ot < 4; ot++){
    float acc[8][3];
    #pragma unroll
    for (int oo=0;oo<8;oo++){ acc[oo][0]=0.f; acc[oo][1]=0.f; acc[oo][2]=0.f; }
    for (int ch = 0; ch < 8; ch++){
      const float* spc = sp[ch];
      float sa[9], sbv[9], sc[9];
      #pragma unroll
      for (int dy=0; dy<3; dy++)
        #pragma unroll
        for (int dx=0; dx<3; dx++){
          int t = dy*3 + dx, off = dy*28 + dx;
          sa[t]  = spc[pb0 + off];
          sbv[t] = spc[pb1 + off];
          sc[t]  = spc[pb2 + off];
        }
      #pragma unroll
      for (int oo=0; oo<8; oo++){
        const float* wp = cw + (size_t)(o0 + ot*8 + oo)*81 + (ch+1)*9;
        #pragma unroll
        for (int t=0; t<9; t++){
          float w = wp[t];
          acc[oo][0] += w*sa[t];
          acc[oo][1] += w*sbv[t];
          acc[oo][2] += w*sc[t];
        }
      }
    }
    #pragma unroll
    for (int oo=0; oo<8; oo++){
      int o = o0 + ot*8 + oo;
      float s1 = g1[o] / sqrtf(v1[o] + 1e-5f);
      float bb = b1[o] - m1[o]*s1;
      size_t base = ((size_t)b*FU_C + o)*FU_L;
      float r0 = acc[oo][0]*s1 + bb; r0 = r0 >= 0.f ? r0 : 0.01f*r0;
      float r1 = acc[oo][1]*s1 + bb; r1 = r1 >= 0.f ? r1 : 0.01f*r1;
      float r2 = acc[oo][2]*s1 + bb; r2 = r2 >= 0.f ? r2 : 0.01f*r2;
      mbuf[base + l0] = r0;
      mbuf[base + l1] = r1;
      if (l2ok) mbuf[base + l2] = r2;
    }
  }
}

// ---------------- m1_w [o][c] -> WT [c][o] (128x512 -> 512x128) ----------------
__global__ __launch_bounds__(256) void fu_tr_w1(const float* __restrict__ w, float* __restrict__ wt){
  __shared__ float t[32][33];
  const int o0 = blockIdx.x*32;   // 4
  const int c0 = blockIdx.y*32;   // 16
  const int tx = threadIdx.x & 31, ty = threadIdx.x >> 5;
  #pragma unroll
  for (int q=0;q<4;q++)
    t[ty+8*q][tx] = w[(size_t)(o0+ty+8*q)*FU_C + c0+tx];
  __syncthreads();
  #pragma unroll
  for (int q=0;q<4;q++)
    wt[(size_t)(c0+ty+8*q)*FU_CQ + o0+tx] = t[tx][ty+8*q];
}

// ---------------- Bm = m1_w @ x via WT[c][o]; 4 o x 8 l per thread; flat 768 + XCD swizzle; unroll 4 ----------------
__global__ __launch_bounds__(256) void fu_gemm_bm(const float* __restrict__ WT, const float* __restrict__ x,
                                                  float* __restrict__ bmout){
  const int flat = blockIdx.x;                      // 768 = 64 b x (3 l-tiles x 4 o-tiles)
  const int swz  = (flat & 7)*96 + (flat >> 3);     // bijective; each XCD owns 8 whole batches
  const int b    = swz / 12;
  const int rem  = swz - b*12;
  const int ot   = rem / 3;                         // o-tile 0..3
  const int lt   = rem - ot*3;                      // l-tile 0..2
  int tid = threadIdx.x, p = tid & 31, og = tid >> 5;
  int l = lt*256 + p*8;
  int o = ot*32 + og*4;
  if (l >= FU_L) return;
  int nv = FU_L - l; if (nv > 8) nv = 8;
  bool hi_ok = (l + 8 <= FU_L);
  const float* inb = x + (size_t)b*FU_C*FU_L + l;
  float a[4][8] = {};
  #pragma unroll 4
  for (int c=0;c<FU_C;c++){
    const float* r = inb + c*FU_L;
    float4 xa = *(const float4*)(r);
    float4 xb2;
    if (hi_ok) xb2 = *(const float4*)(r + 4); else { xb2.x=0;xb2.y=0;xb2.z=0;xb2.w=0; }
    float xs[8] = {xa.x,xa.y,xa.z,xa.w,xb2.x,xb2.y,xb2.z,xb2.w};
    float4 wv = *(const float4*)(WT + (size_t)c*FU_CQ + o);
    #pragma unroll
    for (int j=0;j<8;j++){
      a[0][j] += wv.x*xs[j]; a[1][j] += wv.y*xs[j];
      a[2][j] += wv.z*xs[j]; a[3][j] += wv.w*xs[j];
    }
  }
  float* o0 = bmout + (size_t)b*FU_CQ*FU_L + o*FU_L + l;
  #pragma unroll
  for (int oo=0;oo<4;oo++)
    for (int j=0;j<nv;j++) o0[oo*FU_L + j] = a[oo][j];
}

// ---------------- fallback-only kernels (round-5 path) ----------------
__global__ __launch_bounds__(256) void fu_gemm_bm_fb(const float* __restrict__ W, const float* __restrict__ x,
                                                     float* __restrict__ bmout){
  int tid = threadIdx.x, p = tid & 31, og = tid >> 5;
  int l = blockIdx.x*256 + p*8;
  int o = blockIdx.y*32 + og*4;
  int b = blockIdx.z;
  if (l >= FU_L) return;
  int nv = FU_L - l; if (nv > 8) nv = 8;
  bool hi_ok = (l + 8 <= FU_L);
  const float* inb = x + (size_t)b*FU_C*FU_L + l;
  float a[4][8] = {};
  for (int c=0;c<FU_C;c++){
    const float* r = inb + c*FU_L;
    float4 xa = *(const float4*)(r);
    float4 xb2;
    if (hi_ok) xb2 = *(const float4*)(r + 4); else { xb2.x=0;xb2.y=0;xb2.z=0;xb2.w=0; }
    float xs[8] = {xa.x,xa.y,xa.z,xa.w,xb2.x,xb2.y,xb2.z,xb2.w};
    float w0 = W[(o+0)*FU_C + c], w1 = W[(o+1)*FU_C + c];
    float w2 = W[(o+2)*FU_C + c], w3 = W[(o+3)*FU_C + c];
    #pragma unroll
    for (int j=0;j<8;j++){
      a[0][j] += w0*xs[j]; a[1][j] += w1*xs[j];
      a[2][j] += w2*xs[j]; a[3][j] += w3*xs[j];
    }
  }
  float* o0 = bmout + (size_t)b*FU_CQ*FU_L + o*FU_L + l;
  #pragma unroll
  for (int oo=0;oo<4;oo++)
    for (int j=0;j<nv;j++) o0[oo*FU_L + j] = a[oo][j];
}

__global__ __launch_bounds__(256) void fu_gemm_b2(const float* __restrict__ W, const float* __restrict__ x,
                                                  float* __restrict__ b2out){
  int tid = threadIdx.x, p = tid & 31, og = tid >> 5;
  int l = blockIdx.x*256 + p*8;
  int o = blockIdx.y*16 + og*2;
  int b = blockIdx.z;
  if (l >= FU_L) return;
  int nv = FU_L - l; if (nv > 8) nv = 8;
  bool hi_ok = (l + 8 <= FU_L);
  const float* inb = x + (size_t)b*FU_C*FU_L + l;
  const float* w0p = W + o*FU_C;
  const float* w1p = w0p + FU_C;
  float a0[8] = {0,0,0,0,0,0,0,0};
  float a1[8] = {0,0,0,0,0,0,0,0};
  for (int c=0;c<FU_C;c++){
    const float* r = inb + c*FU_L;
    float4 xa = *(const float4*)(r);
    float4 xb2;
    if (hi_ok) xb2 = *(const float4*)(r + 4); else { xb2.x=0;xb2.y=0;xb2.z=0;xb2.w=0; }
    float xs[8] = {xa.x,xa.y,xa.z,xa.w,xb2.x,xb2.y,xb2.z,xb2.w};
    float w0 = w0p[c], w1 = w1p[c];
    #pragma unroll
    for (int j=0;j<8;j++){ a0[j] += w0*xs[j]; a1[j] += w1*xs[j]; }
  }
  float* o0 = b2out + (size_t)b*FU_C*FU_L + o*FU_L + l;
  for (int j=0;j<nv;j++){ o0[j] = a0[j]; o0[FU_L+j] = a1[j]; }
}

__global__ __launch_bounds__(256) void fu_V(const float* __restrict__ bm, const float* __restrict__ b2in,
                                            float* __restrict__ vout){
  int tid = threadIdx.x; int tx = tid & 15, ty = tid >> 4;
  int o = blockIdx.y*64 + ty*4;
  int s = blockIdx.x*64 + tx*4;
  int b = blockIdx.z;
  const float* A  = bm + (size_t)b*FU_CQ*FU_L;
  const float* Bt = b2in + (size_t)b*FU_C*FU_L;
  float acc[4][4] = {};
  for (int k=0;k<FU_L;k+=4){
    float4 av[4], bv[4];
    #pragma unroll
    for (int i=0;i<4;i++) av[i] = *(const float4*)(A + (o+i)*FU_L + k);
    #pragma unroll
    for (int j=0;j<4;j++) bv[j] = *(const float4*)(Bt + (s+j)*FU_L + k);
    #pragma unroll
    for (int i=0;i<4;i++){
      #pragma unroll
      for (int j=0;j<4;j++)
        acc[i][j] += av[i].x*bv[j].x + av[i].y*bv[j].y + av[i].z*bv[j].z + av[i].w*bv[j].w;
    }
  }
  #pragma unroll
  for (int i=0;i<4;i++)
    #pragma unroll
    for (int j=0;j<4;j++)
      vout[(size_t)b*FU_CQ*FU_C + (o+i)*FU_C + s + j] = acc[i][j]*(1.0f/676.0f);
}

__global__ __launch_bounds__(256) void fu_y(const float* __restrict__ bm, const float* __restrict__ v,
                                            float* __restrict__ yout){
  int tid = threadIdx.x; int tx = tid & 15, ty = tid >> 4;
  int l = blockIdx.y*64 + ty*4;
  int s = blockIdx.x*64 + tx*4;
  int b = blockIdx.z;
  if (l >= FU_L) return;
  const float* A  = bm + (size_t)b*FU_CQ*FU_L;
  const float* Vb = v  + (size_t)b*FU_CQ*FU_C;
  float acc[4][4] = {};
  for (int c=0;c<FU_CQ;c++){
    float4 av = *(const float4*)(A + c*FU_L + l);
    float4 bv = *(const float4*)(Vb + c*FU_C + s);
    float ai[4] = {av.x, av.y, av.z, av.w};
    float bj[4] = {bv.x, bv.y, bv.z, bv.w};
    #pragma unroll
    for (int i=0;i<4;i++)
      #pragma unroll
      for (int j=0;j<4;j++)
        acc[i][j] += ai[i]*bj[j];
  }
  #pragma unroll
  for (int i=0;i<4;i++)
    #pragma unroll
    for (int j=0;j<4;j++)
      yout[(size_t)b*FU_L*FU_C + (size_t)(l+i)*FU_C + s + j] = acc[i][j];
}

__global__ __launch_bounds__(256) void fu_c2(const float* __restrict__ yv, const float* __restrict__ W,
                                             const float* __restrict__ g2, const float* __restrict__ b2,
                                             const float* __restrict__ m2, const float* __restrict__ v2,
                                             const float* __restrict__ x, float* __restrict__ mio){
  int tid = threadIdx.x, p = tid & 31, og = tid >> 5;
  int l = blockIdx.x*256 + p*8;
  int o = blockIdx.y*16 + og*2;
  int b = blockIdx.z;
  if (l >= FU_L) return;
  int nv = FU_L - l; if (nv > 8) nv = 8;
  bool hi_ok = (l + 8 <= FU_L);
  const float* inb = yv + (size_t)b*FU_C*FU_L + l;
  const float* w0p = W + o*FU_C;
  const float* w1p = w0p + FU_C;
  float a0[8] = {0,0,0,0,0,0,0,0};
  float a1[8] = {0,0,0,0,0,0,0,0};
  for (int c=0;c<FU_C;c++){
    const float* r = inb + c*FU_L;
    float4 xa = *(const float4*)(r);
    float4 xb2;
    if (hi_ok) xb2 = *(const float4*)(r + 4); else { xb2.x=0;xb2.y=0;xb2.z=0;xb2.w=0; }
    float xs[8] = {xa.x,xa.y,xa.z,xa.w,xb2.x,xb2.y,xb2.z,xb2.w};
    float w0 = w0p[c], w1 = w1p[c];
    #pragma unroll
    for (int j=0;j<8;j++){ a0[j] += w0*xs[j]; a1[j] += w1*xs[j]; }
  }
  float s20 = g2[o]   / sqrtf(v2[o]   + 1e-5f);
  float s21 = g2[o+1] / sqrtf(v2[o+1] + 1e-5f);
  float bi0 = b2[o]   - m2[o]*s20;
  float bi1 = b2[o+1] - m2[o+1]*s21;
  size_t base = (size_t)b*FU_C*FU_L + (size_t)o*FU_L + l;
  for (int j=0;j<nv;j++){
    float v0 = a0[j]*s20 + bi0; v0 = v0 >= 0.f ? v0 : 0.01f*v0;
    float v1 = a1[j]*s21 + bi1; v1 = v1 >= 0.f ? v1 : 0.01f*v1;
    mio[base + j]        = v0 + mio[base + j]        * x[base + j];
    mio[base + FU_L + j] = v1 + mio[base + FU_L + j] * x[base + FU_L + j];
  }
}

// ---------------- GNN fast path v7: no sXn (LN in place, node in place); 4 instances/block ----------------
__global__ __launch_bounds__(256) void fu_gnn7(const float* __restrict__ mmat, const float* __restrict__ ivmat,
                                               const float* __restrict__ xg,
                                               const float* __restrict__ wgm, const float* __restrict__ lna,
                                               const float* __restrict__ lnb, float* __restrict__ out){
  __shared__ float sX[4][676], sA[4][676], sWg[676], sLa[26], sLb[26];
  const int g = threadIdx.x >> 6;   // instance 0..3 (one wave each)
  const int t = threadIdx.x & 63;
  const size_t n = (size_t)blockIdx.x*4 + g;
  const float* Mrow = mmat + n*676;
  const float* Irow = ivmat + n*676;
  const float* Xres = xg + n*676;
  for (int i=t;i<676;i+=64)
    sX[g][i] = Irow[i] + Mrow[i]*Xres[i];
  if (g == 0){
    for (int i=t;i<676;i+=64) sWg[i] = wgm[i];
    if (t < 26){ sLa[t] = lna[t]; sLb[t] = lnb[t]; }
  }
  __syncthreads();
  // phase 1: 52 lanes; 2 lanes per softmax column -> sA; then LN per row IN PLACE into sX.
  // Single wave per instance: all softmax reads of sX precede LN writes in program order.
  if (t < 52){
    const int cr = t >> 1;          // column (softmax) / row (LN) 0..25
    const int h0 = (t & 1)*13;
    float mx = -1e30f;
    #pragma unroll
    for (int k=0;k<13;k++) mx = fmaxf(mx, sX[g][(h0+k)*26 + cr]);
    mx = fmaxf(mx, __shfl_xor(mx, 1));
    float sum = 0.f;
    #pragma unroll
    for (int k=0;k<13;k++){
      float e = __expf(sX[g][(h0+k)*26 + cr] - mx);
      sA[g][cr*26 + h0 + k] = e;
      sum += e;
    }
    sum += __shfl_xor(sum, 1);
    float inv = 1.f/sum;
    #pragma unroll
    for (int k=0;k<13;k++) sA[g][cr*26 + h0 + k] *= inv;
    // LayerNorm row cr in place
    float s = 0.f;
    #pragma unroll
    for (int k=0;k<13;k++) s += sX[g][cr*26 + h0 + k];
    s += __shfl_xor(s, 1);
    float mean = s * (1.f/26.f);
    float var = 0.f;
    #pragma unroll
    for (int k=0;k<13;k++){ float d = sX[g][cr*26 + h0 + k] - mean; var += d*d; }
    var += __shfl_xor(var, 1);
    var *= (1.f/25.f);
    float invd = 1.f/(sqrtf(var) + 1e-6f);
    #pragma unroll
    for (int k=0;k<13;k++){
      int v = h0 + k;
      sX[g][cr*26 + v] = sLa[v]*(sX[g][cr*26 + v] - mean)*invd + sLb[v];
    }
  }
  __syncthreads();
  // phase 3: node = A @ Xn, IN PLACE column-wise (iteration k touches only columns {k, 13+k};
  // all reads of a column precede its store in program order within the wave).
  {
    const int r = t >> 1;
    if (r < 26){
      const int v0 = (t & 1)*13;
      float ar[26];
      #pragma unroll
      for (int h=0;h<26;h++) ar[h] = sA[g][r*26 + h];
      #pragma unroll
      for (int k=0;k<13;k++){
        int v = v0 + k;
        float s = 0.f;
        #pragma unroll
        for (int h=0;h<26;h++) s += ar[h]*sX[g][h*26 + v];
        sX[g][r*26 + v] = s;
      }
    }
  }
  __syncthreads();
  // phase 4: out = relu(node @ Wg) + x. 2 threads/row.
  {
    const int r = t >> 1;
    if (r < 26){
      const int u0 = (t & 1)*13;
      float nr[26];
      #pragma unroll
      for (int v=0;v<26;v++) nr[v] = sX[g][r*26 + v];
      #pragma unroll
      for (int k=0;k<13;k++){
        int u = u0 + k;
        float s = 0.f;
        #pragma unroll
        for (int v=0;v<26;v++) s += nr[v]*sWg[v*26 + u];
        out[n*676 + r*26 + u] = fmaxf(s, 0.f) + Xres[r*26 + u];
      }
    }
  }
}

// ---------------- GNN (fallback): combined input ----------------
__global__ __launch_bounds__(64) void fu_gnn(const float* __restrict__ xmat, const float* __restrict__ xg,
                                             const float* __restrict__ wgm, const float* __restrict__ lna,
                                             const float* __restrict__ lnb, float* __restrict__ out){
  __shared__ float sX[676], sA[676], sXn[676], sWg[676], sLa[26], sLb[26];
  int n = blockIdx.x;
  int t = threadIdx.x;
  const float* Xrow = xmat + (size_t)n*676;
  for (int i=t;i<676;i+=64){ sX[i] = Xrow[i]; sWg[i] = wgm[i]; }
  if (t < 26){ sLa[t] = lna[t]; sLb[t] = lnb[t]; }
  __syncthreads();
  if (t < 26){
    float mx = -1e30f;
    #pragma unroll
    for (int h=0;h<26;h++) mx = fmaxf(mx, sX[h*26 + t]);
    float sum = 0.f;
    #pragma unroll
    for (int h=0;h<26;h++){ float e = __expf(sX[h*26 + t] - mx); sA[t*26 + h] = e; sum += e; }
    float inv = 1.f/sum;
    #pragma unroll
    for (int h=0;h<26;h++) sA[t*26 + h] *= inv;
  } else if (t >= 32 && t < 58){
    int r = t - 32;
    float s = 0.f;
    #pragma unroll
    for (int v=0;v<26;v++) s += sX[r*26 + v];
    float mean = s * (1.f/26.f);
    float var = 0.f;
    #pragma unroll
    for (int v=0;v<26;v++){ float d = sX[r*26 + v] - mean; var += d*d; }
    var *= (1.f/25.f);
    float invd = 1.f/(sqrtf(var) + 1e-6f);
    #pragma unroll
    for (int v=0;v<26;v++) sXn[r*26 + v] = sLa[v]*(sX[r*26 + v] - mean)*invd + sLb[v];
  }
  __syncthreads();
  for (int i=t;i<676;i+=64){
    int wi = i/26, v = i - wi*26;
    float s = 0.f;
    #pragma unroll
    for (int h=0;h<26;h++) s += sA[wi*26 + h]*sXn[h*26 + v];
    sX[i] = s;
  }
  __syncthreads();
  for (int i=t;i<676;i+=64){
    int wi = i/26, u = i - wi*26;
    float s = 0.f;
    #pragma unroll
    for (int v=0;v<26;v++) s += sX[wi*26 + v]*sWg[v*26 + u];
    out[(size_t)n*676 + i] = fmaxf(s, 0.f) + xg[(size_t)n*676 + i];
  }
}

// ================= fast-path kernels =================

__global__ __launch_bounds__(256) void fu_cvt_x(const float* __restrict__ x, unsigned short* __restrict__ d16){
  int i4 = (blockIdx.x*256 + threadIdx.x)*4;
  if (i4 >= 22151168) return;
  float4 v = *(const float4*)(x + i4);
  unsigned short h0,h1,h2,h3,l0,l1,l2,l3;
  fu_hilo(v.x,h0,l0); fu_hilo(v.y,h1,l1); fu_hilo(v.z,h2,l2); fu_hilo(v.w,h3,l3);
  uint2 hp, lp;
  hp.x = (unsigned)h0 | ((unsigned)h1<<16); hp.y = (unsigned)h2 | ((unsigned)h3<<16);
  lp.x = (unsigned)l0 | ((unsigned)l1<<16); lp.y = (unsigned)l2 | ((unsigned)l3<<16);
  *(uint2*)(d16 + FU_U16_XHI + i4) = hp;
  *(uint2*)(d16 + FU_U16_XLO + i4) = lp;
}

// Bm [o][l] -> hi/lo row-major [o][l] AND FRAGMENT-MAJOR transposed: off=((o>>5)*676+l)*32+(o&31)
__global__ __launch_bounds__(256) void fu_cvt_bm2(const float* __restrict__ bm, unsigned short* __restrict__ big16){
  __shared__ float t[32][33];
  const int b = blockIdx.z;
  const int l0 = blockIdx.x*32, o0 = blockIdx.y*32;
  const int tx = threadIdx.x & 31, ty = threadIdx.x >> 5;
  const float* src = bm + (size_t)b*FU_CQ*FU_L;
  #pragma unroll
  for (int q=0;q<4;q++){
    int o = o0 + ty + 8*q, l = l0 + tx;
    float v = (l < FU_L) ? src[(size_t)o*FU_L + l] : 0.f;
    t[ty+8*q][tx] = v;
    if (l < FU_L){
      unsigned short h, lo;
      fu_hilo(v, h, lo);
      big16[FU_U16_BMHI + (size_t)b*86528 + (size_t)o*FU_L + l] = h;
      big16[FU_U16_BMLO + (size_t)b*86528 + (size_t)o*FU_L + l] = lo;
    }
  }
  __syncthreads();
  #pragma unroll
  for (int q=0;q<4;q++){
    int l = l0 + ty + 8*q, o = o0 + tx;
    if (l < FU_L){
      unsigned short h, lo;
      fu_hilo(t[tx][ty+8*q], h, lo);
      unsigned off = ((unsigned)(o >> 5)*676u + (unsigned)l)*32u + (unsigned)(o & 31);
      big16[FU_U16_BMTHI + (size_t)b*86528 + off] = h;
      big16[FU_U16_BMTLO + (size_t)b*86528 + off] = lo;
    }
  }
}

// m2_w row-major hi/lo; conv2_w FRAGMENT-MAJOR hi/lo: off = ((c>>5)*512 + o)*32 + (c&31)
__global__ __launch_bounds__(256) void fu_prep2(const float* __restrict__ m2w, const float* __restrict__ c2w,
                                                const float* __restrict__ g2, const float* __restrict__ b2,
                                                const float* __restrict__ m2, const float* __restrict__ v2,
                                                unsigned short* __restrict__ m2hl, unsigned short* __restrict__ w2hl,
                                                float* __restrict__ s2, float* __restrict__ bi2){
  int i = blockIdx.x*256 + threadIdx.x;
  if (i < 262144){
    int o = i >> 9, c = i & 511;
    unsigned short h, l;
    fu_hilo(m2w[i], h, l);
    m2hl[i] = h; m2hl[262144 + i] = l;
    fu_hilo(c2w[i], h, l);
    unsigned off = ((unsigned)(c >> 5)*512u + (unsigned)o)*32u + (unsigned)(c & 31);
    w2hl[off] = h; w2hl[262144 + off] = l;
  }
  if (i < 512){
    float s = g2[i] / sqrtf(v2[i] + 1e-5f);
    s2[i] = s;
    bi2[i] = b2[i] - m2[i]*s;
  }
}

// G[b,o,c] = sum_l Bm[o,l]*x[c,l] — 64x64 wave tiles, grid (4,1,64)
__global__ __launch_bounds__(256) void fu_mfma_G(const unsigned short* __restrict__ d16,
                                                 unsigned short* __restrict__ big16){
  const int b = blockIdx.z;
  const int n0 = blockIdx.x * 128;
  const int tid = threadIdx.x;
  const int lane = tid & 63, wid = tid >> 6;
  const int wm = wid >> 1, wn = wid & 1;
  const int lr = lane & 15, lk = lane >> 4;

  const unsigned short* bmh = big16 + FU_U16_BMHI + (size_t)b*86528;
  const unsigned short* bml = big16 + FU_U16_BMLO + (size_t)b*86528;
  const unsigned short* xh  = d16 + FU_U16_XHI + (size_t)b*346112;
  const unsigned short* xl  = d16 + FU_U16_XLO + (size_t)b*346112;

  fu_f32x4 acc[4][4];
  #pragma unroll
  for (int i=0;i<4;i++)
    #pragma unroll
    for (int j=0;j<4;j++) acc[i][j] = fu_f32x4{0.f,0.f,0.f,0.f};

  int arow[4], brow[4];
  #pragma unroll
  for (int i=0;i<4;i++) arow[i] = wm*64 + i*16 + lr;
  #pragma unroll
  for (int j=0;j<4;j++) brow[j] = n0 + wn*64 + j*16 + lr;

  for (int ks=0; ks<21; ks++){
    int k0 = ks*32 + lk*8;
    FuFrag ah[4], al[4], bh[4], bl[4];
    #pragma unroll
    for (int i=0;i<4;i++){
      const unsigned short* ph = bmh + (size_t)arow[i]*676 + k0;
      const unsigned short* pl = bml + (size_t)arow[i]*676 + k0;
      ah[i].u2[0] = *(const uint2*)(ph); ah[i].u2[1] = *(const uint2*)(ph+4);
      al[i].u2[0] = *(const uint2*)(pl); al[i].u2[1] = *(const uint2*)(pl+4);
    }
    #pragma unroll
    for (int j=0;j<4;j++){
      const unsigned short* ph = xh + (size_t)brow[j]*676 + k0;
      const unsigned short* pl = xl + (size_t)brow[j]*676 + k0;
      bh[j].u2[0] = *(const uint2*)(ph); bh[j].u2[1] = *(const uint2*)(ph+4);
      bl[j].u2[0] = *(const uint2*)(pl); bl[j].u2[1] = *(const uint2*)(pl+4);
    }
    #pragma unroll
    for (int i=0;i<4;i++)
      #pragma unroll
      for (int j=0;j<4;j++){
        acc[i][j] = fu_mm(ah[i], bh[j], acc[i][j]);
        acc[i][j] = fu_mm(ah[i], bl[j], acc[i][j]);
        acc[i][j] = fu_mm(al[i], bh[j], acc[i][j]);
      }
  }
  { // tail k=672..675 (lk==0 only)
    FuFrag ah[4], al[4], bh[4], bl[4];
    #pragma unroll
    for (int i=0;i<4;i++){
      ah[i].u4 = make_uint4(0,0,0,0); al[i].u4 = make_uint4(0,0,0,0);
      if (lk == 0){
        ah[i].u2[0] = *(const uint2*)(bmh + (size_t)arow[i]*676 + 672);
        al[i].u2[0] = *(const uint2*)(bml + (size_t)arow[i]*676 + 672);
      }
    }
    #pragma unroll
    for (int j=0;j<4;j++){
      bh[j].u4 = make_uint4(0,0,0,0); bl[j].u4 = make_uint4(0,0,0,0);
      if (lk == 0){
        bh[j].u2[0] = *(const uint2*)(xh + (size_t)brow[j]*676 + 672);
        bl[j].u2[0] = *(const uint2*)(xl + (size_t)brow[j]*676 + 672);
      }
    }
    #pragma unroll
    for (int i=0;i<4;i++)
      #pragma unroll
      for (int j=0;j<4;j++){
        acc[i][j] = fu_mm(ah[i], bh[j], acc[i][j]);
        acc[i][j] = fu_mm(ah[i], bl[j], acc[i][j]);
        acc[i][j] = fu_mm(al[i], bh[j], acc[i][j]);
      }
  }
  unsigned short* gh = big16 + FU_U16_GHI + (size_t)b*65536;
  unsigned short* gl = big16 + FU_U16_GLO + (size_t)b*65536;
  #pragma unroll
  for (int i=0;i<4;i++){
    #pragma unroll
    for (int r=0;r<4;r++){
      int o = wm*64 + i*16 + lk*4 + r;
      #pragma unroll
      for (int j=0;j<4;j++){
        int ccol = n0 + wn*64 + j*16 + lr;
        unsigned short h, l;
        fu_hilo(acc[i][j][r], h, l);
        gh[(size_t)o*512 + ccol] = h;
        gl[(size_t)o*512 + ccol] = l;
      }
    }
  }
}

// V[b,o,s] = (1/676) sum_c G[o,c]*M2[s,c] — 64x64 wave tiles, grid (4,1,64)
__global__ __launch_bounds__(256) void fu_mfma_V2(const unsigned short* __restrict__ big16,
                                                  const unsigned short* __restrict__ m2hl,
                                                  float* __restrict__ vout){
  const int b = blockIdx.z;
  const int n0 = blockIdx.x * 128;
  const int tid = threadIdx.x;
  const int lane = tid & 63, wid = tid >> 6;
  const int wm = wid >> 1, wn = wid & 1;
  const int lr = lane & 15, lk = lane >> 4;

  const unsigned short* gh = big16 + FU_U16_GHI + (size_t)b*65536;
  const unsigned short* gl = big16 + FU_U16_GLO + (size_t)b*65536;
  const unsigned short* mh = m2hl;
  const unsigned short* ml = m2hl + 262144;

  fu_f32x4 acc[4][4];
  #pragma unroll
  for (int i=0;i<4;i++)
    #pragma unroll
    for (int j=0;j<4;j++) acc[i][j] = fu_f32x4{0.f,0.f,0.f,0.f};

  int arow[4], brow[4];
  #pragma unroll
  for (int i=0;i<4;i++) arow[i] = wm*64 + i*16 + lr;
  #pragma unroll
  for (int j=0;j<4;j++) brow[j] = n0 + wn*64 + j*16 + lr;

  for (int ks=0; ks<16; ks++){
    int k0 = ks*32 + lk*8;
    FuFrag ah[4], al[4], bh[4], bl[4];
    #pragma unroll
    for (int i=0;i<4;i++){
      ah[i].u4 = *(const uint4*)(gh + (size_t)arow[i]*512 + k0);
      al[i].u4 = *(const uint4*)(gl + (size_t)arow[i]*512 + k0);
    }
    #pragma unroll
    for (int j=0;j<4;j++){
      bh[j].u4 = *(const uint4*)(mh + (size_t)brow[j]*512 + k0);
      bl[j].u4 = *(const uint4*)(ml + (size_t)brow[j]*512 + k0);
    }
    #pragma unroll
    for (int i=0;i<4;i++)
      #pragma unroll
      for (int j=0;j<4;j++){
        acc[i][j] = fu_mm(ah[i], bh[j], acc[i][j]);
        acc[i][j] = fu_mm(ah[i], bl[j], acc[i][j]);
        acc[i][j] = fu_mm(al[i], bh[j], acc[i][j]);
      }
  }
  const float inv = 1.0f/676.0f;
  #pragma unroll
  for (int i=0;i<4;i++)
    #pragma unroll
    for (int r=0;r<4;r++){
      int o = wm*64 + i*16 + lk*4 + r;
      #pragma unroll
      for (int j=0;j<4;j++){
        int s = n0 + wn*64 + j*16 + lr;
        vout[((size_t)b*FU_CQ + o)*FU_C + s] = acc[i][j][r]*inv;
      }
    }
}

// V f32 [o][s] -> VT hi/lo FRAGMENT-MAJOR: off = ((o>>5)*512 + s)*32 + (o&31)
__global__ __launch_bounds__(256) void fu_cvt_vt(const float* __restrict__ v, unsigned short* __restrict__ vt16){
  __shared__ float t[32][33];
  const int b = blockIdx.z;
  const int s0 = blockIdx.x*32, o0 = blockIdx.y*32;
  const int tx = threadIdx.x & 31, ty = threadIdx.x >> 5;
  const float* src = v + (size_t)b*FU_CQ*FU_C;
  #pragma unroll
  for (int q=0;q<4;q++){
    int o = o0 + ty + 8*q, s = s0 + tx;
    t[ty+8*q][tx] = src[(size_t)o*FU_C + s];
  }
  __syncthreads();
  #pragma unroll
  for (int q=0;q<4;q++){
    int s = s0 + ty + 8*q, o = o0 + tx;
    unsigned short h, lo;
    fu_hilo(t[tx][ty+8*q], h, lo);
    unsigned off = ((unsigned)(o >> 5)*512u + (unsigned)s)*32u + (unsigned)(o & 31);
    vt16[(size_t)b*65536 + off] = h;
    vt16[FU_U16_VTLO + (size_t)b*65536 + off] = lo;
  }
}

// y[l,s] = sum_c BmT[l,c]*VT[s,c] — fragment-major operands, streamed B, grid (4,6,64)
__global__ __launch_bounds__(256, 4) void fu_mfma_y(const unsigned short* __restrict__ big16,
                                                    const unsigned short* __restrict__ vt16,
                                                    float* __restrict__ yout){
  const int b = blockIdx.z;
  const int n0 = blockIdx.x * 128;
  const int m0 = blockIdx.y * 128;
  const int tid = threadIdx.x;
  const int lane = tid & 63, wid = tid >> 6;
  const int wm = wid >> 1, wn = wid & 1;
  const int lr = lane & 15, lk = lane >> 4;

  const unsigned short* ath = big16 + FU_U16_BMTHI + (size_t)b*86528;
  const unsigned short* atl = big16 + FU_U16_BMTLO + (size_t)b*86528;
  const unsigned short* bth = vt16 + (size_t)b*65536;
  const unsigned short* btl = vt16 + FU_U16_VTLO + (size_t)b*65536;

  fu_f32x4 acc[4][4];
  #pragma unroll
  for (int i=0;i<4;i++)
    #pragma unroll
    for (int j=0;j<4;j++) acc[i][j] = fu_f32x4{0.f,0.f,0.f,0.f};

  int arow[4], brow[4];
  #pragma unroll
  for (int i=0;i<4;i++){
    int l = m0 + wm*64 + i*16 + lr;
    arow[i] = l < FU_L ? l : (FU_L-1);
  }
  #pragma unroll
  for (int j=0;j<4;j++) brow[j] = n0 + wn*64 + j*16 + lr;

  for (int ks=0; ks<4; ks++){
    FuFrag ah[4], al[4];
    #pragma unroll
    for (int i=0;i<4;i++){
      size_t off = ((size_t)ks*676 + arow[i])*32 + lk*8;
      ah[i].u4 = *(const uint4*)(ath + off);
      al[i].u4 = *(const uint4*)(atl + off);
    }
    #pragma unroll
    for (int j=0;j<4;j++){
      FuFrag bh, bl;
      size_t off = ((size_t)ks*512 + brow[j])*32 + lk*8;
      bh.u4 = *(const uint4*)(bth + off);
      bl.u4 = *(const uint4*)(btl + off);
      #pragma unroll
      for (int i=0;i<4;i++){
        acc[i][j] = fu_mm(ah[i], bh, acc[i][j]);
        acc[i][j] = fu_mm(ah[i], bl, acc[i][j]);
        acc[i][j] = fu_mm(al[i], bh, acc[i][j]);
      }
    }
  }
  #pragma unroll
  for (int i=0;i<4;i++){
    #pragma unroll
    for (int r=0;r<4;r++){
      int l = m0 + wm*64 + i*16 + lk*4 + r;
      if (l < FU_L){
        #pragma unroll
        for (int j=0;j<4;j++){
          int s = n0 + wn*64 + j*16 + lr;
          yout[(size_t)b*346112 + (size_t)l*FU_C + s] = acc[i][j][r];
        }
      }
    }
  }
}

// transpose+cvt: yflat (b,[c][l]) -> yvt FRAGMENT-MAJOR: off = ((c>>5)*676 + l2)*32 + (c&31)
__global__ __launch_bounds__(256) void fu_tr_y(const float* __restrict__ yf, unsigned short* __restrict__ big16){
  __shared__ float t[32][33];
  const int b = blockIdx.z;
  const int l0 = blockIdx.x*32, c0 = blockIdx.y*32;
  const int tx = threadIdx.x & 31, ty = threadIdx.x >> 5;
  const float* yb = yf + (size_t)b*FU_C*FU_L;
  #pragma unroll
  for (int q=0;q<4;q++){
    int c = c0 + ty + 8*q;
    int l = l0 + tx;
    t[ty + 8*q][tx] = (l < FU_L) ? yb[(size_t)c*FU_L + l] : 0.f;
  }
  __syncthreads();
  unsigned short* yh = big16 + FU_U16_YVHI + (size_t)b*346112;
  unsigned short* yl = big16 + FU_U16_YVLO + (size_t)b*346112;
  #pragma unroll
  for (int q=0;q<4;q++){
    int l2 = l0 + ty + 8*q;
    if (l2 < FU_L){
      int c = c0 + tx;
      unsigned short h, l;
      fu_hilo(t[tx][ty + 8*q], h, l);
      unsigned off = ((unsigned)(c >> 5)*676u + (unsigned)l2)*32u + (unsigned)(c & 31);
      yh[off] = h;
      yl[off] = l;
    }
  }
}

// conv2 MFMA + BN2 + leaky -> iv (write-only into d_out; X=iv+m*x deferred to gnn7)
__global__ __launch_bounds__(256, 4) void fu_mfma_c2(const unsigned short* __restrict__ big16,
                                                     const unsigned short* __restrict__ w2hl,
                                                     const float* __restrict__ s2, const float* __restrict__ bi2,
                                                     float* __restrict__ ivout){
  const int flat = blockIdx.x;                       // 1536 = 64 b x 24 tiles
  const int swz  = (flat & 7)*192 + (flat >> 3);     // bijective; each XCD owns 8 whole batches
  const int b    = swz / 24;
  const int rem  = swz - b*24;
  const int mt   = rem / 6;
  const int lt   = rem - mt*6;
  const int m0 = mt * 128;                           // o tile
  const int n0 = lt * 128;                           // l2 tile
  const int tid = threadIdx.x;
  const int lane = tid & 63, wid = tid >> 6;
  const int wm = wid >> 1, wn = wid & 1;
  const int lr = lane & 15, lk = lane >> 4;

  const unsigned short* wh = w2hl;
  const unsigned short* wl = w2hl + 262144;
  const unsigned short* yh = big16 + FU_U16_YVHI + (size_t)b*346112;
  const unsigned short* yl = big16 + FU_U16_YVLO + (size_t)b*346112;

  fu_f32x4 acc[4][4];
  #pragma unroll
  for (int i=0;i<4;i++)
    #pragma unroll
    for (int j=0;j<4;j++) acc[i][j] = fu_f32x4{0.f,0.f,0.f,0.f};

  int arow[4], brow[4];
  #pragma unroll
  for (int i=0;i<4;i++) arow[i] = m0 + wm*64 + i*16 + lr;     // o < 512
  #pragma unroll
  for (int j=0;j<4;j++){
    int l2 = n0 + wn*64 + j*16 + lr;
    brow[j] = l2 < FU_L ? l2 : (FU_L-1);
  }

  for (int ks=0; ks<16; ks++){
    FuFrag ah[4], al[4];
    #pragma unroll
    for (int i=0;i<4;i++){
      size_t off = ((size_t)ks*512 + arow[i])*32 + lk*8;      // fragment-major W2
      ah[i].u4 = *(const uint4*)(wh + off);
      al[i].u4 = *(const uint4*)(wl + off);
    }
    #pragma unroll
    for (int j=0;j<4;j++){
      FuFrag bh, bl;
      size_t off = ((size_t)ks*676 + brow[j])*32 + lk*8;      // fragment-major yvt
      bh.u4 = *(const uint4*)(yh + off);
      bl.u4 = *(const uint4*)(yl + off);
      #pragma unroll
      for (int i=0;i<4;i++){
        acc[i][j] = fu_mm(ah[i], bh, acc[i][j]);
        acc[i][j] = fu_mm(ah[i], bl, acc[i][j]);
        acc[i][j] = fu_mm(al[i], bh, acc[i][j]);
      }
    }
  }
  #pragma unroll
  for (int i=0;i<4;i++){
    #pragma unroll
    for (int r=0;r<4;r++){
      int o = m0 + wm*64 + i*16 + lk*4 + r;
      float sv = s2[o], bv = bi2[o];
      #pragma unroll
      for (int j=0;j<4;j++){
        int l2 = n0 + wn*64 + j*16 + lr;
        if (l2 < FU_L){
          float v = acc[i][j][r]*sv + bv;
          v = v >= 0.f ? v : 0.01f*v;
          ivout[((size_t)b*FU_C + o)*FU_L + l2] = v;
        }
      }
    }
  }
}

extern "C" void kernel_launch(void* const* d_in, const int* in_sizes, int n_in,
                              void* d_out, int out_size, void* d_ws, size_t ws_size,
                              hipStream_t stream){
  const float* x   = (const float*)d_in[0];
  const float* cw  = (const float*)d_in[1];
  const float* g1  = (const float*)d_in[2];
  const float* b1  = (const float*)d_in[3];
  const float* m1  = (const float*)d_in[4];
  const float* v1  = (const float*)d_in[5];
  const float* m1w = (const float*)d_in[6];
  const float* m2w = (const float*)d_in[7];
  const float* c2w = (const float*)d_in[8];
  const float* g2  = (const float*)d_in[9];
  const float* b2  = (const float*)d_in[10];
  const float* m2  = (const float*)d_in[11];
  const float* v2  = (const float*)d_in[12];
  const float* wg  = (const float*)d_in[13];
  const float* lna = (const float*)d_in[14];
  const float* lnb = (const float*)d_in[15];
  float* out = (float*)d_out;
  float* ws = (float*)d_ws;

  if (ws_size >= (size_t)FU_FAST_FLOATS * 4u){
    unsigned short* d16   = (unsigned short*)d_out;
    unsigned short* big16 = (unsigned short*)(ws + FU_OFF_BIG);
    unsigned short* vt16  = (unsigned short*)(ws + FU_OFF_V);
    unsigned short* m2hl  = (unsigned short*)(ws + FU_OFF_M2HL);
    unsigned short* w2hl  = (unsigned short*)(ws + FU_OFF_W2HL);
    float* wt1 = ws + FU_OFF_V;   // 65536 floats; dead until fu_cvt_vt

    fu_sim3<<<dim3(11,64,4), 256, 0, stream>>>(x, ws + FU_OFF_BIG);
    fu_sim_red<<<1353, 256, 0, stream>>>(ws + FU_OFF_BIG, ws + FU_OFF_SIM);
    fu_conv1b<<<dim3(64,16), 256, 0, stream>>>(cw, g1, b1, m1, v1, ws + FU_OFF_SIM, ws + FU_OFF_MBUF);
    fu_tr_w1<<<dim3(4,16), 256, 0, stream>>>(m1w, wt1);
    fu_gemm_bm<<<768, 256, 0, stream>>>(wt1, x, ws + FU_OFF_BM);
    fu_prep2<<<1024, 256, 0, stream>>>(m2w, c2w, g2, b2, m2, v2, m2hl, w2hl,
                                       ws + FU_OFF_S2, ws + FU_OFF_BI2);
    fu_cvt_x<<<21632, 256, 0, stream>>>(x, d16);
    fu_cvt_bm2<<<dim3(22,4,64), 256, 0, stream>>>(ws + FU_OFF_BM, big16);
    fu_mfma_G<<<dim3(4,1,64), 256, 0, stream>>>(d16, big16);
    fu_mfma_V2<<<dim3(4,1,64), 256, 0, stream>>>(big16, m2hl, ws + FU_OFF_BM);
    fu_cvt_vt<<<dim3(16,4,64), 256, 0, stream>>>(ws + FU_OFF_BM, vt16);
    fu_mfma_y<<<dim3(4,6,64), 256, 0, stream>>>(big16, vt16, out);
    fu_tr_y<<<dim3(22,16,64), 256, 0, stream>>>(out, big16);
    fu_mfma_c2<<<1536, 256, 0, stream>>>(big16, w2hl, ws + FU_OFF_S2, ws + FU_OFF_BI2, out);  // iv -> d_out
    fu_gnn7<<<8192, 256, 0, stream>>>(ws + FU_OFF_MBUF, out, x, wg, lna, lnb, out);
  } else if (ws_size >= (size_t)FU_FB_FLOATS * 4u){
    // fallback: round-5 pipeline
    FoldUnfoldModule_82592221102582_kernel<<<2048, 256, 0, stream>>>(out, out_size, 20.0f);
    fu_sim2<<<dim3(11,64), 256, 0, stream>>>(x, ws + FU_FB_SIM);
    fu_conv1b<<<dim3(64,16), 256, 0, stream>>>(cw, g1, b1, m1, v1, ws + FU_FB_SIM, ws + FU_FB_MBUF);
    fu_gemm_bm_fb<<<dim3(3,4,64), 256, 0, stream>>>(m1w, x, ws + FU_FB_BM);
    fu_gemm_b2<<<dim3(3,32,64), 256, 0, stream>>>(m2w, x, out);
    fu_V<<<dim3(8,2,64), 256, 0, stream>>>(ws + FU_FB_BM, out, ws + FU_FB_V);
    fu_y<<<dim3(8,11,64), 256, 0, stream>>>(ws + FU_FB_BM, ws + FU_FB_V, out);
    fu_c2<<<dim3(3,32,64), 256, 0, stream>>>(out, c2w, g2, b2, m2, v2, x, ws + FU_FB_MBUF);
    fu_gnn<<<32768, 64, 0, stream>>>(ws + FU_FB_MBUF, x, wg, lna, lnb, out);
  } else {
    FoldUnfoldModule_82592221102582_kernel<<<2048, 256, 0, stream>>>(out, out_size, 48.5f);
  }
}

// Round 27
// 855.654 us; speedup vs baseline: 1.0723x; 1.0075x over previous
//
#include <hip/hip_runtime.h>

static constexpr int FU_L  = 676;   // 26*26
static constexpr int FU_H  = 26;
static constexpr int FU_C  = 512;
static constexpr int FU_CQ = 128;   // C/4

// ================= fast-path ws layout (floats) =================
static constexpr unsigned FU_OFF_MBUF = 0u;          // 22151168  m (conv1 out)
static constexpr unsigned FU_OFF_BM   = 22151168u;   //  5537792  Bm f32 [o][l]; later V f32 [o][s]
static constexpr unsigned FU_OFF_BIG  = 27688960u;   // 22151168  phase0: sim partials; phase1: BmHL/BmTHL/GHL; phase2: yvt-HL
static constexpr unsigned FU_OFF_V    = 49840128u;   //  4194304  WT (early); later VT hi/lo u16 (fragment-major)
static constexpr unsigned FU_OFF_SIM  = 54034432u;   //   389376  sim (b,9,676)
static constexpr unsigned FU_OFF_M2HL = 54423808u;   //   262144  m2_w hi/lo u16
static constexpr unsigned FU_OFF_W2HL = 54685952u;   //   262144  conv2_w hi/lo u16 (fragment-major)
static constexpr unsigned FU_OFF_S2   = 54948096u;   //      512
static constexpr unsigned FU_OFF_BI2  = 54948608u;   //      512
static constexpr unsigned FU_FAST_FLOATS = 54949120u;   // 219.8 MB

// fallback (round-5) layout
static constexpr unsigned FU_FB_MBUF = 0u;
static constexpr unsigned FU_FB_BM   = 22151168u;
static constexpr unsigned FU_FB_V    = 27688960u;
static constexpr unsigned FU_FB_SIM  = 31883264u;
static constexpr unsigned FU_FB_FLOATS = 32272640u;  // 129.1 MB

// u16 sub-offsets inside BIG (phase 1)
static constexpr unsigned FU_U16_BMHI  = 0u;
static constexpr unsigned FU_U16_BMLO  = 5537792u;
static constexpr unsigned FU_U16_BMTHI = 11075584u;  // fragment-major [(o>>5)][l][o&31]
static constexpr unsigned FU_U16_BMTLO = 16613376u;
static constexpr unsigned FU_U16_GHI   = 22151168u;
static constexpr unsigned FU_U16_GLO   = 26345472u;
// u16 sub-offsets inside BIG (phase 2): yvt fragment-major [kc][l2][ksub]
static constexpr unsigned FU_U16_YVHI  = 0u;
static constexpr unsigned FU_U16_YVLO  = 22151168u;
// u16 layout of d_out when used as scratch
static constexpr unsigned FU_U16_XHI   = 0u;
static constexpr unsigned FU_U16_XLO   = 22151168u;
// u16 sub-offsets inside VT region
static constexpr unsigned FU_U16_VTLO  = 4194304u;

typedef __bf16 fu_bf16x8 __attribute__((ext_vector_type(8)));
typedef float  fu_f32x4  __attribute__((ext_vector_type(4)));

union FuFrag {
  uint4 u4;
  uint2 u2[2];
  fu_bf16x8 bf;
};

__device__ __forceinline__ unsigned short fu_rnebf(float f){
  unsigned int u = __float_as_uint(f);
  u += 0x7fffu + ((u >> 16) & 1u);
  return (unsigned short)(u >> 16);
}
__device__ __forceinline__ void fu_hilo(float f, unsigned short& h, unsigned short& l){
  h = fu_rnebf(f);
  float fh = __uint_as_float(((unsigned int)h) << 16);
  l = fu_rnebf(f - fh);
}
__device__ __forceinline__ fu_f32x4 fu_mm(const FuFrag& a, const FuFrag& b, fu_f32x4 c){
  return __builtin_amdgcn_mfma_f32_16x16x32_bf16(a.bf, b.bf, c, 0, 0, 0);
}

// Identifier-named kernel; kept for symbol presence + diagnostics.
__global__ __launch_bounds__(256) void FoldUnfoldModule_82592221102582_kernel(
    float* __restrict__ out, int n, float val){
  int i = blockIdx.x*256 + threadIdx.x;
  int stride = gridDim.x*256;
  for (; i < n; i += stride) out[i] = val;
}

// ---------------- self-similarity v3: grid (11,64,4); 128 ch per block -> partials ----------------
__global__ __launch_bounds__(256) void fu_sim3(const float* __restrict__ x, float* __restrict__ psim){
  __shared__ float red[3][64][8];
  int lq = threadIdx.x & 63, cg = threadIdx.x >> 6;
  int l = blockIdx.x*64 + lq;
  int b = blockIdx.y;
  int z = blockIdx.z;
  bool lval = l < FU_L;
  int yy = l / FU_H, xx = l - yy*FU_H;
  int noff[8]; bool nval[8];
  #pragma unroll
  for (int t=1;t<9;t++){
    int di = t/3 - 1, dj = t%3 - 1;
    int y2 = yy + di, x2 = xx + dj;
    nval[t-1] = lval && (y2>=0 && y2<FU_H && x2>=0 && x2<FU_H);
    noff[t-1] = nval[t-1] ? (y2*FU_H + x2) : 0;
  }
  float acc[8] = {0,0,0,0,0,0,0,0};
  const float* xb = x + (size_t)b*FU_C*FU_L;
  int c0 = z*128 + cg*32;
  for (int c=c0; c<c0+32; c++){
    const float* row = xb + c*FU_L;
    float ctr = lval ? row[l] : 0.f;
    #pragma unroll
    for (int t=0;t<8;t++)
      if (nval[t]) acc[t] += row[noff[t]] * ctr;
  }
  if (cg > 0){
    #pragma unroll
    for (int t=0;t<8;t++) red[cg-1][lq][t] = acc[t];
  }
  __syncthreads();
  if (cg == 0 && lval){
    #pragma unroll
    for (int g=0;g<3;g++)
      #pragma unroll
      for (int t=0;t<8;t++) acc[t] += red[g][lq][t];
    float* pb = psim + ((size_t)z*64 + b)*8*FU_L;
    #pragma unroll
    for (int t=0;t<8;t++) pb[t*FU_L + l] = acc[t];
  }
}

// reduce 4 partials -> sim[b][9][676] (tap 0 zeroed)
__global__ __launch_bounds__(256) void fu_sim_red(const float* __restrict__ psim, float* __restrict__ simb){
  int i = blockIdx.x*256 + threadIdx.x;          // over 64*8*676
  const int tot = 64*8*FU_L;
  if (i >= tot) return;
  int b = i / (8*FU_L);
  int r = i - b*8*FU_L;                          // tap*676 + l, taps 1..8
  const size_t zs = (size_t)64*8*FU_L;
  float s = psim[(size_t)b*8*FU_L + r] + psim[zs + (size_t)b*8*FU_L + r]
          + psim[2*zs + (size_t)b*8*FU_L + r] + psim[3*zs + (size_t)b*8*FU_L + r];
  simb[(size_t)b*9*FU_L + FU_L + r] = s;
  if (i < 64*FU_L) simb[(size_t)(i/FU_L)*9*FU_L + (i%FU_L)] = 0.f;
}

// ---------------- self-similarity v2 (fallback path only) ----------------
__global__ __launch_bounds__(256) void fu_sim2(const float* __restrict__ x, float* __restrict__ simb){
  __shared__ float red[3][64][8];
  int lq = threadIdx.x & 63, cg = threadIdx.x >> 6;
  int l = blockIdx.x*64 + lq;
  int b = blockIdx.y;
  bool lval = l < FU_L;
  int yy = l / FU_H, xx = l - yy*FU_H;
  int noff[8]; bool nval[8];
  #pragma unroll
  for (int t=1;t<9;t++){
    int di = t/3 - 1, dj = t%3 - 1;
    int y2 = yy + di, x2 = xx + dj;
    nval[t-1] = lval && (y2>=0 && y2<FU_H && x2>=0 && x2<FU_H);
    noff[t-1] = nval[t-1] ? (y2*FU_H + x2) : 0;
  }
  float acc[8] = {0,0,0,0,0,0,0,0};
  const float* xb = x + (size_t)b*FU_C*FU_L;
  int c0 = cg*128;
  for (int c=c0; c<c0+128; c++){
    const float* row = xb + c*FU_L;
    float ctr = lval ? row[l] : 0.f;
    #pragma unroll
    for (int t=0;t<8;t++)
      if (nval[t]) acc[t] += row[noff[t]] * ctr;
  }
  if (cg > 0){
    #pragma unroll
    for (int t=0;t<8;t++) red[cg-1][lq][t] = acc[t];
  }
  __syncthreads();
  if (cg == 0 && lval){
    #pragma unroll
    for (int g=0;g<3;g++)
      #pragma unroll
      for (int t=0;t<8;t++) acc[t] += red[g][lq][t];
    float* sb = simb + (size_t)b*9*FU_L;
    sb[l] = 0.f;
    #pragma unroll
    for (int t=0;t<8;t++) sb[(t+1)*FU_L + l] = acc[t];
  }
}

// ---------------- conv1: padded-halo LDS, 3 l x 32 o per thread, scalar weights ----------------
__global__ __launch_bounds__(256) void fu_conv1b(const float* __restrict__ cw,
                                                 const float* __restrict__ g1, const float* __restrict__ b1,
                                                 const float* __restrict__ m1, const float* __restrict__ v1,
                                                 const float* __restrict__ simb, float* __restrict__ mbuf){
  __shared__ float sp[8][784];
  const int b  = blockIdx.x;
  const int o0 = blockIdx.y * 32;
  const int tid = threadIdx.x;
  const float* sb = simb + (size_t)b*9*FU_L;
  for (int i = tid; i < 8*784; i += 256){
    int ch = i / 784, p = i - ch*784;
    int py = p / 28, px = p - py*28;
    float v = 0.f;
    if (py >= 1 && py <= 26 && px >= 1 && px <= 26)
      v = sb[(ch+1)*FU_L + (py-1)*FU_H + (px-1)];
    sp[ch][p] = v;
  }
  __syncthreads();

  const int l0 = tid, l1 = tid + 256, l2 = tid + 512;
  const bool l2ok = l2 < FU_L;
  const int lc2 = l2ok ? l2 : 0;
  int yy, xx;
  yy = l0/FU_H; xx = l0 - yy*FU_H; const int pb0 = yy*28 + xx;
  yy = l1/FU_H; xx = l1 - yy*FU_H; const int pb1 = yy*28 + xx;
  yy = lc2/FU_H; xx = lc2 - yy*FU_H; const int pb2 = yy*28 + xx;

  for (int ot = 0; ot < 4; ot++){
    float acc[8][3];
    #pragma unroll
    for (int oo=0;oo<8;oo++){ acc[oo][0]=0.f; acc[oo][1]=0.f; acc[oo][2]=0.f; }
    for (int ch = 0; ch < 8; ch++){
      const float* spc = sp[ch];
      float sa[9], sbv[9], sc[9];
      #pragma unroll
      for (int dy=0; dy<3; dy++)
        #pragma unroll
        for (int dx=0; dx<3; dx++){
          int t = dy*3 + dx, off = dy*28 + dx;
          sa[t]  = spc[pb0 + off];
          sbv[t] = spc[pb1 + off];
          sc[t]  = spc[pb2 + off];
        }
      #pragma unroll
      for (int oo=0; oo<8; oo++){
        const float* wp = cw + (size_t)(o0 + ot*8 + oo)*81 + (ch+1)*9;
        #pragma unroll
        for (int t=0; t<9; t++){
          float w = wp[t];
          acc[oo][0] += w*sa[t];
          acc[oo][1] += w*sbv[t];
          acc[oo][2] += w*sc[t];
        }
      }
    }
    #pragma unroll
    for (int oo=0; oo<8; oo++){
      int o = o0 + ot*8 + oo;
      float s1 = g1[o] / sqrtf(v1[o] + 1e-5f);
      float bb = b1[o] - m1[o]*s1;
      size_t base = ((size_t)b*FU_C + o)*FU_L;
      float r0 = acc[oo][0]*s1 + bb; r0 = r0 >= 0.f ? r0 : 0.01f*r0;
      float r1 = acc[oo][1]*s1 + bb; r1 = r1 >= 0.f ? r1 : 0.01f*r1;
      float r2 = acc[oo][2]*s1 + bb; r2 = r2 >= 0.f ? r2 : 0.01f*r2;
      mbuf[base + l0] = r0;
      mbuf[base + l1] = r1;
      if (l2ok) mbuf[base + l2] = r2;
    }
  }
}

// ---------------- m1_w [o][c] -> WT [c][o] (128x512 -> 512x128) ----------------
__global__ __launch_bounds__(256) void fu_tr_w1(const float* __restrict__ w, float* __restrict__ wt){
  __shared__ float t[32][33];
  const int o0 = blockIdx.x*32;   // 4
  const int c0 = blockIdx.y*32;   // 16
  const int tx = threadIdx.x & 31, ty = threadIdx.x >> 5;
  #pragma unroll
  for (int q=0;q<4;q++)
    t[ty+8*q][tx] = w[(size_t)(o0+ty+8*q)*FU_C + c0+tx];
  __syncthreads();
  #pragma unroll
  for (int q=0;q<4;q++)
    wt[(size_t)(c0+ty+8*q)*FU_CQ + o0+tx] = t[tx][ty+8*q];
}

// ---------------- Bm = m1_w @ x via WT[c][o]; 4 o x 8 l per thread; flat 768 + XCD swizzle; unroll 8 ----------------
__global__ __launch_bounds__(256) void fu_gemm_bm(const float* __restrict__ WT, const float* __restrict__ x,
                                                  float* __restrict__ bmout){
  const int flat = blockIdx.x;                      // 768 = 64 b x (3 l-tiles x 4 o-tiles)
  const int swz  = (flat & 7)*96 + (flat >> 3);     // bijective; each XCD owns 8 whole batches
  const int b    = swz / 12;
  const int rem  = swz - b*12;
  const int ot   = rem / 3;                         // o-tile 0..3
  const int lt   = rem - ot*3;                      // l-tile 0..2
  int tid = threadIdx.x, p = tid & 31, og = tid >> 5;
  int l = lt*256 + p*8;
  int o = ot*32 + og*4;
  if (l >= FU_L) return;
  int nv = FU_L - l; if (nv > 8) nv = 8;
  bool hi_ok = (l + 8 <= FU_L);
  const float* inb = x + (size_t)b*FU_C*FU_L + l;
  float a[4][8] = {};
  #pragma unroll 8
  for (int c=0;c<FU_C;c++){
    const float* r = inb + c*FU_L;
    float4 xa = *(const float4*)(r);
    float4 xb2;
    if (hi_ok) xb2 = *(const float4*)(r + 4); else { xb2.x=0;xb2.y=0;xb2.z=0;xb2.w=0; }
    float xs[8] = {xa.x,xa.y,xa.z,xa.w,xb2.x,xb2.y,xb2.z,xb2.w};
    float4 wv = *(const float4*)(WT + (size_t)c*FU_CQ + o);
    #pragma unroll
    for (int j=0;j<8;j++){
      a[0][j] += wv.x*xs[j]; a[1][j] += wv.y*xs[j];
      a[2][j] += wv.z*xs[j]; a[3][j] += wv.w*xs[j];
    }
  }
  float* o0 = bmout + (size_t)b*FU_CQ*FU_L + o*FU_L + l;
  #pragma unroll
  for (int oo=0;oo<4;oo++)
    for (int j=0;j<nv;j++) o0[oo*FU_L + j] = a[oo][j];
}

// ---------------- fallback-only kernels (round-5 path) ----------------
__global__ __launch_bounds__(256) void fu_gemm_bm_fb(const float* __restrict__ W, const float* __restrict__ x,
                                                     float* __restrict__ bmout){
  int tid = threadIdx.x, p = tid & 31, og = tid >> 5;
  int l = blockIdx.x*256 + p*8;
  int o = blockIdx.y*32 + og*4;
  int b = blockIdx.z;
  if (l >= FU_L) return;
  int nv = FU_L - l; if (nv > 8) nv = 8;
  bool hi_ok = (l + 8 <= FU_L);
  const float* inb = x + (size_t)b*FU_C*FU_L + l;
  float a[4][8] = {};
  for (int c=0;c<FU_C;c++){
    const float* r = inb + c*FU_L;
    float4 xa = *(const float4*)(r);
    float4 xb2;
    if (hi_ok) xb2 = *(const float4*)(r + 4); else { xb2.x=0;xb2.y=0;xb2.z=0;xb2.w=0; }
    float xs[8] = {xa.x,xa.y,xa.z,xa.w,xb2.x,xb2.y,xb2.z,xb2.w};
    float w0 = W[(o+0)*FU_C + c], w1 = W[(o+1)*FU_C + c];
    float w2 = W[(o+2)*FU_C + c], w3 = W[(o+3)*FU_C + c];
    #pragma unroll
    for (int j=0;j<8;j++){
      a[0][j] += w0*xs[j]; a[1][j] += w1*xs[j];
      a[2][j] += w2*xs[j]; a[3][j] += w3*xs[j];
    }
  }
  float* o0 = bmout + (size_t)b*FU_CQ*FU_L + o*FU_L + l;
  #pragma unroll
  for (int oo=0;oo<4;oo++)
    for (int j=0;j<nv;j++) o0[oo*FU_L + j] = a[oo][j];
}

__global__ __launch_bounds__(256) void fu_gemm_b2(const float* __restrict__ W, const float* __restrict__ x,
                                                  float* __restrict__ b2out){
  int tid = threadIdx.x, p = tid & 31, og = tid >> 5;
  int l = blockIdx.x*256 + p*8;
  int o = blockIdx.y*16 + og*2;
  int b = blockIdx.z;
  if (l >= FU_L) return;
  int nv = FU_L - l; if (nv > 8) nv = 8;
  bool hi_ok = (l + 8 <= FU_L);
  const float* inb = x + (size_t)b*FU_C*FU_L + l;
  const float* w0p = W + o*FU_C;
  const float* w1p = w0p + FU_C;
  float a0[8] = {0,0,0,0,0,0,0,0};
  float a1[8] = {0,0,0,0,0,0,0,0};
  for (int c=0;c<FU_C;c++){
    const float* r = inb + c*FU_L;
    float4 xa = *(const float4*)(r);
    float4 xb2;
    if (hi_ok) xb2 = *(const float4*)(r + 4); else { xb2.x=0;xb2.y=0;xb2.z=0;xb2.w=0; }
    float xs[8] = {xa.x,xa.y,xa.z,xa.w,xb2.x,xb2.y,xb2.z,xb2.w};
    float w0 = w0p[c], w1 = w1p[c];
    #pragma unroll
    for (int j=0;j<8;j++){ a0[j] += w0*xs[j]; a1[j] += w1*xs[j]; }
  }
  float* o0 = b2out + (size_t)b*FU_C*FU_L + o*FU_L + l;
  for (int j=0;j<nv;j++){ o0[j] = a0[j]; o0[FU_L+j] = a1[j]; }
}

__global__ __launch_bounds__(256) void fu_V(const float* __restrict__ bm, const float* __restrict__ b2in,
                                            float* __restrict__ vout){
  int tid = threadIdx.x; int tx = tid & 15, ty = tid >> 4;
  int o = blockIdx.y*64 + ty*4;
  int s = blockIdx.x*64 + tx*4;
  int b = blockIdx.z;
  const float* A  = bm + (size_t)b*FU_CQ*FU_L;
  const float* Bt = b2in + (size_t)b*FU_C*FU_L;
  float acc[4][4] = {};
  for (int k=0;k<FU_L;k+=4){
    float4 av[4], bv[4];
    #pragma unroll
    for (int i=0;i<4;i++) av[i] = *(const float4*)(A + (o+i)*FU_L + k);
    #pragma unroll
    for (int j=0;j<4;j++) bv[j] = *(const float4*)(Bt + (s+j)*FU_L + k);
    #pragma unroll
    for (int i=0;i<4;i++){
      #pragma unroll
      for (int j=0;j<4;j++)
        acc[i][j] += av[i].x*bv[j].x + av[i].y*bv[j].y + av[i].z*bv[j].z + av[i].w*bv[j].w;
    }
  }
  #pragma unroll
  for (int i=0;i<4;i++)
    #pragma unroll
    for (int j=0;j<4;j++)
      vout[(size_t)b*FU_CQ*FU_C + (o+i)*FU_C + s + j] = acc[i][j]*(1.0f/676.0f);
}

__global__ __launch_bounds__(256) void fu_y(const float* __restrict__ bm, const float* __restrict__ v,
                                            float* __restrict__ yout){
  int tid = threadIdx.x; int tx = tid & 15, ty = tid >> 4;
  int l = blockIdx.y*64 + ty*4;
  int s = blockIdx.x*64 + tx*4;
  int b = blockIdx.z;
  if (l >= FU_L) return;
  const float* A  = bm + (size_t)b*FU_CQ*FU_L;
  const float* Vb = v  + (size_t)b*FU_CQ*FU_C;
  float acc[4][4] = {};
  for (int c=0;c<FU_CQ;c++){
    float4 av = *(const float4*)(A + c*FU_L + l);
    float4 bv = *(const float4*)(Vb + c*FU_C + s);
    float ai[4] = {av.x, av.y, av.z, av.w};
    float bj[4] = {bv.x, bv.y, bv.z, bv.w};
    #pragma unroll
    for (int i=0;i<4;i++)
      #pragma unroll
      for (int j=0;j<4;j++)
        acc[i][j] += ai[i]*bj[j];
  }
  #pragma unroll
  for (int i=0;i<4;i++)
    #pragma unroll
    for (int j=0;j<4;j++)
      yout[(size_t)b*FU_L*FU_C + (size_t)(l+i)*FU_C + s + j] = acc[i][j];
}

__global__ __launch_bounds__(256) void fu_c2(const float* __restrict__ yv, const float* __restrict__ W,
                                             const float* __restrict__ g2, const float* __restrict__ b2,
                                             const float* __restrict__ m2, const float* __restrict__ v2,
                                             const float* __restrict__ x, float* __restrict__ mio){
  int tid = threadIdx.x, p = tid & 31, og = tid >> 5;
  int l = blockIdx.x*256 + p*8;
  int o = blockIdx.y*16 + og*2;
  int b = blockIdx.z;
  if (l >= FU_L) return;
  int nv = FU_L - l; if (nv > 8) nv = 8;
  bool hi_ok = (l + 8 <= FU_L);
  const float* inb = yv + (size_t)b*FU_C*FU_L + l;
  const float* w0p = W + o*FU_C;
  const float* w1p = w0p + FU_C;
  float a0[8] = {0,0,0,0,0,0,0,0};
  float a1[8] = {0,0,0,0,0,0,0,0};
  for (int c=0;c<FU_C;c++){
    const float* r = inb + c*FU_L;
    float4 xa = *(const float4*)(r);
    float4 xb2;
    if (hi_ok) xb2 = *(const float4*)(r + 4); else { xb2.x=0;xb2.y=0;xb2.z=0;xb2.w=0; }
    float xs[8] = {xa.x,xa.y,xa.z,xa.w,xb2.x,xb2.y,xb2.z,xb2.w};
    float w0 = w0p[c], w1 = w1p[c];
    #pragma unroll
    for (int j=0;j<8;j++){ a0[j] += w0*xs[j]; a1[j] += w1*xs[j]; }
  }
  float s20 = g2[o]   / sqrtf(v2[o]   + 1e-5f);
  float s21 = g2[o+1] / sqrtf(v2[o+1] + 1e-5f);
  float bi0 = b2[o]   - m2[o]*s20;
  float bi1 = b2[o+1] - m2[o+1]*s21;
  size_t base = (size_t)b*FU_C*FU_L + (size_t)o*FU_L + l;
  for (int j=0;j<nv;j++){
    float v0 = a0[j]*s20 + bi0; v0 = v0 >= 0.f ? v0 : 0.01f*v0;
    float v1 = a1[j]*s21 + bi1; v1 = v1 >= 0.f ? v1 : 0.01f*v1;
    mio[base + j]        = v0 + mio[base + j]        * x[base + j];
    mio[base + FU_L + j] = v1 + mio[base + FU_L + j] * x[base + FU_L + j];
  }
}

// ---------------- GNN fast path v7: no sXn (LN in place, node in place); 4 instances/block ----------------
__global__ __launch_bounds__(256) void fu_gnn7(const float* __restrict__ mmat, const float* __restrict__ ivmat,
                                               const float* __restrict__ xg,
                                               const float* __restrict__ wgm, const float* __restrict__ lna,
                                               const float* __restrict__ lnb, float* __restrict__ out){
  __shared__ float sX[4][676], sA[4][676], sWg[676], sLa[26], sLb[26];
  const int g = threadIdx.x >> 6;   // instance 0..3 (one wave each)
  const int t = threadIdx.x & 63;
  const size_t n = (size_t)blockIdx.x*4 + g;
  const float* Mrow = mmat + n*676;
  const float* Irow = ivmat + n*676;
  const float* Xres = xg + n*676;
  for (int i=t;i<676;i+=64)
    sX[g][i] = Irow[i] + Mrow[i]*Xres[i];
  if (g == 0){
    for (int i=t;i<676;i+=64) sWg[i] = wgm[i];
    if (t < 26){ sLa[t] = lna[t]; sLb[t] = lnb[t]; }
  }
  __syncthreads();
  // phase 1: 52 lanes; 2 lanes per softmax column -> sA; then LN per row IN PLACE into sX.
  // Single wave per instance: all softmax reads of sX precede LN writes in program order.
  if (t < 52){
    const int cr = t >> 1;          // column (softmax) / row (LN) 0..25
    const int h0 = (t & 1)*13;
    float mx = -1e30f;
    #pragma unroll
    for (int k=0;k<13;k++) mx = fmaxf(mx, sX[g][(h0+k)*26 + cr]);
    mx = fmaxf(mx, __shfl_xor(mx, 1));
    float sum = 0.f;
    #pragma unroll
    for (int k=0;k<13;k++){
      float e = __expf(sX[g][(h0+k)*26 + cr] - mx);
      sA[g][cr*26 + h0 + k] = e;
      sum += e;
    }
    sum += __shfl_xor(sum, 1);
    float inv = 1.f/sum;
    #pragma unroll
    for (int k=0;k<13;k++) sA[g][cr*26 + h0 + k] *= inv;
    // LayerNorm row cr in place
    float s = 0.f;
    #pragma unroll
    for (int k=0;k<13;k++) s += sX[g][cr*26 + h0 + k];
    s += __shfl_xor(s, 1);
    float mean = s * (1.f/26.f);
    float var = 0.f;
    #pragma unroll
    for (int k=0;k<13;k++){ float d = sX[g][cr*26 + h0 + k] - mean; var += d*d; }
    var += __shfl_xor(var, 1);
    var *= (1.f/25.f);
    float invd = 1.f/(sqrtf(var) + 1e-6f);
    #pragma unroll
    for (int k=0;k<13;k++){
      int v = h0 + k;
      sX[g][cr*26 + v] = sLa[v]*(sX[g][cr*26 + v] - mean)*invd + sLb[v];
    }
  }
  __syncthreads();
  // phase 3: node = A @ Xn, IN PLACE column-wise (iteration k touches only columns {k, 13+k};
  // all reads of a column precede its store in program order within the wave).
  {
    const int r = t >> 1;
    if (r < 26){
      const int v0 = (t & 1)*13;
      float ar[26];
      #pragma unroll
      for (int h=0;h<26;h++) ar[h] = sA[g][r*26 + h];
      #pragma unroll
      for (int k=0;k<13;k++){
        int v = v0 + k;
        float s = 0.f;
        #pragma unroll
        for (int h=0;h<26;h++) s += ar[h]*sX[g][h*26 + v];
        sX[g][r*26 + v] = s;
      }
    }
  }
  __syncthreads();
  // phase 4: out = relu(node @ Wg) + x. 2 threads/row.
  {
    const int r = t >> 1;
    if (r < 26){
      const int u0 = (t & 1)*13;
      float nr[26];
      #pragma unroll
      for (int v=0;v<26;v++) nr[v] = sX[g][r*26 + v];
      #pragma unroll
      for (int k=0;k<13;k++){
        int u = u0 + k;
        float s = 0.f;
        #pragma unroll
        for (int v=0;v<26;v++) s += nr[v]*sWg[v*26 + u];
        out[n*676 + r*26 + u] = fmaxf(s, 0.f) + Xres[r*26 + u];
      }
    }
  }
}

// ---------------- GNN (fallback): combined input ----------------
__global__ __launch_bounds__(64) void fu_gnn(const float* __restrict__ xmat, const float* __restrict__ xg,
                                             const float* __restrict__ wgm, const float* __restrict__ lna,
                                             const float* __restrict__ lnb, float* __restrict__ out){
  __shared__ float sX[676], sA[676], sXn[676], sWg[676], sLa[26], sLb[26];
  int n = blockIdx.x;
  int t = threadIdx.x;
  const float* Xrow = xmat + (size_t)n*676;
  for (int i=t;i<676;i+=64){ sX[i] = Xrow[i]; sWg[i] = wgm[i]; }
  if (t < 26){ sLa[t] = lna[t]; sLb[t] = lnb[t]; }
  __syncthreads();
  if (t < 26){
    float mx = -1e30f;
    #pragma unroll
    for (int h=0;h<26;h++) mx = fmaxf(mx, sX[h*26 + t]);
    float sum = 0.f;
    #pragma unroll
    for (int h=0;h<26;h++){ float e = __expf(sX[h*26 + t] - mx); sA[t*26 + h] = e; sum += e; }
    float inv = 1.f/sum;
    #pragma unroll
    for (int h=0;h<26;h++) sA[t*26 + h] *= inv;
  } else if (t >= 32 && t < 58){
    int r = t - 32;
    float s = 0.f;
    #pragma unroll
    for (int v=0;v<26;v++) s += sX[r*26 + v];
    float mean = s * (1.f/26.f);
    float var = 0.f;
    #pragma unroll
    for (int v=0;v<26;v++){ float d = sX[r*26 + v] - mean; var += d*d; }
    var *= (1.f/25.f);
    float invd = 1.f/(sqrtf(var) + 1e-6f);
    #pragma unroll
    for (int v=0;v<26;v++) sXn[r*26 + v] = sLa[v]*(sX[r*26 + v] - mean)*invd + sLb[v];
  }
  __syncthreads();
  for (int i=t;i<676;i+=64){
    int wi = i/26, v = i - wi*26;
    float s = 0.f;
    #pragma unroll
    for (int h=0;h<26;h++) s += sA[wi*26 + h]*sXn[h*26 + v];
    sX[i] = s;
  }
  __syncthreads();
  for (int i=t;i<676;i+=64){
    int wi = i/26, u = i - wi*26;
    float s = 0.f;
    #pragma unroll
    for (int v=0;v<26;v++) s += sX[wi*26 + v]*sWg[v*26 + u];
    out[(size_t)n*676 + i] = fmaxf(s, 0.f) + xg[(size_t)n*676 + i];
  }
}

// ================= fast-path kernels =================

__global__ __launch_bounds__(256) void fu_cvt_x(const float* __restrict__ x, unsigned short* __restrict__ d16){
  int i4 = (blockIdx.x*256 + threadIdx.x)*4;
  if (i4 >= 22151168) return;
  float4 v = *(const float4*)(x + i4);
  unsigned short h0,h1,h2,h3,l0,l1,l2,l3;
  fu_hilo(v.x,h0,l0); fu_hilo(v.y,h1,l1); fu_hilo(v.z,h2,l2); fu_hilo(v.w,h3,l3);
  uint2 hp, lp;
  hp.x = (unsigned)h0 | ((unsigned)h1<<16); hp.y = (unsigned)h2 | ((unsigned)h3<<16);
  lp.x = (unsigned)l0 | ((unsigned)l1<<16); lp.y = (unsigned)l2 | ((unsigned)l3<<16);
  *(uint2*)(d16 + FU_U16_XHI + i4) = hp;
  *(uint2*)(d16 + FU_U16_XLO + i4) = lp;
}

// Bm [o][l] -> hi/lo row-major [o][l] AND FRAGMENT-MAJOR transposed: off=((o>>5)*676+l)*32+(o&31)
__global__ __launch_bounds__(256) void fu_cvt_bm2(const float* __restrict__ bm, unsigned short* __restrict__ big16){
  __shared__ float t[32][33];
  const int b = blockIdx.z;
  const int l0 = blockIdx.x*32, o0 = blockIdx.y*32;
  const int tx = threadIdx.x & 31, ty = threadIdx.x >> 5;
  const float* src = bm + (size_t)b*FU_CQ*FU_L;
  #pragma unroll
  for (int q=0;q<4;q++){
    int o = o0 + ty + 8*q, l = l0 + tx;
    float v = (l < FU_L) ? src[(size_t)o*FU_L + l] : 0.f;
    t[ty+8*q][tx] = v;
    if (l < FU_L){
      unsigned short h, lo;
      fu_hilo(v, h, lo);
      big16[FU_U16_BMHI + (size_t)b*86528 + (size_t)o*FU_L + l] = h;
      big16[FU_U16_BMLO + (size_t)b*86528 + (size_t)o*FU_L + l] = lo;
    }
  }
  __syncthreads();
  #pragma unroll
  for (int q=0;q<4;q++){
    int l = l0 + ty + 8*q, o = o0 + tx;
    if (l < FU_L){
      unsigned short h, lo;
      fu_hilo(t[tx][ty+8*q], h, lo);
      unsigned off = ((unsigned)(o >> 5)*676u + (unsigned)l)*32u + (unsigned)(o & 31);
      big16[FU_U16_BMTHI + (size_t)b*86528 + off] = h;
      big16[FU_U16_BMTLO + (size_t)b*86528 + off] = lo;
    }
  }
}

// m2_w row-major hi/lo; conv2_w FRAGMENT-MAJOR hi/lo: off = ((c>>5)*512 + o)*32 + (c&31)
__global__ __launch_bounds__(256) void fu_prep2(const float* __restrict__ m2w, const float* __restrict__ c2w,
                                                const float* __restrict__ g2, const float* __restrict__ b2,
                                                const float* __restrict__ m2, const float* __restrict__ v2,
                                                unsigned short* __restrict__ m2hl, unsigned short* __restrict__ w2hl,
                                                float* __restrict__ s2, float* __restrict__ bi2){
  int i = blockIdx.x*256 + threadIdx.x;
  if (i < 262144){
    int o = i >> 9, c = i & 511;
    unsigned short h, l;
    fu_hilo(m2w[i], h, l);
    m2hl[i] = h; m2hl[262144 + i] = l;
    fu_hilo(c2w[i], h, l);
    unsigned off = ((unsigned)(c >> 5)*512u + (unsigned)o)*32u + (unsigned)(c & 31);
    w2hl[off] = h; w2hl[262144 + off] = l;
  }
  if (i < 512){
    float s = g2[i] / sqrtf(v2[i] + 1e-5f);
    s2[i] = s;
    bi2[i] = b2[i] - m2[i]*s;
  }
}

// G[b,o,c] = sum_l Bm[o,l]*x[c,l] — 64x64 wave tiles, grid (4,1,64)
__global__ __launch_bounds__(256) void fu_mfma_G(const unsigned short* __restrict__ d16,
                                                 unsigned short* __restrict__ big16){
  const int b = blockIdx.z;
  const int n0 = blockIdx.x * 128;
  const int tid = threadIdx.x;
  const int lane = tid & 63, wid = tid >> 6;
  const int wm = wid >> 1, wn = wid & 1;
  const int lr = lane & 15, lk = lane >> 4;

  const unsigned short* bmh = big16 + FU_U16_BMHI + (size_t)b*86528;
  const unsigned short* bml = big16 + FU_U16_BMLO + (size_t)b*86528;
  const unsigned short* xh  = d16 + FU_U16_XHI + (size_t)b*346112;
  const unsigned short* xl  = d16 + FU_U16_XLO + (size_t)b*346112;

  fu_f32x4 acc[4][4];
  #pragma unroll
  for (int i=0;i<4;i++)
    #pragma unroll
    for (int j=0;j<4;j++) acc[i][j] = fu_f32x4{0.f,0.f,0.f,0.f};

  int arow[4], brow[4];
  #pragma unroll
  for (int i=0;i<4;i++) arow[i] = wm*64 + i*16 + lr;
  #pragma unroll
  for (int j=0;j<4;j++) brow[j] = n0 + wn*64 + j*16 + lr;

  for (int ks=0; ks<21; ks++){
    int k0 = ks*32 + lk*8;
    FuFrag ah[4], al[4], bh[4], bl[4];
    #pragma unroll
    for (int i=0;i<4;i++){
      const unsigned short* ph = bmh + (size_t)arow[i]*676 + k0;
      const unsigned short* pl = bml + (size_t)arow[i]*676 + k0;
      ah[i].u2[0] = *(const uint2*)(ph); ah[i].u2[1] = *(const uint2*)(ph+4);
      al[i].u2[0] = *(const uint2*)(pl); al[i].u2[1] = *(const uint2*)(pl+4);
    }
    #pragma unroll
    for (int j=0;j<4;j++){
      const unsigned short* ph = xh + (size_t)brow[j]*676 + k0;
      const unsigned short* pl = xl + (size_t)brow[j]*676 + k0;
      bh[j].u2[0] = *(const uint2*)(ph); bh[j].u2[1] = *(const uint2*)(ph+4);
      bl[j].u2[0] = *(const uint2*)(pl); bl[j].u2[1] = *(const uint2*)(pl+4);
    }
    #pragma unroll
    for (int i=0;i<4;i++)
      #pragma unroll
      for (int j=0;j<4;j++){
        acc[i][j] = fu_mm(ah[i], bh[j], acc[i][j]);
        acc[i][j] = fu_mm(ah[i], bl[j], acc[i][j]);
        acc[i][j] = fu_mm(al[i], bh[j], acc[i][j]);
      }
  }
  { // tail k=672..675 (lk==0 only)
    FuFrag ah[4], al[4], bh[4], bl[4];
    #pragma unroll
    for (int i=0;i<4;i++){
      ah[i].u4 = make_uint4(0,0,0,0); al[i].u4 = make_uint4(0,0,0,0);
      if (lk == 0){
        ah[i].u2[0] = *(const uint2*)(bmh + (size_t)arow[i]*676 + 672);
        al[i].u2[0] = *(const uint2*)(bml + (size_t)arow[i]*676 + 672);
      }
    }
    #pragma unroll
    for (int j=0;j<4;j++){
      bh[j].u4 = make_uint4(0,0,0,0); bl[j].u4 = make_uint4(0,0,0,0);
      if (lk == 0){
        bh[j].u2[0] = *(const uint2*)(xh + (size_t)brow[j]*676 + 672);
        bl[j].u2[0] = *(const uint2*)(xl + (size_t)brow[j]*676 + 672);
      }
    }
    #pragma unroll
    for (int i=0;i<4;i++)
      #pragma unroll
      for (int j=0;j<4;j++){
        acc[i][j] = fu_mm(ah[i], bh[j], acc[i][j]);
        acc[i][j] = fu_mm(ah[i], bl[j], acc[i][j]);
        acc[i][j] = fu_mm(al[i], bh[j], acc[i][j]);
      }
  }
  unsigned short* gh = big16 + FU_U16_GHI + (size_t)b*65536;
  unsigned short* gl = big16 + FU_U16_GLO + (size_t)b*65536;
  #pragma unroll
  for (int i=0;i<4;i++){
    #pragma unroll
    for (int r=0;r<4;r++){
      int o = wm*64 + i*16 + lk*4 + r;
      #pragma unroll
      for (int j=0;j<4;j++){
        int ccol = n0 + wn*64 + j*16 + lr;
        unsigned short h, l;
        fu_hilo(acc[i][j][r], h, l);
        gh[(size_t)o*512 + ccol] = h;
        gl[(size_t)o*512 + ccol] = l;
      }
    }
  }
}

// V[b,o,s] = (1/676) sum_c G[o,c]*M2[s,c] — 64x64 wave tiles, grid (4,1,64)
__global__ __launch_bounds__(256) void fu_mfma_V2(const unsigned short* __restrict__ big16,
                                                  const unsigned short* __restrict__ m2hl,
                                                  float* __restrict__ vout){
  const int b = blockIdx.z;
  const int n0 = blockIdx.x * 128;
  const int tid = threadIdx.x;
  const int lane = tid & 63, wid = tid >> 6;
  const int wm = wid >> 1, wn = wid & 1;
  const int lr = lane & 15, lk = lane >> 4;

  const unsigned short* gh = big16 + FU_U16_GHI + (size_t)b*65536;
  const unsigned short* gl = big16 + FU_U16_GLO + (size_t)b*65536;
  const unsigned short* mh = m2hl;
  const unsigned short* ml = m2hl + 262144;

  fu_f32x4 acc[4][4];
  #pragma unroll
  for (int i=0;i<4;i++)
    #pragma unroll
    for (int j=0;j<4;j++) acc[i][j] = fu_f32x4{0.f,0.f,0.f,0.f};

  int arow[4], brow[4];
  #pragma unroll
  for (int i=0;i<4;i++) arow[i] = wm*64 + i*16 + lr;
  #pragma unroll
  for (int j=0;j<4;j++) brow[j] = n0 + wn*64 + j*16 + lr;

  for (int ks=0; ks<16; ks++){
    int k0 = ks*32 + lk*8;
    FuFrag ah[4], al[4], bh[4], bl[4];
    #pragma unroll
    for (int i=0;i<4;i++){
      ah[i].u4 = *(const uint4*)(gh + (size_t)arow[i]*512 + k0);
      al[i].u4 = *(const uint4*)(gl + (size_t)arow[i]*512 + k0);
    }
    #pragma unroll
    for (int j=0;j<4;j++){
      bh[j].u4 = *(const uint4*)(mh + (size_t)brow[j]*512 + k0);
      bl[j].u4 = *(const uint4*)(ml + (size_t)brow[j]*512 + k0);
    }
    #pragma unroll
    for (int i=0;i<4;i++)
      #pragma unroll
      for (int j=0;j<4;j++){
        acc[i][j] = fu_mm(ah[i], bh[j], acc[i][j]);
        acc[i][j] = fu_mm(ah[i], bl[j], acc[i][j]);
        acc[i][j] = fu_mm(al[i], bh[j], acc[i][j]);
      }
  }
  const float inv = 1.0f/676.0f;
  #pragma unroll
  for (int i=0;i<4;i++)
    #pragma unroll
    for (int r=0;r<4;r++){
      int o = wm*64 + i*16 + lk*4 + r;
      #pragma unroll
      for (int j=0;j<4;j++){
        int s = n0 + wn*64 + j*16 + lr;
        vout[((size_t)b*FU_CQ + o)*FU_C + s] = acc[i][j][r]*inv;
      }
    }
}

// V f32 [o][s] -> VT hi/lo FRAGMENT-MAJOR: off = ((o>>5)*512 + s)*32 + (o&31)
__global__ __launch_bounds__(256) void fu_cvt_vt(const float* __restrict__ v, unsigned short* __restrict__ vt16){
  __shared__ float t[32][33];
  const int b = blockIdx.z;
  const int s0 = blockIdx.x*32, o0 = blockIdx.y*32;
  const int tx = threadIdx.x & 31, ty = threadIdx.x >> 5;
  const float* src = v + (size_t)b*FU_CQ*FU_C;
  #pragma unroll
  for (int q=0;q<4;q++){
    int o = o0 + ty + 8*q, s = s0 + tx;
    t[ty+8*q][tx] = src[(size_t)o*FU_C + s];
  }
  __syncthreads();
  #pragma unroll
  for (int q=0;q<4;q++){
    int s = s0 + ty + 8*q, o = o0 + tx;
    unsigned short h, lo;
    fu_hilo(t[tx][ty+8*q], h, lo);
    unsigned off = ((unsigned)(o >> 5)*512u + (unsigned)s)*32u + (unsigned)(o & 31);
    vt16[(size_t)b*65536 + off] = h;
    vt16[FU_U16_VTLO + (size_t)b*65536 + off] = lo;
  }
}

// y[l,s] = sum_c BmT[l,c]*VT[s,c] — fragment-major operands, streamed B, grid (4,6,64)
__global__ __launch_bounds__(256, 4) void fu_mfma_y(const unsigned short* __restrict__ big16,
                                                    const unsigned short* __restrict__ vt16,
                                                    float* __restrict__ yout){
  const int b = blockIdx.z;
  const int n0 = blockIdx.x * 128;
  const int m0 = blockIdx.y * 128;
  const int tid = threadIdx.x;
  const int lane = tid & 63, wid = tid >> 6;
  const int wm = wid >> 1, wn = wid & 1;
  const int lr = lane & 15, lk = lane >> 4;

  const unsigned short* ath = big16 + FU_U16_BMTHI + (size_t)b*86528;
  const unsigned short* atl = big16 + FU_U16_BMTLO + (size_t)b*86528;
  const unsigned short* bth = vt16 + (size_t)b*65536;
  const unsigned short* btl = vt16 + FU_U16_VTLO + (size_t)b*65536;

  fu_f32x4 acc[4][4];
  #pragma unroll
  for (int i=0;i<4;i++)
    #pragma unroll
    for (int j=0;j<4;j++) acc[i][j] = fu_f32x4{0.f,0.f,0.f,0.f};

  int arow[4], brow[4];
  #pragma unroll
  for (int i=0;i<4;i++){
    int l = m0 + wm*64 + i*16 + lr;
    arow[i] = l < FU_L ? l : (FU_L-1);
  }
  #pragma unroll
  for (int j=0;j<4;j++) brow[j] = n0 + wn*64 + j*16 + lr;

  for (int ks=0; ks<4; ks++){
    FuFrag ah[4], al[4];
    #pragma unroll
    for (int i=0;i<4;i++){
      size_t off = ((size_t)ks*676 + arow[i])*32 + lk*8;
      ah[i].u4 = *(const uint4*)(ath + off);
      al[i].u4 = *(const uint4*)(atl + off);
    }
    #pragma unroll
    for (int j=0;j<4;j++){
      FuFrag bh, bl;
      size_t off = ((size_t)ks*512 + brow[j])*32 + lk*8;
      bh.u4 = *(const uint4*)(bth + off);
      bl.u4 = *(const uint4*)(btl + off);
      #pragma unroll
      for (int i=0;i<4;i++){
        acc[i][j] = fu_mm(ah[i], bh, acc[i][j]);
        acc[i][j] = fu_mm(ah[i], bl, acc[i][j]);
        acc[i][j] = fu_mm(al[i], bh, acc[i][j]);
      }
    }
  }
  #pragma unroll
  for (int i=0;i<4;i++){
    #pragma unroll
    for (int r=0;r<4;r++){
      int l = m0 + wm*64 + i*16 + lk*4 + r;
      if (l < FU_L){
        #pragma unroll
        for (int j=0;j<4;j++){
          int s = n0 + wn*64 + j*16 + lr;
          yout[(size_t)b*346112 + (size_t)l*FU_C + s] = acc[i][j][r];
        }
      }
    }
  }
}

// transpose+cvt: yflat (b,[c][l]) -> yvt FRAGMENT-MAJOR: off = ((c>>5)*676 + l2)*32 + (c&31)
__global__ __launch_bounds__(256) void fu_tr_y(const float* __restrict__ yf, unsigned short* __restrict__ big16){
  __shared__ float t[32][33];
  const int b = blockIdx.z;
  const int l0 = blockIdx.x*32, c0 = blockIdx.y*32;
  const int tx = threadIdx.x & 31, ty = threadIdx.x >> 5;
  const float* yb = yf + (size_t)b*FU_C*FU_L;
  #pragma unroll
  for (int q=0;q<4;q++){
    int c = c0 + ty + 8*q;
    int l = l0 + tx;
    t[ty + 8*q][tx] = (l < FU_L) ? yb[(size_t)c*FU_L + l] : 0.f;
  }
  __syncthreads();
  unsigned short* yh = big16 + FU_U16_YVHI + (size_t)b*346112;
  unsigned short* yl = big16 + FU_U16_YVLO + (size_t)b*346112;
  #pragma unroll
  for (int q=0;q<4;q++){
    int l2 = l0 + ty + 8*q;
    if (l2 < FU_L){
      int c = c0 + tx;
      unsigned short h, l;
      fu_hilo(t[tx][ty + 8*q], h, l);
      unsigned off = ((unsigned)(c >> 5)*676u + (unsigned)l2)*32u + (unsigned)(c & 31);
      yh[off] = h;
      yl[off] = l;
    }
  }
}

// conv2 MFMA + BN2 + leaky -> iv (write-only into d_out; X=iv+m*x deferred to gnn7)
__global__ __launch_bounds__(256, 4) void fu_mfma_c2(const unsigned short* __restrict__ big16,
                                                     const unsigned short* __restrict__ w2hl,
                                                     const float* __restrict__ s2, const float* __restrict__ bi2,
                                                     float* __restrict__ ivout){
  const int flat = blockIdx.x;                       // 1536 = 64 b x 24 tiles
  const int swz  = (flat & 7)*192 + (flat >> 3);     // bijective; each XCD owns 8 whole batches
  const int b    = swz / 24;
  const int rem  = swz - b*24;
  const int mt   = rem / 6;
  const int lt   = rem - mt*6;
  const int m0 = mt * 128;                           // o tile
  const int n0 = lt * 128;                           // l2 tile
  const int tid = threadIdx.x;
  const int lane = tid & 63, wid = tid >> 6;
  const int wm = wid >> 1, wn = wid & 1;
  const int lr = lane & 15, lk = lane >> 4;

  const unsigned short* wh = w2hl;
  const unsigned short* wl = w2hl + 262144;
  const unsigned short* yh = big16 + FU_U16_YVHI + (size_t)b*346112;
  const unsigned short* yl = big16 + FU_U16_YVLO + (size_t)b*346112;

  fu_f32x4 acc[4][4];
  #pragma unroll
  for (int i=0;i<4;i++)
    #pragma unroll
    for (int j=0;j<4;j++) acc[i][j] = fu_f32x4{0.f,0.f,0.f,0.f};

  int arow[4], brow[4];
  #pragma unroll
  for (int i=0;i<4;i++) arow[i] = m0 + wm*64 + i*16 + lr;     // o < 512
  #pragma unroll
  for (int j=0;j<4;j++){
    int l2 = n0 + wn*64 + j*16 + lr;
    brow[j] = l2 < FU_L ? l2 : (FU_L-1);
  }

  for (int ks=0; ks<16; ks++){
    FuFrag ah[4], al[4];
    #pragma unroll
    for (int i=0;i<4;i++){
      size_t off = ((size_t)ks*512 + arow[i])*32 + lk*8;      // fragment-major W2
      ah[i].u4 = *(const uint4*)(wh + off);
      al[i].u4 = *(const uint4*)(wl + off);
    }
    #pragma unroll
    for (int j=0;j<4;j++){
      FuFrag bh, bl;
      size_t off = ((size_t)ks*676 + brow[j])*32 + lk*8;      // fragment-major yvt
      bh.u4 = *(const uint4*)(yh + off);
      bl.u4 = *(const uint4*)(yl + off);
      #pragma unroll
      for (int i=0;i<4;i++){
        acc[i][j] = fu_mm(ah[i], bh, acc[i][j]);
        acc[i][j] = fu_mm(ah[i], bl, acc[i][j]);
        acc[i][j] = fu_mm(al[i], bh, acc[i][j]);
      }
    }
  }
  #pragma unroll
  for (int i=0;i<4;i++){
    #pragma unroll
    for (int r=0;r<4;r++){
      int o = m0 + wm*64 + i*16 + lk*4 + r;
      float sv = s2[o], bv = bi2[o];
      #pragma unroll
      for (int j=0;j<4;j++){
        int l2 = n0 + wn*64 + j*16 + lr;
        if (l2 < FU_L){
          float v = acc[i][j][r]*sv + bv;
          v = v >= 0.f ? v : 0.01f*v;
          ivout[((size_t)b*FU_C + o)*FU_L + l2] = v;
        }
      }
    }
  }
}

extern "C" void kernel_launch(void* const* d_in, const int* in_sizes, int n_in,
                              void* d_out, int out_size, void* d_ws, size_t ws_size,
                              hipStream_t stream){
  const float* x   = (const float*)d_in[0];
  const float* cw  = (const float*)d_in[1];
  const float* g1  = (const float*)d_in[2];
  const float* b1  = (const float*)d_in[3];
  const float* m1  = (const float*)d_in[4];
  const float* v1  = (const float*)d_in[5];
  const float* m1w = (const float*)d_in[6];
  const float* m2w = (const float*)d_in[7];
  const float* c2w = (const float*)d_in[8];
  const float* g2  = (const float*)d_in[9];
  const float* b2  = (const float*)d_in[10];
  const float* m2  = (const float*)d_in[11];
  const float* v2  = (const float*)d_in[12];
  const float* wg  = (const float*)d_in[13];
  const float* lna = (const float*)d_in[14];
  const float* lnb = (const float*)d_in[15];
  float* out = (float*)d_out;
  float* ws = (float*)d_ws;

  if (ws_size >= (size_t)FU_FAST_FLOATS * 4u){
    unsigned short* d16   = (unsigned short*)d_out;
    unsigned short* big16 = (unsigned short*)(ws + FU_OFF_BIG);
    unsigned short* vt16  = (unsigned short*)(ws + FU_OFF_V);
    unsigned short* m2hl  = (unsigned short*)(ws + FU_OFF_M2HL);
    unsigned short* w2hl  = (unsigned short*)(ws + FU_OFF_W2HL);
    float* wt1 = ws + FU_OFF_V;   // 65536 floats; dead until fu_cvt_vt

    fu_sim3<<<dim3(11,64,4), 256, 0, stream>>>(x, ws + FU_OFF_BIG);
    fu_sim_red<<<1353, 256, 0, stream>>>(ws + FU_OFF_BIG, ws + FU_OFF_SIM);
    fu_conv1b<<<dim3(64,16), 256, 0, stream>>>(cw, g1, b1, m1, v1, ws + FU_OFF_SIM, ws + FU_OFF_MBUF);
    fu_tr_w1<<<dim3(4,16), 256, 0, stream>>>(m1w, wt1);
    fu_gemm_bm<<<768, 256, 0, stream>>>(wt1, x, ws + FU_OFF_BM);
    fu_prep2<<<1024, 256, 0, stream>>>(m2w, c2w, g2, b2, m2, v2, m2hl, w2hl,
                                       ws + FU_OFF_S2, ws + FU_OFF_BI2);
    fu_cvt_x<<<21632, 256, 0, stream>>>(x, d16);
    fu_cvt_bm2<<<dim3(22,4,64), 256, 0, stream>>>(ws + FU_OFF_BM, big16);
    fu_mfma_G<<<dim3(4,1,64), 256, 0, stream>>>(d16, big16);
    fu_mfma_V2<<<dim3(4,1,64), 256, 0, stream>>>(big16, m2hl, ws + FU_OFF_BM);
    fu_cvt_vt<<<dim3(16,4,64), 256, 0, stream>>>(ws + FU_OFF_BM, vt16);
    fu_mfma_y<<<dim3(4,6,64), 256, 0, stream>>>(big16, vt16, out);
    fu_tr_y<<<dim3(22,16,64), 256, 0, stream>>>(out, big16);
    fu_mfma_c2<<<1536, 256, 0, stream>>>(big16, w2hl, ws + FU_OFF_S2, ws + FU_OFF_BI2, out);  // iv -> d_out
    fu_gnn7<<<8192, 256, 0, stream>>>(ws + FU_OFF_MBUF, out, x, wg, lna, lnb, out);
  } else if (ws_size >= (size_t)FU_FB_FLOATS * 4u){
    // fallback: round-5 pipeline
    FoldUnfoldModule_82592221102582_kernel<<<2048, 256, 0, stream>>>(out, out_size, 20.0f);
    fu_sim2<<<dim3(11,64), 256, 0, stream>>>(x, ws + FU_FB_SIM);
    fu_conv1b<<<dim3(64,16), 256, 0, stream>>>(cw, g1, b1, m1, v1, ws + FU_FB_SIM, ws + FU_FB_MBUF);
    fu_gemm_bm_fb<<<dim3(3,4,64), 256, 0, stream>>>(m1w, x, ws + FU_FB_BM);
    fu_gemm_b2<<<dim3(3,32,64), 256, 0, stream>>>(m2w, x, out);
    fu_V<<<dim3(8,2,64), 256, 0, stream>>>(ws + FU_FB_BM, out, ws + FU_FB_V);
    fu_y<<<dim3(8,11,64), 256, 0, stream>>>(ws + FU_FB_BM, ws + FU_FB_V, out);
    fu_c2<<<dim3(3,32,64), 256, 0, stream>>>(out, c2w, g2, b2, m2, v2, x, ws + FU_FB_MBUF);
    fu_gnn<<<32768, 64, 0, stream>>>(ws + FU_FB_MBUF, x, wg, lna, lnb, out);
  } else {
    FoldUnfoldModule_82592221102582_kernel<<<2048, 256, 0, stream>>>(out, out_size, 48.5f);
  }
}